// Round 3
// baseline (1861.024 us; speedup 1.0000x reference)
//
#include <hip/hip_runtime.h>
#include <math.h>

// Problem constants (from reference)
#define BB    2
#define SS    2048
#define HIDD  2048
#define NHH   16
#define NKVV  4
#define HDD   128
#define MROWS 4096            // B*S
#define QG_N  4096            // 2*NH*HD
#define KV_N  512             // NKV*HD
#define O_N   2048            // NH*HD
#define KDIM  2048            // shared K for all four GEMMs
#define EPS_  1e-6f
#define SCALE_ 0.08838834764831845f   // 1/sqrt(128)

typedef __attribute__((ext_vector_type(8))) __bf16 bf16x8;
typedef __attribute__((ext_vector_type(8))) unsigned short u16x8;
typedef __attribute__((ext_vector_type(4))) float f32x4;

__device__ __forceinline__ unsigned short f2bf(float f) {
  return __builtin_bit_cast(unsigned short, (__bf16)f);   // RNE via v_cvt
}

// ---------------------------------------------------------------------------
// fp32 -> bf16 convert, 4 elems/thread
// ---------------------------------------------------------------------------
__global__ __launch_bounds__(256) void f2bf_k(const float* __restrict__ in,
                                              unsigned short* __restrict__ out, int n4) {
  int i = blockIdx.x * 256 + threadIdx.x;
  if (i < n4) {
    float4 v = ((const float4*)in)[i];
    ushort4 u;
    u.x = f2bf(v.x); u.y = f2bf(v.y); u.z = f2bf(v.z); u.w = f2bf(v.w);
    ((ushort4*)out)[i] = u;
  }
}

// ---------------------------------------------------------------------------
// RMSNorm -> bf16 x.  One block per row.
// ---------------------------------------------------------------------------
__global__ __launch_bounds__(256) void rmsnorm_k(const float* __restrict__ h,
                                                 const float* __restrict__ w,
                                                 unsigned short* __restrict__ x) {
  int row = blockIdx.x;
  int t = threadIdx.x;
  const float4* hr = (const float4*)(h + (size_t)row * HIDD);
  const float4* w4 = (const float4*)w;

  float4 v0 = hr[t], v1 = hr[t + 256];
  float ss = v0.x*v0.x + v0.y*v0.y + v0.z*v0.z + v0.w*v0.w
           + v1.x*v1.x + v1.y*v1.y + v1.z*v1.z + v1.w*v1.w;
#pragma unroll
  for (int off = 32; off > 0; off >>= 1) ss += __shfl_down(ss, off, 64);

  __shared__ float part[4];
  __shared__ float rs_sh;
  if ((t & 63) == 0) part[t >> 6] = ss;
  __syncthreads();
  if (t == 0) rs_sh = rsqrtf((part[0]+part[1]+part[2]+part[3]) * (1.0f/HIDD) + EPS_);
  __syncthreads();
  float rs = rs_sh;

  float4 w0 = w4[t], w1 = w4[t + 256];
  ushort4 o0, o1;
  o0.x = f2bf(v0.x * rs * (1.f + w0.x));
  o0.y = f2bf(v0.y * rs * (1.f + w0.y));
  o0.z = f2bf(v0.z * rs * (1.f + w0.z));
  o0.w = f2bf(v0.w * rs * (1.f + w0.w));
  o1.x = f2bf(v1.x * rs * (1.f + w1.x));
  o1.y = f2bf(v1.y * rs * (1.f + w1.y));
  o1.z = f2bf(v1.z * rs * (1.f + w1.z));
  o1.w = f2bf(v1.w * rs * (1.f + w1.w));
  ushort4* xr = (ushort4*)(x + (size_t)row * HIDD);
  xr[t] = o0;
  xr[t + 256] = o1;
}

// ---------------------------------------------------------------------------
// bf16 MFMA GEMM: C[M,N] (fp32) = A[M,2048](bf16) * W[N,2048](bf16)^T.
// 128x128 tile, BK=64, 256 threads = 4 waves (2x2), wave tile 64x64,
// 4x4 fragments of 16x16x32 MFMA.  LDS tiles [128][64] bf16 with G4 swizzle
// byte ^= ((row&7)<<4): frag reads are 2-way (free), staging writes linear.
// ---------------------------------------------------------------------------
__global__ __launch_bounds__(256) void gemm_bf16(const unsigned short* __restrict__ Ab,
                                                 const unsigned short* __restrict__ Bb,
                                                 float* __restrict__ C,
                                                 int Ndim) {
  __shared__ unsigned short Als[128 * 64];
  __shared__ unsigned short Bls[128 * 64];
  char* ldsA = (char*)Als;
  char* ldsB = (char*)Bls;

  int t   = threadIdx.x;
  int r15 = t & 15;
  int g   = (t & 63) >> 4;
  int w   = t >> 6;
  int wr  = w >> 1, wc = w & 1;
  int bm  = blockIdx.y * 128, bn = blockIdx.x * 128;

  f32x4 acc[4][4] = {};

  for (int k0 = 0; k0 < KDIM; k0 += 64) {
    __syncthreads();            // previous iteration's readers done
    // stage A and B tiles: 8192 bf16 each, 8 elems (16B) per thread per round
#pragma unroll
    for (int it = 0; it < 4; ++it) {
      int f    = it * 256 + t;
      int row  = f >> 3;
      int slot = f & 7;
      int ldso = row * 128 + (((slot ^ (row & 7)) << 4));
      u16x8 a8 = *(const u16x8*)(Ab + ((size_t)(bm + row) << 11) + k0 + slot * 8);
      *(u16x8*)(ldsA + ldso) = a8;
      u16x8 b8 = *(const u16x8*)(Bb + ((size_t)(bn + row) << 11) + k0 + slot * 8);
      *(u16x8*)(ldsB + ldso) = b8;
    }
    __syncthreads();

#pragma unroll
    for (int tt = 0; tt < 2; ++tt) {
      bf16x8 af[4], bfv[4];
#pragma unroll
      for (int mi = 0; mi < 4; ++mi) {
        int row = wr * 64 + mi * 16 + r15;
        af[mi] = *(const bf16x8*)(ldsA + row * 128 + (((4 * tt + g) ^ (row & 7)) << 4));
      }
#pragma unroll
      for (int ni = 0; ni < 4; ++ni) {
        int row = wc * 64 + ni * 16 + r15;
        bfv[ni] = *(const bf16x8*)(ldsB + row * 128 + (((4 * tt + g) ^ (row & 7)) << 4));
      }
#pragma unroll
      for (int mi = 0; mi < 4; ++mi)
#pragma unroll
        for (int ni = 0; ni < 4; ++ni)
          acc[mi][ni] = __builtin_amdgcn_mfma_f32_16x16x32_bf16(af[mi], bfv[ni], acc[mi][ni], 0, 0, 0);
    }
  }

  // epilogue: C/D layout col=lane&15, row=(lane>>4)*4+reg
#pragma unroll
  for (int mi = 0; mi < 4; ++mi)
#pragma unroll
    for (int ni = 0; ni < 4; ++ni) {
      int col = bn + wc * 64 + ni * 16 + r15;
#pragma unroll
      for (int r = 0; r < 4; ++r) {
        int rowg = bm + wr * 64 + mi * 16 + g * 4 + r;
        C[(size_t)rowg * Ndim + col] = acc[mi][ni][r];
      }
    }
}

// ---------------------------------------------------------------------------
// Flash-style fp32 GQA attention + sigmoid-gate epilogue (bf16 output).
// Block = (q-tile of 64 rows, head h, batch b). 256 threads.
// ---------------------------------------------------------------------------
__global__ __launch_bounds__(256) void attn_k(const float* __restrict__ qg,
                                              const float* __restrict__ kbuf,
                                              const float* __restrict__ vbuf,
                                              unsigned short* __restrict__ obuf) {
  __shared__ float Qs[64][132];   // [r][k], pad->2-way reads
  __shared__ float Kt[128][65];   // [k][c], stride 65 -> 2-way reads
  __shared__ float Vs[64][128];   // [c][d], conflict-free with d=dd*16+tx
  __shared__ float Ps[64][68];    // [r][c]
  int qt = blockIdx.x, h = blockIdx.y, b = blockIdx.z;
  int kh = h >> 2;                // G = 4
  int t = threadIdx.x, tx = t & 15, ty = t >> 4;
  size_t rowQ0 = (size_t)b * SS + qt * 64;

  // stage Q tile, scale folded in
#pragma unroll
  for (int it = 0; it < 8; ++it) {
    int f = t + it * 256;
    int r = f >> 5, c4 = (f & 31) << 2;
    float4 v = *(const float4*)(qg + (rowQ0 + r) * QG_N + h * HDD + c4);
    v.x *= SCALE_; v.y *= SCALE_; v.z *= SCALE_; v.w *= SCALE_;
    *(float4*)&Qs[r][c4] = v;
  }

  float acc[4][8] = {};
  float Mrun[4] = {-INFINITY, -INFINITY, -INFINITY, -INFINITY};
  float Lrun[4] = {};

  for (int kt = 0; kt < SS / 64; ++kt) {
    size_t rowK0 = (size_t)b * SS + kt * 64;
    __syncthreads();            // prev PV done before overwriting Kt/Vs/Ps
#pragma unroll
    for (int it = 0; it < 8; ++it) {
      int f = t + it * 256;
      int c = f >> 5, k4 = (f & 31) << 2;
      float4 kv = *(const float4*)(kbuf + (rowK0 + c) * KV_N + kh * HDD + k4);
      Kt[k4+0][c] = kv.x; Kt[k4+1][c] = kv.y;
      Kt[k4+2][c] = kv.z; Kt[k4+3][c] = kv.w;
      *(float4*)&Vs[c][k4] = *(const float4*)(vbuf + (rowK0 + c) * KV_N + kh * HDD + k4);
    }
    __syncthreads();

    // S = Q K^T  (scale already folded into Q)
    float s[4][4] = {};
#pragma unroll 4
    for (int k = 0; k < HDD; ++k) {
      float a[4], bb[4];
#pragma unroll
      for (int i = 0; i < 4; ++i) a[i] = Qs[ty*4 + i][k];
#pragma unroll
      for (int j = 0; j < 4; ++j) bb[j] = Kt[k][tx*4 + j];
#pragma unroll
      for (int i = 0; i < 4; ++i)
#pragma unroll
        for (int j = 0; j < 4; ++j)
          s[i][j] = fmaf(a[i], bb[j], s[i][j]);
    }

    // online softmax per row (reduce across 16 tx lanes)
#pragma unroll
    for (int i = 0; i < 4; ++i) {
      float mt = fmaxf(fmaxf(s[i][0], s[i][1]), fmaxf(s[i][2], s[i][3]));
#pragma unroll
      for (int off = 1; off < 16; off <<= 1) mt = fmaxf(mt, __shfl_xor(mt, off, 64));
      float newM = fmaxf(Mrun[i], mt);
      float alpha = __expf(Mrun[i] - newM);   // first tile: exp(-inf)=0
      float psum = 0.f;
#pragma unroll
      for (int j = 0; j < 4; ++j) {
        float p = __expf(s[i][j] - newM);
        Ps[ty*4 + i][tx*4 + j] = p;
        psum += p;
      }
#pragma unroll
      for (int off = 1; off < 16; off <<= 1) psum += __shfl_xor(psum, off, 64);
      Lrun[i] = Lrun[i] * alpha + psum;
      Mrun[i] = newM;
#pragma unroll
      for (int dd = 0; dd < 8; ++dd) acc[i][dd] *= alpha;
    }
    __syncthreads();            // Ps visible to all lanes

    // O += P V
#pragma unroll 4
    for (int c = 0; c < 64; ++c) {
      float p[4], vv[8];
#pragma unroll
      for (int i = 0; i < 4; ++i) p[i] = Ps[ty*4 + i][c];
#pragma unroll
      for (int dd = 0; dd < 8; ++dd) vv[dd] = Vs[c][dd*16 + tx];
#pragma unroll
      for (int i = 0; i < 4; ++i)
#pragma unroll
        for (int dd = 0; dd < 8; ++dd)
          acc[i][dd] = fmaf(p[i], vv[dd], acc[i][dd]);
    }
  }

  // epilogue: normalize, sigmoid-gate, store bf16 o[b,s, h*HD+d]
#pragma unroll
  for (int i = 0; i < 4; ++i) {
    float invL = 1.f / Lrun[i];
    size_t row = rowQ0 + ty*4 + i;
#pragma unroll
    for (int dd = 0; dd < 8; ++dd) {
      int d = dd*16 + tx;
      float gt = qg[row * QG_N + O_N + h * HDD + d];   // gate = second half of qg
      float sg = 1.f / (1.f + __expf(-gt));
      obuf[row * (size_t)O_N + h * HDD + d] = f2bf(acc[i][dd] * invL * sg);
    }
  }
}

// ---------------------------------------------------------------------------
// Launch
// ---------------------------------------------------------------------------
extern "C" void kernel_launch(void* const* d_in, const int* in_sizes, int n_in,
                              void* d_out, int out_size, void* d_ws, size_t ws_size,
                              hipStream_t stream) {
  const float* hs = (const float*)d_in[0];
  // d_in[1] = position_ids (unused by the reference)
  const float* Wq = (const float*)d_in[2];
  const float* Wk = (const float*)d_in[3];
  const float* Wv = (const float*)d_in[4];
  const float* Wo = (const float*)d_in[5];
  const float* nw = (const float*)d_in[6];
  float* out = (float*)d_out;

  // workspace layout (~147 MB):
  // fp32: qgb 67.1 | kb 8.4 | vb 8.4
  // bf16: x 16.8 | ob 16.8 | Wq 16.8 | Wk 2.1 | Wv 2.1 | Wo 8.4
  float* qgb = (float*)d_ws;
  float* kb  = qgb + (size_t)MROWS * QG_N;
  float* vb  = kb  + (size_t)MROWS * KV_N;
  unsigned short* xb  = (unsigned short*)(vb + (size_t)MROWS * KV_N);
  unsigned short* ob  = xb  + (size_t)MROWS * HIDD;
  unsigned short* wqb = ob  + (size_t)MROWS * O_N;
  unsigned short* wkb = wqb + (size_t)QG_N * KDIM;
  unsigned short* wvb = wkb + (size_t)KV_N * KDIM;
  unsigned short* wob = wvb + (size_t)KV_N * KDIM;

  // weight + activation converts (memory-bound, ~40 us total)
  f2bf_k<<<(QG_N*KDIM/4 + 255)/256, 256, 0, stream>>>(Wq, wqb, QG_N*KDIM/4);
  f2bf_k<<<(KV_N*KDIM/4 + 255)/256, 256, 0, stream>>>(Wk, wkb, KV_N*KDIM/4);
  f2bf_k<<<(KV_N*KDIM/4 + 255)/256, 256, 0, stream>>>(Wv, wvb, KV_N*KDIM/4);
  f2bf_k<<<(O_N*KDIM/4  + 255)/256, 256, 0, stream>>>(Wo, wob, O_N*KDIM/4);
  rmsnorm_k<<<MROWS, 256, 0, stream>>>(hs, nw, xb);

  gemm_bf16<<<dim3(QG_N/128, MROWS/128), 256, 0, stream>>>(xb, wqb, qgb, QG_N);
  gemm_bf16<<<dim3(KV_N/128, MROWS/128), 256, 0, stream>>>(xb, wkb, kb, KV_N);
  gemm_bf16<<<dim3(KV_N/128, MROWS/128), 256, 0, stream>>>(xb, wvb, vb, KV_N);
  attn_k<<<dim3(SS/64, NHH, BB), 256, 0, stream>>>(qgb, kb, vb, ob);
  gemm_bf16<<<dim3(O_N/128, MROWS/128), 256, 0, stream>>>(ob, wob, out, O_N);
}

// Round 5
// 434.964 us; speedup vs baseline: 4.2786x; 4.2786x over previous
//
#include <hip/hip_runtime.h>
#include <math.h>

// Problem constants (from reference)
#define BB    2
#define SS    2048
#define HIDD  2048
#define NHH   16
#define NKVV  4
#define HDD   128
#define MROWS 4096            // B*S
#define QG_N  4096            // 2*NH*HD
#define KV_N  512             // NKV*HD
#define O_N   2048            // NH*HD
#define KDIM  2048            // shared K for all four GEMMs
#define EPS_  1e-6f
#define SCALE_ 0.08838834764831845f   // 1/sqrt(128)

typedef __attribute__((ext_vector_type(8))) __bf16 bf16x8;
typedef __attribute__((ext_vector_type(8))) unsigned short u16x8;
typedef __attribute__((ext_vector_type(4))) float f32x4;

__device__ __forceinline__ unsigned short f2bf(float f) {
  return __builtin_bit_cast(unsigned short, (__bf16)f);   // RNE via v_cvt
}

// ---------------------------------------------------------------------------
// fp32 -> bf16 convert, 4 elems/thread
// ---------------------------------------------------------------------------
__global__ __launch_bounds__(256) void f2bf_k(const float* __restrict__ in,
                                              unsigned short* __restrict__ out, int n4) {
  int i = blockIdx.x * 256 + threadIdx.x;
  if (i < n4) {
    float4 v = ((const float4*)in)[i];
    ushort4 u;
    u.x = f2bf(v.x); u.y = f2bf(v.y); u.z = f2bf(v.z); u.w = f2bf(v.w);
    ((ushort4*)out)[i] = u;
  }
}

// ---------------------------------------------------------------------------
// RMSNorm -> bf16 x.  One block per row.
// ---------------------------------------------------------------------------
__global__ __launch_bounds__(256) void rmsnorm_k(const float* __restrict__ h,
                                                 const float* __restrict__ w,
                                                 unsigned short* __restrict__ x) {
  int row = blockIdx.x;
  int t = threadIdx.x;
  const float4* hr = (const float4*)(h + (size_t)row * HIDD);
  const float4* w4 = (const float4*)w;

  float4 v0 = hr[t], v1 = hr[t + 256];
  float ss = v0.x*v0.x + v0.y*v0.y + v0.z*v0.z + v0.w*v0.w
           + v1.x*v1.x + v1.y*v1.y + v1.z*v1.z + v1.w*v1.w;
#pragma unroll
  for (int off = 32; off > 0; off >>= 1) ss += __shfl_down(ss, off, 64);

  __shared__ float part[4];
  __shared__ float rs_sh;
  if ((t & 63) == 0) part[t >> 6] = ss;
  __syncthreads();
  if (t == 0) rs_sh = rsqrtf((part[0]+part[1]+part[2]+part[3]) * (1.0f/HIDD) + EPS_);
  __syncthreads();
  float rs = rs_sh;

  float4 w0 = w4[t], w1 = w4[t + 256];
  ushort4 o0, o1;
  o0.x = f2bf(v0.x * rs * (1.f + w0.x));
  o0.y = f2bf(v0.y * rs * (1.f + w0.y));
  o0.z = f2bf(v0.z * rs * (1.f + w0.z));
  o0.w = f2bf(v0.w * rs * (1.f + w0.w));
  o1.x = f2bf(v1.x * rs * (1.f + w1.x));
  o1.y = f2bf(v1.y * rs * (1.f + w1.y));
  o1.z = f2bf(v1.z * rs * (1.f + w1.z));
  o1.w = f2bf(v1.w * rs * (1.f + w1.w));
  ushort4* xr = (ushort4*)(x + (size_t)row * HIDD);
  xr[t] = o0;
  xr[t + 256] = o1;
}

// ---------------------------------------------------------------------------
// bf16 MFMA GEMM: C[M,N] = A[M,2048](bf16) * W[N,2048](bf16)^T.
// Output fp32 (OBF=0) or bf16 (OBF=1).
// 128x128 tile, BK=64, 4 waves (2x2), wave tile 64x64, 16x16x32 MFMA.
// ---------------------------------------------------------------------------
template <int OBF>
__global__ __launch_bounds__(256) void gemm_bf16(const unsigned short* __restrict__ Ab,
                                                 const unsigned short* __restrict__ Bb,
                                                 void* __restrict__ Cv,
                                                 int Ndim) {
  __shared__ unsigned short Als[128 * 64];
  __shared__ unsigned short Bls[128 * 64];
  char* ldsA = (char*)Als;
  char* ldsB = (char*)Bls;

  int t   = threadIdx.x;
  int r15 = t & 15;
  int g   = (t & 63) >> 4;
  int w   = t >> 6;
  int wr  = w >> 1, wc = w & 1;
  int bm  = blockIdx.y * 128, bn = blockIdx.x * 128;

  f32x4 acc[4][4] = {};

  for (int k0 = 0; k0 < KDIM; k0 += 64) {
    __syncthreads();
#pragma unroll
    for (int it = 0; it < 4; ++it) {
      int f    = it * 256 + t;
      int row  = f >> 3;
      int slot = f & 7;
      int ldso = row * 128 + (((slot ^ (row & 7)) << 4));
      u16x8 a8 = *(const u16x8*)(Ab + ((size_t)(bm + row) << 11) + k0 + slot * 8);
      *(u16x8*)(ldsA + ldso) = a8;
      u16x8 b8 = *(const u16x8*)(Bb + ((size_t)(bn + row) << 11) + k0 + slot * 8);
      *(u16x8*)(ldsB + ldso) = b8;
    }
    __syncthreads();

#pragma unroll
    for (int tt = 0; tt < 2; ++tt) {
      bf16x8 af[4], bfv[4];
#pragma unroll
      for (int mi = 0; mi < 4; ++mi) {
        int row = wr * 64 + mi * 16 + r15;
        af[mi] = *(const bf16x8*)(ldsA + row * 128 + (((4 * tt + g) ^ (row & 7)) << 4));
      }
#pragma unroll
      for (int ni = 0; ni < 4; ++ni) {
        int row = wc * 64 + ni * 16 + r15;
        bfv[ni] = *(const bf16x8*)(ldsB + row * 128 + (((4 * tt + g) ^ (row & 7)) << 4));
      }
#pragma unroll
      for (int mi = 0; mi < 4; ++mi)
#pragma unroll
        for (int ni = 0; ni < 4; ++ni)
          acc[mi][ni] = __builtin_amdgcn_mfma_f32_16x16x32_bf16(af[mi], bfv[ni], acc[mi][ni], 0, 0, 0);
    }
  }

  // epilogue: C/D layout col=lane&15, row=(lane>>4)*4+reg
#pragma unroll
  for (int mi = 0; mi < 4; ++mi)
#pragma unroll
    for (int ni = 0; ni < 4; ++ni) {
      int col = bn + wc * 64 + ni * 16 + r15;
#pragma unroll
      for (int r = 0; r < 4; ++r) {
        int rowg = bm + wr * 64 + mi * 16 + g * 4 + r;
        if (OBF)
          ((unsigned short*)Cv)[(size_t)rowg * Ndim + col] = f2bf(acc[mi][ni][r]);
        else
          ((float*)Cv)[(size_t)rowg * Ndim + col] = acc[mi][ni][r];
      }
    }
}

// ---------------------------------------------------------------------------
// bf16 MFMA flash attention + sigmoid-gate epilogue.
// Block = (q-tile 64 rows, head h, batch b), 256 thr = 4 waves, 16 q-rows/wave.
// Q in registers (4 A-frags/lane). K [64][128] and Vt [128][64] staged bf16 in
// LDS per KV-tile, chunk^=(row&7) 16B swizzle (b128 bank floor). P goes
// through per-wave LDS to convert D-layout -> A-layout for the PV MFMAs.
// fp32 accumulators / softmax / gate.
// ---------------------------------------------------------------------------
__global__ __launch_bounds__(256) void attn_mfma(const float* __restrict__ qg,
                                                 const unsigned short* __restrict__ kb,
                                                 const unsigned short* __restrict__ vb,
                                                 unsigned short* __restrict__ obuf) {
  __shared__ unsigned short Ks[64 * 128];   // [kv][d]
  __shared__ unsigned short Vt[128 * 64];   // [d][kv]
  __shared__ unsigned short Ps[4][16 * 64]; // per-wave [q][kv]
  char* ldsK = (char*)Ks;
  char* ldsV = (char*)Vt;

  int t = threadIdx.x;
  int l = t & 63, w = t >> 6;
  int c15 = l & 15, g = l >> 4;
  char* ldsP = (char*)(Ps[w]);
  int qt = blockIdx.x, h = blockIdx.y, b = blockIdx.z;
  int kh = h >> 2;                          // G = 4
  size_t rowQ0 = (size_t)b * SS + (size_t)qt * 64;

  // Q fragments in registers: row = w*16 + c15, k(d) = g*8 + 32*ks + j
  bf16x8 qf[4];
#pragma unroll
  for (int ks = 0; ks < 4; ++ks) {
    int d0 = g * 8 + ks * 32;
    const float* qp = qg + (rowQ0 + w * 16 + c15) * QG_N + h * HDD + d0;
    float4 a = *(const float4*)qp;
    float4 c = *(const float4*)(qp + 4);
    qf[ks][0] = (__bf16)(a.x * SCALE_); qf[ks][1] = (__bf16)(a.y * SCALE_);
    qf[ks][2] = (__bf16)(a.z * SCALE_); qf[ks][3] = (__bf16)(a.w * SCALE_);
    qf[ks][4] = (__bf16)(c.x * SCALE_); qf[ks][5] = (__bf16)(c.y * SCALE_);
    qf[ks][6] = (__bf16)(c.z * SCALE_); qf[ks][7] = (__bf16)(c.w * SCALE_);
  }

  f32x4 accO[8] = {};
  float mrun[4] = {-INFINITY, -INFINITY, -INFINITY, -INFINITY};
  float lrun[4] = {0.f, 0.f, 0.f, 0.f};

  for (int kt = 0; kt < SS / 64; ++kt) {
    size_t rowK0 = (size_t)b * SS + (size_t)kt * 64;
    __syncthreads();            // all reads of prev Ks/Vt done
    // stage K: coalesced 16B loads, swizzled b128 LDS writes
#pragma unroll
    for (int it = 0; it < 4; ++it) {
      int f = it * 256 + t;
      int kv = f >> 4, slot = f & 15;
      u16x8 kd = *(const u16x8*)(kb + (rowK0 + kv) * KV_N + kh * HDD + slot * 8);
      *(u16x8*)(ldsK + kv * 256 + (((slot ^ (kv & 7)) << 4))) = kd;
    }
    // stage V transposed: kv-major lanes -> conflict-free b16 writes
#pragma unroll
    for (int it = 0; it < 4; ++it) {
      int f = it * 256 + t;
      int kv = f & 63;
      int d8 = (f >> 6) * 8;
      u16x8 vd = *(const u16x8*)(vb + (rowK0 + kv) * KV_N + kh * HDD + d8);
#pragma unroll
      for (int i = 0; i < 8; ++i) {
        int d = d8 + i;
        *(unsigned short*)(ldsV + d * 128 + (((kv >> 3) ^ (d & 7)) << 4) + (kv & 7) * 2) = vd[i];
      }
    }
    __syncthreads();

    // S = Q K^T : 16 MFMA.  accS[nf] covers kv = nf*16 + c15
    f32x4 accS[4] = {};
#pragma unroll
    for (int nf = 0; nf < 4; ++nf) {
      int kvr = nf * 16 + c15;
#pragma unroll
      for (int ks = 0; ks < 4; ++ks) {
        bf16x8 kf = *(const bf16x8*)(ldsK + kvr * 256 + ((((g + 4 * ks) ^ (kvr & 7)) << 4)));
        accS[nf] = __builtin_amdgcn_mfma_f32_16x16x32_bf16(qf[ks], kf, accS[nf], 0, 0, 0);
      }
    }

    // online softmax: row q = g*4 + r, cols spread over 16 lanes x 4 nf
    float al[4];
#pragma unroll
    for (int r = 0; r < 4; ++r) {
      float mt = fmaxf(fmaxf(accS[0][r], accS[1][r]), fmaxf(accS[2][r], accS[3][r]));
#pragma unroll
      for (int off = 1; off < 16; off <<= 1) mt = fmaxf(mt, __shfl_xor(mt, off, 64));
      float mnew = fmaxf(mrun[r], mt);
      al[r] = __expf(mrun[r] - mnew);       // first tile: exp(-inf)=0
      mrun[r] = mnew;
    }
    float ps[4] = {0.f, 0.f, 0.f, 0.f};
#pragma unroll
    for (int nf = 0; nf < 4; ++nf) {
      int kv = nf * 16 + c15;
#pragma unroll
      for (int r = 0; r < 4; ++r) {
        float p = __expf(accS[nf][r] - mrun[r]);
        ps[r] += p;
        int q = g * 4 + r;
        *(unsigned short*)(ldsP + q * 128 + (((kv >> 3) ^ (q & 7)) << 4) + (kv & 7) * 2) = f2bf(p);
      }
    }
#pragma unroll
    for (int r = 0; r < 4; ++r) {
#pragma unroll
      for (int off = 1; off < 16; off <<= 1) ps[r] += __shfl_xor(ps[r], off, 64);
      lrun[r] = lrun[r] * al[r] + ps[r];
#pragma unroll
      for (int df = 0; df < 8; ++df) accO[df][r] *= al[r];
    }
    asm volatile("s_waitcnt lgkmcnt(0)" ::: "memory");  // own-wave P writes done

    // O += P V : 16 MFMA.  A = P[q][kv] (own wave), B = Vt[d][kv]
#pragma unroll
    for (int ks2 = 0; ks2 < 2; ++ks2) {
      bf16x8 pf = *(const bf16x8*)(ldsP + c15 * 128 + ((((g + 4 * ks2) ^ (c15 & 7)) << 4)));
#pragma unroll
      for (int df = 0; df < 8; ++df) {
        int d = df * 16 + c15;
        bf16x8 vf = *(const bf16x8*)(ldsV + d * 128 + ((((g + 4 * ks2) ^ (d & 7)) << 4)));
        accO[df] = __builtin_amdgcn_mfma_f32_16x16x32_bf16(pf, vf, accO[df], 0, 0, 0);
      }
    }
  }

  // epilogue: normalize, sigmoid-gate, bf16 store
#pragma unroll
  for (int r = 0; r < 4; ++r) {
    float invL = 1.f / lrun[r];
    size_t row = rowQ0 + w * 16 + g * 4 + r;
#pragma unroll
    for (int df = 0; df < 8; ++df) {
      int d = df * 16 + c15;
      float gt = qg[row * QG_N + O_N + h * HDD + d];
      float sg = 1.f / (1.f + __expf(-gt));
      obuf[row * (size_t)O_N + h * HDD + d] = f2bf(accO[df][r] * invL * sg);
    }
  }
}

// ---------------------------------------------------------------------------
// Launch
// ---------------------------------------------------------------------------
extern "C" void kernel_launch(void* const* d_in, const int* in_sizes, int n_in,
                              void* d_out, int out_size, void* d_ws, size_t ws_size,
                              hipStream_t stream) {
  const float* hs = (const float*)d_in[0];
  // d_in[1] = position_ids (unused by the reference)
  const float* Wq = (const float*)d_in[2];
  const float* Wk = (const float*)d_in[3];
  const float* Wv = (const float*)d_in[4];
  const float* Wo = (const float*)d_in[5];
  const float* nw = (const float*)d_in[6];
  float* out = (float*)d_out;

  // workspace (~138 MB): qgb fp32 | bf16: kb,vb,x,ob,Wq,Wk,Wv,Wo
  float* qgb = (float*)d_ws;
  unsigned short* kb16 = (unsigned short*)(qgb + (size_t)MROWS * QG_N);
  unsigned short* vb16 = kb16 + (size_t)MROWS * KV_N;
  unsigned short* xb   = vb16 + (size_t)MROWS * KV_N;
  unsigned short* ob   = xb   + (size_t)MROWS * HIDD;
  unsigned short* wqb  = ob   + (size_t)MROWS * O_N;
  unsigned short* wkb  = wqb  + (size_t)QG_N * KDIM;
  unsigned short* wvb  = wkb  + (size_t)KV_N * KDIM;
  unsigned short* wob  = wvb  + (size_t)KV_N * KDIM;

  f2bf_k<<<(QG_N*KDIM/4 + 255)/256, 256, 0, stream>>>(Wq, wqb, QG_N*KDIM/4);
  f2bf_k<<<(KV_N*KDIM/4 + 255)/256, 256, 0, stream>>>(Wk, wkb, KV_N*KDIM/4);
  f2bf_k<<<(KV_N*KDIM/4 + 255)/256, 256, 0, stream>>>(Wv, wvb, KV_N*KDIM/4);
  f2bf_k<<<(O_N*KDIM/4  + 255)/256, 256, 0, stream>>>(Wo, wob, O_N*KDIM/4);
  rmsnorm_k<<<MROWS, 256, 0, stream>>>(hs, nw, xb);

  gemm_bf16<0><<<dim3(QG_N/128, MROWS/128), 256, 0, stream>>>(xb, wqb, qgb, QG_N);
  gemm_bf16<1><<<dim3(KV_N/128, MROWS/128), 256, 0, stream>>>(xb, wkb, kb16, KV_N);
  gemm_bf16<1><<<dim3(KV_N/128, MROWS/128), 256, 0, stream>>>(xb, wvb, vb16, KV_N);
  attn_mfma<<<dim3(SS/64, NHH, BB), 256, 0, stream>>>(qgb, kb16, vb16, ob);
  gemm_bf16<0><<<dim3(O_N/128, MROWS/128), 256, 0, stream>>>(ob, wob, out, O_N);
}

// Round 6
// 389.247 us; speedup vs baseline: 4.7811x; 1.1175x over previous
//
#include <hip/hip_runtime.h>
#include <math.h>

// Problem constants (from reference)
#define BB    2
#define SS    2048
#define HIDD  2048
#define NHH   16
#define NKVV  4
#define HDD   128
#define MROWS 4096            // B*S
#define QG_N  4096            // 2*NH*HD
#define KV_N  512             // NKV*HD
#define O_N   2048            // NH*HD
#define KDIM  2048            // shared K for all four GEMMs (row stride of A and W)
#define EPS_  1e-6f
#define SCALE_ 0.08838834764831845f   // 1/sqrt(128)

typedef __attribute__((ext_vector_type(8))) __bf16 bf16x8;
typedef __attribute__((ext_vector_type(8))) unsigned short u16x8;
typedef __attribute__((ext_vector_type(4))) float f32x4;

__device__ __forceinline__ unsigned short f2bf(float f) {
  return __builtin_bit_cast(unsigned short, (__bf16)f);   // RNE via v_cvt
}

// ---------------------------------------------------------------------------
// fp32 -> bf16 convert, 4 elems/thread
// ---------------------------------------------------------------------------
__global__ __launch_bounds__(256) void f2bf_k(const float* __restrict__ in,
                                              unsigned short* __restrict__ out, int n4) {
  int i = blockIdx.x * 256 + threadIdx.x;
  if (i < n4) {
    float4 v = ((const float4*)in)[i];
    ushort4 u;
    u.x = f2bf(v.x); u.y = f2bf(v.y); u.z = f2bf(v.z); u.w = f2bf(v.w);
    ((ushort4*)out)[i] = u;
  }
}

// ---------------------------------------------------------------------------
// RMSNorm -> bf16 x.  One block per row.
// ---------------------------------------------------------------------------
__global__ __launch_bounds__(256) void rmsnorm_k(const float* __restrict__ h,
                                                 const float* __restrict__ w,
                                                 unsigned short* __restrict__ x) {
  int row = blockIdx.x;
  int t = threadIdx.x;
  const float4* hr = (const float4*)(h + (size_t)row * HIDD);
  const float4* w4 = (const float4*)w;

  float4 v0 = hr[t], v1 = hr[t + 256];
  float ss = v0.x*v0.x + v0.y*v0.y + v0.z*v0.z + v0.w*v0.w
           + v1.x*v1.x + v1.y*v1.y + v1.z*v1.z + v1.w*v1.w;
#pragma unroll
  for (int off = 32; off > 0; off >>= 1) ss += __shfl_down(ss, off, 64);

  __shared__ float part[4];
  __shared__ float rs_sh;
  if ((t & 63) == 0) part[t >> 6] = ss;
  __syncthreads();
  if (t == 0) rs_sh = rsqrtf((part[0]+part[1]+part[2]+part[3]) * (1.0f/HIDD) + EPS_);
  __syncthreads();
  float rs = rs_sh;

  float4 w0 = w4[t], w1 = w4[t + 256];
  ushort4 o0, o1;
  o0.x = f2bf(v0.x * rs * (1.f + w0.x));
  o0.y = f2bf(v0.y * rs * (1.f + w0.y));
  o0.z = f2bf(v0.z * rs * (1.f + w0.z));
  o0.w = f2bf(v0.w * rs * (1.f + w0.w));
  o1.x = f2bf(v1.x * rs * (1.f + w1.x));
  o1.y = f2bf(v1.y * rs * (1.f + w1.y));
  o1.z = f2bf(v1.z * rs * (1.f + w1.z));
  o1.w = f2bf(v1.w * rs * (1.f + w1.w));
  ushort4* xr = (ushort4*)(x + (size_t)row * HIDD);
  xr[t] = o0;
  xr[t + 256] = o1;
}

// ---------------------------------------------------------------------------
// bf16 MFMA GEMM core: C[.,Ndim] = A[.,2048](bf16) * W[.,2048](bf16)^T.
// 128x128 tile, BK=64, 4 waves (2x2), wave tile 64x64, 16x16x32 MFMA.
// Staging via global_load_lds width=16: LINEAR LDS dest (wave-uniform base +
// lane*16), swizzle applied on the per-lane GLOBAL source chunk
// (slot ^= row&7), so the swizzled ds_read_b128 side is unchanged (rule #21:
// inverse-swizzled source + swizzled read).
// ---------------------------------------------------------------------------
template <int OBF>
__device__ __forceinline__ void gemm_core(const unsigned short* __restrict__ Ab,
                                          const unsigned short* __restrict__ Bb,
                                          void* __restrict__ Cv,
                                          int Ndim, int bm, int bn,
                                          unsigned short* Als, unsigned short* Bls) {
  char* ldsA = (char*)Als;
  char* ldsB = (char*)Bls;

  int t   = threadIdx.x;
  int r15 = t & 15;
  int g   = (t & 63) >> 4;
  int w   = t >> 6;
  int wr  = w >> 1, wc = w & 1;

  f32x4 acc[4][4] = {};

  for (int k0 = 0; k0 < KDIM; k0 += 64) {
    __syncthreads();            // previous iteration's readers done
#pragma unroll
    for (int it = 0; it < 4; ++it) {
      int f      = it * 256 + t;
      int row    = f >> 3;          // 0..127
      int schunk = (f & 7) ^ (row & 7);   // pre-swizzled source chunk
      unsigned ldsbase = (unsigned)((it * 256 + (w << 6)) << 4);  // wave-uniform
      __builtin_amdgcn_global_load_lds(
          (const unsigned int*)(Ab + ((size_t)(bm + row) << 11) + k0 + schunk * 8),
          (unsigned int*)(ldsA + ldsbase), 16, 0, 0);
      __builtin_amdgcn_global_load_lds(
          (const unsigned int*)(Bb + ((size_t)(bn + row) << 11) + k0 + schunk * 8),
          (unsigned int*)(ldsB + ldsbase), 16, 0, 0);
    }
    __syncthreads();

#pragma unroll
    for (int tt = 0; tt < 2; ++tt) {
      bf16x8 af[4], bfv[4];
#pragma unroll
      for (int mi = 0; mi < 4; ++mi) {
        int row = wr * 64 + mi * 16 + r15;
        af[mi] = *(const bf16x8*)(ldsA + row * 128 + (((4 * tt + g) ^ (row & 7)) << 4));
      }
#pragma unroll
      for (int ni = 0; ni < 4; ++ni) {
        int row = wc * 64 + ni * 16 + r15;
        bfv[ni] = *(const bf16x8*)(ldsB + row * 128 + (((4 * tt + g) ^ (row & 7)) << 4));
      }
#pragma unroll
      for (int mi = 0; mi < 4; ++mi)
#pragma unroll
        for (int ni = 0; ni < 4; ++ni)
          acc[mi][ni] = __builtin_amdgcn_mfma_f32_16x16x32_bf16(af[mi], bfv[ni], acc[mi][ni], 0, 0, 0);
    }
  }

  // epilogue: C/D layout col=lane&15, row=(lane>>4)*4+reg
#pragma unroll
  for (int mi = 0; mi < 4; ++mi)
#pragma unroll
    for (int ni = 0; ni < 4; ++ni) {
      int col = bn + wc * 64 + ni * 16 + r15;
#pragma unroll
      for (int r = 0; r < 4; ++r) {
        int rowg = bm + wr * 64 + mi * 16 + g * 4 + r;
        if (OBF)
          ((unsigned short*)Cv)[(size_t)rowg * Ndim + col] = f2bf(acc[mi][ni][r]);
        else
          ((float*)Cv)[(size_t)rowg * Ndim + col] = acc[mi][ni][r];
      }
    }
}

template <int OBF>
__global__ __launch_bounds__(256) void gemm_bf16(const unsigned short* __restrict__ Ab,
                                                 const unsigned short* __restrict__ Bb,
                                                 void* __restrict__ Cv,
                                                 int Ndim) {
  __shared__ unsigned short Als[128 * 64];
  __shared__ unsigned short Bls[128 * 64];
  gemm_core<OBF>(Ab, Bb, Cv, Ndim, blockIdx.y * 128, blockIdx.x * 128, Als, Bls);
}

// K and V GEMMs fused into one dispatch (N=512 each -> 256 blocks total, all
// CUs busy instead of half). blockIdx.x 0..3 -> K panel, 4..7 -> V panel.
__global__ __launch_bounds__(256) void gemm_kv(const unsigned short* __restrict__ Ab,
                                               const unsigned short* __restrict__ Wk,
                                               const unsigned short* __restrict__ Wv,
                                               unsigned short* __restrict__ Ck,
                                               unsigned short* __restrict__ Cva) {
  __shared__ unsigned short Als[128 * 64];
  __shared__ unsigned short Bls[128 * 64];
  int bx = blockIdx.x;
  const unsigned short* Bb = (bx < 4) ? Wk : Wv;
  unsigned short* Cv = (bx < 4) ? Ck : Cva;
  gemm_core<1>(Ab, Bb, (void*)Cv, KV_N, blockIdx.y * 128, (bx & 3) * 128, Als, Bls);
}

// ---------------------------------------------------------------------------
// bf16 MFMA flash attention + sigmoid-gate epilogue.  (unchanged, validated)
// Block = (q-tile 64 rows, head h, batch b), 256 thr = 4 waves, 16 q-rows/wave.
// ---------------------------------------------------------------------------
__global__ __launch_bounds__(256) void attn_mfma(const float* __restrict__ qg,
                                                 const unsigned short* __restrict__ kb,
                                                 const unsigned short* __restrict__ vb,
                                                 unsigned short* __restrict__ obuf) {
  __shared__ unsigned short Ks[64 * 128];   // [kv][d]
  __shared__ unsigned short Vt[128 * 64];   // [d][kv]
  __shared__ unsigned short Ps[4][16 * 64]; // per-wave [q][kv]
  char* ldsK = (char*)Ks;
  char* ldsV = (char*)Vt;

  int t = threadIdx.x;
  int l = t & 63, w = t >> 6;
  int c15 = l & 15, g = l >> 4;
  char* ldsP = (char*)(Ps[w]);
  int qt = blockIdx.x, h = blockIdx.y, b = blockIdx.z;
  int kh = h >> 2;                          // G = 4
  size_t rowQ0 = (size_t)b * SS + (size_t)qt * 64;

  // Q fragments in registers: row = w*16 + c15, k(d) = g*8 + 32*ks + j
  bf16x8 qf[4];
#pragma unroll
  for (int ks = 0; ks < 4; ++ks) {
    int d0 = g * 8 + ks * 32;
    const float* qp = qg + (rowQ0 + w * 16 + c15) * QG_N + h * HDD + d0;
    float4 a = *(const float4*)qp;
    float4 c = *(const float4*)(qp + 4);
    qf[ks][0] = (__bf16)(a.x * SCALE_); qf[ks][1] = (__bf16)(a.y * SCALE_);
    qf[ks][2] = (__bf16)(a.z * SCALE_); qf[ks][3] = (__bf16)(a.w * SCALE_);
    qf[ks][4] = (__bf16)(c.x * SCALE_); qf[ks][5] = (__bf16)(c.y * SCALE_);
    qf[ks][6] = (__bf16)(c.z * SCALE_); qf[ks][7] = (__bf16)(c.w * SCALE_);
  }

  f32x4 accO[8] = {};
  float mrun[4] = {-INFINITY, -INFINITY, -INFINITY, -INFINITY};
  float lrun[4] = {0.f, 0.f, 0.f, 0.f};

  for (int kt = 0; kt < SS / 64; ++kt) {
    size_t rowK0 = (size_t)b * SS + (size_t)kt * 64;
    __syncthreads();            // all reads of prev Ks/Vt done
    // stage K: coalesced 16B loads, swizzled b128 LDS writes
#pragma unroll
    for (int it = 0; it < 4; ++it) {
      int f = it * 256 + t;
      int kv = f >> 4, slot = f & 15;
      u16x8 kd = *(const u16x8*)(kb + (rowK0 + kv) * KV_N + kh * HDD + slot * 8);
      *(u16x8*)(ldsK + kv * 256 + (((slot ^ (kv & 7)) << 4))) = kd;
    }
    // stage V transposed: kv-major lanes -> conflict-free b16 writes
#pragma unroll
    for (int it = 0; it < 4; ++it) {
      int f = it * 256 + t;
      int kv = f & 63;
      int d8 = (f >> 6) * 8;
      u16x8 vd = *(const u16x8*)(vb + (rowK0 + kv) * KV_N + kh * HDD + d8);
#pragma unroll
      for (int i = 0; i < 8; ++i) {
        int d = d8 + i;
        *(unsigned short*)(ldsV + d * 128 + (((kv >> 3) ^ (d & 7)) << 4) + (kv & 7) * 2) = vd[i];
      }
    }
    __syncthreads();

    // S = Q K^T : 16 MFMA.  accS[nf] covers kv = nf*16 + c15
    f32x4 accS[4] = {};
#pragma unroll
    for (int nf = 0; nf < 4; ++nf) {
      int kvr = nf * 16 + c15;
#pragma unroll
      for (int ks = 0; ks < 4; ++ks) {
        bf16x8 kf = *(const bf16x8*)(ldsK + kvr * 256 + ((((g + 4 * ks) ^ (kvr & 7)) << 4)));
        accS[nf] = __builtin_amdgcn_mfma_f32_16x16x32_bf16(qf[ks], kf, accS[nf], 0, 0, 0);
      }
    }

    // online softmax: row q = g*4 + r, cols spread over 16 lanes x 4 nf
    float al[4];
#pragma unroll
    for (int r = 0; r < 4; ++r) {
      float mt = fmaxf(fmaxf(accS[0][r], accS[1][r]), fmaxf(accS[2][r], accS[3][r]));
#pragma unroll
      for (int off = 1; off < 16; off <<= 1) mt = fmaxf(mt, __shfl_xor(mt, off, 64));
      float mnew = fmaxf(mrun[r], mt);
      al[r] = __expf(mrun[r] - mnew);       // first tile: exp(-inf)=0
      mrun[r] = mnew;
    }
    float ps[4] = {0.f, 0.f, 0.f, 0.f};
#pragma unroll
    for (int nf = 0; nf < 4; ++nf) {
      int kv = nf * 16 + c15;
#pragma unroll
      for (int r = 0; r < 4; ++r) {
        float p = __expf(accS[nf][r] - mrun[r]);
        ps[r] += p;
        int q = g * 4 + r;
        *(unsigned short*)(ldsP + q * 128 + (((kv >> 3) ^ (q & 7)) << 4) + (kv & 7) * 2) = f2bf(p);
      }
    }
#pragma unroll
    for (int r = 0; r < 4; ++r) {
#pragma unroll
      for (int off = 1; off < 16; off <<= 1) ps[r] += __shfl_xor(ps[r], off, 64);
      lrun[r] = lrun[r] * al[r] + ps[r];
#pragma unroll
      for (int df = 0; df < 8; ++df) accO[df][r] *= al[r];
    }
    asm volatile("s_waitcnt lgkmcnt(0)" ::: "memory");  // own-wave P writes done

    // O += P V : 16 MFMA.  A = P[q][kv] (own wave), B = Vt[d][kv]
#pragma unroll
    for (int ks2 = 0; ks2 < 2; ++ks2) {
      bf16x8 pf = *(const bf16x8*)(ldsP + c15 * 128 + ((((g + 4 * ks2) ^ (c15 & 7)) << 4)));
#pragma unroll
      for (int df = 0; df < 8; ++df) {
        int d = df * 16 + c15;
        bf16x8 vf = *(const bf16x8*)(ldsV + d * 128 + ((((g + 4 * ks2) ^ (d & 7)) << 4)));
        accO[df] = __builtin_amdgcn_mfma_f32_16x16x32_bf16(pf, vf, accO[df], 0, 0, 0);
      }
    }
  }

  // epilogue: normalize, sigmoid-gate, bf16 store
#pragma unroll
  for (int r = 0; r < 4; ++r) {
    float invL = 1.f / lrun[r];
    size_t row = rowQ0 + w * 16 + g * 4 + r;
#pragma unroll
    for (int df = 0; df < 8; ++df) {
      int d = df * 16 + c15;
      float gt = qg[row * QG_N + O_N + h * HDD + d];
      float sg = 1.f / (1.f + __expf(-gt));
      obuf[row * (size_t)O_N + h * HDD + d] = f2bf(accO[df][r] * invL * sg);
    }
  }
}

// ---------------------------------------------------------------------------
// Launch
// ---------------------------------------------------------------------------
extern "C" void kernel_launch(void* const* d_in, const int* in_sizes, int n_in,
                              void* d_out, int out_size, void* d_ws, size_t ws_size,
                              hipStream_t stream) {
  const float* hs = (const float*)d_in[0];
  // d_in[1] = position_ids (unused by the reference)
  const float* Wq = (const float*)d_in[2];
  const float* Wk = (const float*)d_in[3];
  const float* Wv = (const float*)d_in[4];
  const float* Wo = (const float*)d_in[5];
  const float* nw = (const float*)d_in[6];
  float* out = (float*)d_out;

  // workspace (~138 MB): qgb fp32 | bf16: kb,vb,x,ob,Wq,Wk,Wv,Wo
  float* qgb = (float*)d_ws;
  unsigned short* kb16 = (unsigned short*)(qgb + (size_t)MROWS * QG_N);
  unsigned short* vb16 = kb16 + (size_t)MROWS * KV_N;
  unsigned short* xb   = vb16 + (size_t)MROWS * KV_N;
  unsigned short* ob   = xb   + (size_t)MROWS * HIDD;
  unsigned short* wqb  = ob   + (size_t)MROWS * O_N;
  unsigned short* wkb  = wqb  + (size_t)QG_N * KDIM;
  unsigned short* wvb  = wkb  + (size_t)KV_N * KDIM;
  unsigned short* wob  = wvb  + (size_t)KV_N * KDIM;

  f2bf_k<<<(QG_N*KDIM/4 + 255)/256, 256, 0, stream>>>(Wq, wqb, QG_N*KDIM/4);
  f2bf_k<<<(KV_N*KDIM/4 + 255)/256, 256, 0, stream>>>(Wk, wkb, KV_N*KDIM/4);
  f2bf_k<<<(KV_N*KDIM/4 + 255)/256, 256, 0, stream>>>(Wv, wvb, KV_N*KDIM/4);
  f2bf_k<<<(O_N*KDIM/4  + 255)/256, 256, 0, stream>>>(Wo, wob, O_N*KDIM/4);
  rmsnorm_k<<<MROWS, 256, 0, stream>>>(hs, nw, xb);

  gemm_bf16<0><<<dim3(QG_N/128, MROWS/128), 256, 0, stream>>>(xb, wqb, qgb, QG_N);
  gemm_kv<<<dim3(8, MROWS/128), 256, 0, stream>>>(xb, wkb, wvb, kb16, vb16);
  attn_mfma<<<dim3(SS/64, NHH, BB), 256, 0, stream>>>(qgb, kb16, vb16, ob);
  gemm_bf16<0><<<dim3(O_N/128, MROWS/128), 256, 0, stream>>>(ob, wob, out, O_N);
}

// Round 7
// 373.975 us; speedup vs baseline: 4.9763x; 1.0408x over previous
//
#include <hip/hip_runtime.h>
#include <math.h>

// Problem constants (from reference)
#define BB    2
#define SS    2048
#define HIDD  2048
#define NHH   16
#define NKVV  4
#define HDD   128
#define MROWS 4096            // B*S
#define QG_N  4096            // 2*NH*HD
#define KV_N  512             // NKV*HD
#define O_N   2048            // NH*HD
#define KDIM  2048            // shared K for all four GEMMs (row stride of A and W)
#define EPS_  1e-6f
#define SCALE_ 0.08838834764831845f   // 1/sqrt(128)

typedef __attribute__((ext_vector_type(8))) __bf16 bf16x8;
typedef __attribute__((ext_vector_type(8))) unsigned short u16x8;
typedef __attribute__((ext_vector_type(4))) float f32x4;

__device__ __forceinline__ unsigned short f2bf(float f) {
  return __builtin_bit_cast(unsigned short, (__bf16)f);   // RNE via v_cvt
}

// ---------------------------------------------------------------------------
// fp32 -> bf16 convert, 4 elems/thread
// ---------------------------------------------------------------------------
__global__ __launch_bounds__(256) void f2bf_k(const float* __restrict__ in,
                                              unsigned short* __restrict__ out, int n4) {
  int i = blockIdx.x * 256 + threadIdx.x;
  if (i < n4) {
    float4 v = ((const float4*)in)[i];
    ushort4 u;
    u.x = f2bf(v.x); u.y = f2bf(v.y); u.z = f2bf(v.z); u.w = f2bf(v.w);
    ((ushort4*)out)[i] = u;
  }
}

// ---------------------------------------------------------------------------
// RMSNorm -> bf16 x.  One block per row.
// ---------------------------------------------------------------------------
__global__ __launch_bounds__(256) void rmsnorm_k(const float* __restrict__ h,
                                                 const float* __restrict__ w,
                                                 unsigned short* __restrict__ x) {
  int row = blockIdx.x;
  int t = threadIdx.x;
  const float4* hr = (const float4*)(h + (size_t)row * HIDD);
  const float4* w4 = (const float4*)w;

  float4 v0 = hr[t], v1 = hr[t + 256];
  float ss = v0.x*v0.x + v0.y*v0.y + v0.z*v0.z + v0.w*v0.w
           + v1.x*v1.x + v1.y*v1.y + v1.z*v1.z + v1.w*v1.w;
#pragma unroll
  for (int off = 32; off > 0; off >>= 1) ss += __shfl_down(ss, off, 64);

  __shared__ float part[4];
  __shared__ float rs_sh;
  if ((t & 63) == 0) part[t >> 6] = ss;
  __syncthreads();
  if (t == 0) rs_sh = rsqrtf((part[0]+part[1]+part[2]+part[3]) * (1.0f/HIDD) + EPS_);
  __syncthreads();
  float rs = rs_sh;

  float4 w0 = w4[t], w1 = w4[t + 256];
  ushort4 o0, o1;
  o0.x = f2bf(v0.x * rs * (1.f + w0.x));
  o0.y = f2bf(v0.y * rs * (1.f + w0.y));
  o0.z = f2bf(v0.z * rs * (1.f + w0.z));
  o0.w = f2bf(v0.w * rs * (1.f + w0.w));
  o1.x = f2bf(v1.x * rs * (1.f + w1.x));
  o1.y = f2bf(v1.y * rs * (1.f + w1.y));
  o1.z = f2bf(v1.z * rs * (1.f + w1.z));
  o1.w = f2bf(v1.w * rs * (1.f + w1.w));
  ushort4* xr = (ushort4*)(x + (size_t)row * HIDD);
  xr[t] = o0;
  xr[t + 256] = o1;
}

// ---------------------------------------------------------------------------
// bf16 MFMA GEMM core: C[.,Ndim] = A[.,2048](bf16) * W[.,2048](bf16)^T.
// 128x128 tile, BK=64, 4 waves (2x2), wave tile 64x64, 16x16x32 MFMA.
// Staging via global_load_lds width=16 (linear dest, pre-swizzled source).
// ---------------------------------------------------------------------------
template <int OBF>
__device__ __forceinline__ void gemm_core(const unsigned short* __restrict__ Ab,
                                          const unsigned short* __restrict__ Bb,
                                          void* __restrict__ Cv,
                                          int Ndim, int bm, int bn,
                                          unsigned short* Als, unsigned short* Bls) {
  char* ldsA = (char*)Als;
  char* ldsB = (char*)Bls;

  int t   = threadIdx.x;
  int r15 = t & 15;
  int g   = (t & 63) >> 4;
  int w   = t >> 6;
  int wr  = w >> 1, wc = w & 1;

  f32x4 acc[4][4] = {};

  for (int k0 = 0; k0 < KDIM; k0 += 64) {
    __syncthreads();            // previous iteration's readers done
#pragma unroll
    for (int it = 0; it < 4; ++it) {
      int f      = it * 256 + t;
      int row    = f >> 3;          // 0..127
      int schunk = (f & 7) ^ (row & 7);   // pre-swizzled source chunk
      unsigned ldsbase = (unsigned)((it * 256 + (w << 6)) << 4);  // wave-uniform
      __builtin_amdgcn_global_load_lds(
          (const unsigned int*)(Ab + ((size_t)(bm + row) << 11) + k0 + schunk * 8),
          (unsigned int*)(ldsA + ldsbase), 16, 0, 0);
      __builtin_amdgcn_global_load_lds(
          (const unsigned int*)(Bb + ((size_t)(bn + row) << 11) + k0 + schunk * 8),
          (unsigned int*)(ldsB + ldsbase), 16, 0, 0);
    }
    __syncthreads();

#pragma unroll
    for (int tt = 0; tt < 2; ++tt) {
      bf16x8 af[4], bfv[4];
#pragma unroll
      for (int mi = 0; mi < 4; ++mi) {
        int row = wr * 64 + mi * 16 + r15;
        af[mi] = *(const bf16x8*)(ldsA + row * 128 + (((4 * tt + g) ^ (row & 7)) << 4));
      }
#pragma unroll
      for (int ni = 0; ni < 4; ++ni) {
        int row = wc * 64 + ni * 16 + r15;
        bfv[ni] = *(const bf16x8*)(ldsB + row * 128 + (((4 * tt + g) ^ (row & 7)) << 4));
      }
#pragma unroll
      for (int mi = 0; mi < 4; ++mi)
#pragma unroll
        for (int ni = 0; ni < 4; ++ni)
          acc[mi][ni] = __builtin_amdgcn_mfma_f32_16x16x32_bf16(af[mi], bfv[ni], acc[mi][ni], 0, 0, 0);
    }
  }

  // epilogue: C/D layout col=lane&15, row=(lane>>4)*4+reg
#pragma unroll
  for (int mi = 0; mi < 4; ++mi)
#pragma unroll
    for (int ni = 0; ni < 4; ++ni) {
      int col = bn + wc * 64 + ni * 16 + r15;
#pragma unroll
      for (int r = 0; r < 4; ++r) {
        int rowg = bm + wr * 64 + mi * 16 + g * 4 + r;
        if (OBF)
          ((unsigned short*)Cv)[(size_t)rowg * Ndim + col] = f2bf(acc[mi][ni][r]);
        else
          ((float*)Cv)[(size_t)rowg * Ndim + col] = acc[mi][ni][r];
      }
    }
}

template <int OBF>
__global__ __launch_bounds__(256) void gemm_bf16(const unsigned short* __restrict__ Ab,
                                                 const unsigned short* __restrict__ Bb,
                                                 void* __restrict__ Cv,
                                                 int Ndim) {
  __shared__ unsigned short Als[128 * 64];
  __shared__ unsigned short Bls[128 * 64];
  gemm_core<OBF>(Ab, Bb, Cv, Ndim, blockIdx.y * 128, blockIdx.x * 128, Als, Bls);
}

// K and V GEMMs fused into one dispatch.
__global__ __launch_bounds__(256) void gemm_kv(const unsigned short* __restrict__ Ab,
                                               const unsigned short* __restrict__ Wk,
                                               const unsigned short* __restrict__ Wv,
                                               unsigned short* __restrict__ Ck,
                                               unsigned short* __restrict__ Cva) {
  __shared__ unsigned short Als[128 * 64];
  __shared__ unsigned short Bls[128 * 64];
  int bx = blockIdx.x;
  const unsigned short* Bb = (bx < 4) ? Wk : Wv;
  unsigned short* Cv = (bx < 4) ? Ck : Cva;
  gemm_core<1>(Ab, Bb, (void*)Cv, KV_N, blockIdx.y * 128, (bx & 3) * 128, Als, Bls);
}

// ---------------------------------------------------------------------------
// bf16 MFMA flash attention v2: swapped QK^T (S^T = K·Q) so each lane owns one
// q-column with 16 kv values in registers -> softmax reduce = 2 shfl_xor.
// Q-tile 128 rows/block (2 q-frags per wave) amortizes K/V staging 2x.
// P packed to b64 LDS chunks, XOR-swizzled by q&15 (bank floor both sides).
// Defer-max (THR=8) skips accO rescale when wave-uniformly safe.
// Block = 256 thr = 4 waves; grid (SS/128, NH, B).  LDS 48 KB.
// ---------------------------------------------------------------------------
__global__ __launch_bounds__(256) void attn_mfma(const float* __restrict__ qg,
                                                 const unsigned short* __restrict__ kb,
                                                 const unsigned short* __restrict__ vb,
                                                 unsigned short* __restrict__ obuf) {
  __shared__ unsigned short Ks[64 * 128];   // [kv][d], chunk^=(kv&7) swizzle
  __shared__ unsigned short Vt[128 * 64];   // [d][kv], chunk^=(d&7) swizzle
  __shared__ unsigned short Ps[4][32 * 64]; // per-wave [q][kv], 8B chunk^=(q&15)
  char* ldsK = (char*)Ks;
  char* ldsV = (char*)Vt;

  int t = threadIdx.x;
  int l = t & 63, w = t >> 6;
  int c15 = l & 15, g = l >> 4;
  char* ldsP = (char*)(Ps[w]);
  int qt = blockIdx.x, h = blockIdx.y, b = blockIdx.z;
  int kh = h >> 2;                          // G = 4
  size_t rowQ0 = (size_t)b * SS + (size_t)qt * 128;

  // Q fragments (B-operand): col=c15 -> q row = w*32 + qi*16 + c15,
  // k(d) = g*8 + ks*32 + j  (same lane map as the old A-operand load)
  bf16x8 qf[2][4];
#pragma unroll
  for (int qi = 0; qi < 2; ++qi)
#pragma unroll
    for (int ks = 0; ks < 4; ++ks) {
      int d0 = g * 8 + ks * 32;
      const float* qp = qg + (rowQ0 + w * 32 + qi * 16 + c15) * QG_N + h * HDD + d0;
      float4 a = *(const float4*)qp;
      float4 c = *(const float4*)(qp + 4);
      bf16x8 q8;
      q8[0] = (__bf16)(a.x * SCALE_); q8[1] = (__bf16)(a.y * SCALE_);
      q8[2] = (__bf16)(a.z * SCALE_); q8[3] = (__bf16)(a.w * SCALE_);
      q8[4] = (__bf16)(c.x * SCALE_); q8[5] = (__bf16)(c.y * SCALE_);
      q8[6] = (__bf16)(c.z * SCALE_); q8[7] = (__bf16)(c.w * SCALE_);
      qf[qi][ks] = q8;
    }

  f32x4 accO[2][8] = {};
  float mrun[2] = {-INFINITY, -INFINITY};
  float lrun[2] = {0.f, 0.f};

  for (int kt = 0; kt < SS / 64; ++kt) {
    size_t rowK0 = (size_t)b * SS + (size_t)kt * 64;
    __syncthreads();            // all reads of prev Ks/Vt done
    // stage K via global_load_lds (linear dest, pre-swizzled source chunk)
#pragma unroll
    for (int it = 0; it < 4; ++it) {
      int f = it * 256 + t;
      int kv = f >> 4;
      int schunk = (f & 15) ^ (kv & 7);
      unsigned ldsbase = (unsigned)((it * 256 + (w << 6)) << 4);
      __builtin_amdgcn_global_load_lds(
          (const unsigned int*)(kb + (rowK0 + kv) * KV_N + kh * HDD + schunk * 8),
          (unsigned int*)(ldsK + ldsbase), 16, 0, 0);
    }
    // stage V transposed: kv-major lanes -> b16 writes
#pragma unroll
    for (int it = 0; it < 4; ++it) {
      int f = it * 256 + t;
      int kv = f & 63;
      int d8 = (f >> 6) * 8;
      u16x8 vd = *(const u16x8*)(vb + (rowK0 + kv) * KV_N + kh * HDD + d8);
#pragma unroll
      for (int i = 0; i < 8; ++i) {
        int d = d8 + i;
        *(unsigned short*)(ldsV + d * 128 + (((kv >> 3) ^ (d & 7)) << 4) + (kv & 7) * 2) = vd[i];
      }
    }
    __syncthreads();

    // S^T = K Q : 32 MFMA.  accS[qi][nf]: col=c15=q, row=kv=nf*16+g*4+r
    f32x4 accS[2][4] = {};
#pragma unroll
    for (int nf = 0; nf < 4; ++nf) {
      int kvr = nf * 16 + c15;
#pragma unroll
      for (int ks = 0; ks < 4; ++ks) {
        bf16x8 kf = *(const bf16x8*)(ldsK + kvr * 256 + ((((g + 4 * ks) ^ (kvr & 7)) << 4)));
#pragma unroll
        for (int qi = 0; qi < 2; ++qi)
          accS[qi][nf] = __builtin_amdgcn_mfma_f32_16x16x32_bf16(kf, qf[qi][ks], accS[qi][nf], 0, 0, 0);
      }
    }

    // per-lane tile max over own q-column (16 regs), reduce over 4 kv-groups
    float mt[2];
#pragma unroll
    for (int qi = 0; qi < 2; ++qi) {
      float m0 = fmaxf(fmaxf(accS[qi][0][0], accS[qi][0][1]), fmaxf(accS[qi][0][2], accS[qi][0][3]));
#pragma unroll
      for (int nf = 1; nf < 4; ++nf)
        m0 = fmaxf(m0, fmaxf(fmaxf(accS[qi][nf][0], accS[qi][nf][1]), fmaxf(accS[qi][nf][2], accS[qi][nf][3])));
      m0 = fmaxf(m0, __shfl_xor(m0, 16, 64));
      m0 = fmaxf(m0, __shfl_xor(m0, 32, 64));
      mt[qi] = m0;
    }

    // defer-max: skip rescale when wave-uniformly safe (bounded by e^8)
    bool safe = (mt[0] <= mrun[0] + 8.f) && (mt[1] <= mrun[1] + 8.f);
    if (!__all(safe)) {
#pragma unroll
      for (int qi = 0; qi < 2; ++qi) {
        float mnew = fmaxf(mrun[qi], mt[qi]);
        float al = __expf(mrun[qi] - mnew);   // first tile: exp(-inf)=0
        mrun[qi] = mnew;
        lrun[qi] *= al;
        float alr[4];
#pragma unroll
        for (int r = 0; r < 4; ++r) alr[r] = __shfl(al, g * 4 + r, 16);
#pragma unroll
        for (int df = 0; df < 8; ++df)
#pragma unroll
          for (int r = 0; r < 4; ++r) accO[qi][df][r] *= alr[r];
      }
    }

    // P = exp(S - m) in place, accumulate row-sum, pack 4 kv -> b64 store
#pragma unroll
    for (int qi = 0; qi < 2; ++qi) {
      float ps = 0.f;
#pragma unroll
      for (int nf = 0; nf < 4; ++nf) {
        float p0 = __expf(accS[qi][nf][0] - mrun[qi]);
        float p1 = __expf(accS[qi][nf][1] - mrun[qi]);
        float p2 = __expf(accS[qi][nf][2] - mrun[qi]);
        float p3 = __expf(accS[qi][nf][3] - mrun[qi]);
        ps += (p0 + p1) + (p2 + p3);
        ushort4 pk;
        pk.x = f2bf(p0); pk.y = f2bf(p1); pk.z = f2bf(p2); pk.w = f2bf(p3);
        int q = qi * 16 + c15;
        *(ushort4*)(ldsP + q * 128 + ((((nf << 2) + g) ^ (q & 15)) << 3)) = pk;
      }
      ps += __shfl_xor(ps, 16, 64);
      ps += __shfl_xor(ps, 32, 64);
      lrun[qi] += ps;
    }
    asm volatile("s_waitcnt lgkmcnt(0)" ::: "memory");  // own-wave P writes done

    // O += P V : 32 MFMA.  A = P[q][kv] (own wave), B = Vt[d][kv]
#pragma unroll
    for (int ks2 = 0; ks2 < 2; ++ks2) {
      bf16x8 pf[2];
#pragma unroll
      for (int qi = 0; qi < 2; ++qi) {
        int q = qi * 16 + c15;
        int ch0 = ((ks2 << 3) + (g << 1)) ^ (q & 15);
        int ch1 = ((ks2 << 3) + (g << 1) + 1) ^ (q & 15);
        ushort4 lo = *(const ushort4*)(ldsP + q * 128 + (ch0 << 3));
        ushort4 hi = *(const ushort4*)(ldsP + q * 128 + (ch1 << 3));
        u16x8 p8 = {lo.x, lo.y, lo.z, lo.w, hi.x, hi.y, hi.z, hi.w};
        pf[qi] = __builtin_bit_cast(bf16x8, p8);
      }
#pragma unroll
      for (int df = 0; df < 8; ++df) {
        int d = df * 16 + c15;
        bf16x8 vf = *(const bf16x8*)(ldsV + d * 128 + ((((g + 4 * ks2) ^ (d & 7)) << 4)));
#pragma unroll
        for (int qi = 0; qi < 2; ++qi)
          accO[qi][df] = __builtin_amdgcn_mfma_f32_16x16x32_bf16(pf[qi], vf, accO[qi][df], 0, 0, 0);
      }
    }
  }

  // epilogue: normalize (invL via shfl), sigmoid-gate, bf16 store
#pragma unroll
  for (int qi = 0; qi < 2; ++qi) {
    float invL = 1.f / lrun[qi];
    float ivr[4];
#pragma unroll
    for (int r = 0; r < 4; ++r) ivr[r] = __shfl(invL, g * 4 + r, 16);
#pragma unroll
    for (int r = 0; r < 4; ++r) {
      size_t row = rowQ0 + w * 32 + qi * 16 + g * 4 + r;
#pragma unroll
      for (int df = 0; df < 8; ++df) {
        int d = df * 16 + c15;
        float gt = qg[row * QG_N + O_N + h * HDD + d];
        float sg = 1.f / (1.f + __expf(-gt));
        obuf[row * (size_t)O_N + h * HDD + d] = f2bf(accO[qi][df][r] * ivr[r] * sg);
      }
    }
  }
}

// ---------------------------------------------------------------------------
// Launch
// ---------------------------------------------------------------------------
extern "C" void kernel_launch(void* const* d_in, const int* in_sizes, int n_in,
                              void* d_out, int out_size, void* d_ws, size_t ws_size,
                              hipStream_t stream) {
  const float* hs = (const float*)d_in[0];
  // d_in[1] = position_ids (unused by the reference)
  const float* Wq = (const float*)d_in[2];
  const float* Wk = (const float*)d_in[3];
  const float* Wv = (const float*)d_in[4];
  const float* Wo = (const float*)d_in[5];
  const float* nw = (const float*)d_in[6];
  float* out = (float*)d_out;

  // workspace (~138 MB): qgb fp32 | bf16: kb,vb,x,ob,Wq,Wk,Wv,Wo
  float* qgb = (float*)d_ws;
  unsigned short* kb16 = (unsigned short*)(qgb + (size_t)MROWS * QG_N);
  unsigned short* vb16 = kb16 + (size_t)MROWS * KV_N;
  unsigned short* xb   = vb16 + (size_t)MROWS * KV_N;
  unsigned short* ob   = xb   + (size_t)MROWS * HIDD;
  unsigned short* wqb  = ob   + (size_t)MROWS * O_N;
  unsigned short* wkb  = wqb  + (size_t)QG_N * KDIM;
  unsigned short* wvb  = wkb  + (size_t)KV_N * KDIM;
  unsigned short* wob  = wvb  + (size_t)KV_N * KDIM;

  f2bf_k<<<(QG_N*KDIM/4 + 255)/256, 256, 0, stream>>>(Wq, wqb, QG_N*KDIM/4);
  f2bf_k<<<(KV_N*KDIM/4 + 255)/256, 256, 0, stream>>>(Wk, wkb, KV_N*KDIM/4);
  f2bf_k<<<(KV_N*KDIM/4 + 255)/256, 256, 0, stream>>>(Wv, wvb, KV_N*KDIM/4);
  f2bf_k<<<(O_N*KDIM/4  + 255)/256, 256, 0, stream>>>(Wo, wob, O_N*KDIM/4);
  rmsnorm_k<<<MROWS, 256, 0, stream>>>(hs, nw, xb);

  gemm_bf16<0><<<dim3(QG_N/128, MROWS/128), 256, 0, stream>>>(xb, wqb, qgb, QG_N);
  gemm_kv<<<dim3(8, MROWS/128), 256, 0, stream>>>(xb, wkb, wvb, kb16, vb16);
  attn_mfma<<<dim3(SS/128, NHH, BB), 256, 0, stream>>>(qgb, kb16, vb16, ob);
  gemm_bf16<0><<<dim3(O_N/128, MROWS/128), 256, 0, stream>>>(ob, wob, out, O_N);
}

// Round 8
// 296.295 us; speedup vs baseline: 6.2810x; 1.2622x over previous
//
#include <hip/hip_runtime.h>
#include <math.h>

// Problem constants (from reference)
#define BB    2
#define SS    2048
#define HIDD  2048
#define NHH   16
#define NKVV  4
#define HDD   128
#define MROWS 4096            // B*S
#define QG_N  4096            // 2*NH*HD
#define KV_N  512             // NKV*HD
#define O_N   2048            // NH*HD
#define KDIM  2048            // shared K for all four GEMMs (row stride of A and W)
#define EPS_  1e-6f
#define SCALE_ 0.08838834764831845f   // 1/sqrt(128)

typedef __attribute__((ext_vector_type(8))) __bf16 bf16x8;
typedef __attribute__((ext_vector_type(8))) unsigned short u16x8;
typedef __attribute__((ext_vector_type(4))) float f32x4;

__device__ __forceinline__ unsigned short f2bf(float f) {
  return __builtin_bit_cast(unsigned short, (__bf16)f);   // RNE via v_cvt
}

// ---------------------------------------------------------------------------
// fp32 -> bf16 convert, 4 elems/thread
// ---------------------------------------------------------------------------
__global__ __launch_bounds__(256) void f2bf_k(const float* __restrict__ in,
                                              unsigned short* __restrict__ out, int n4) {
  int i = blockIdx.x * 256 + threadIdx.x;
  if (i < n4) {
    float4 v = ((const float4*)in)[i];
    ushort4 u;
    u.x = f2bf(v.x); u.y = f2bf(v.y); u.z = f2bf(v.z); u.w = f2bf(v.w);
    ((ushort4*)out)[i] = u;
  }
}

// ---------------------------------------------------------------------------
// RMSNorm -> bf16 x.  One block per row.
// ---------------------------------------------------------------------------
__global__ __launch_bounds__(256) void rmsnorm_k(const float* __restrict__ h,
                                                 const float* __restrict__ w,
                                                 unsigned short* __restrict__ x) {
  int row = blockIdx.x;
  int t = threadIdx.x;
  const float4* hr = (const float4*)(h + (size_t)row * HIDD);
  const float4* w4 = (const float4*)w;

  float4 v0 = hr[t], v1 = hr[t + 256];
  float ss = v0.x*v0.x + v0.y*v0.y + v0.z*v0.z + v0.w*v0.w
           + v1.x*v1.x + v1.y*v1.y + v1.z*v1.z + v1.w*v1.w;
#pragma unroll
  for (int off = 32; off > 0; off >>= 1) ss += __shfl_down(ss, off, 64);

  __shared__ float part[4];
  __shared__ float rs_sh;
  if ((t & 63) == 0) part[t >> 6] = ss;
  __syncthreads();
  if (t == 0) rs_sh = rsqrtf((part[0]+part[1]+part[2]+part[3]) * (1.0f/HIDD) + EPS_);
  __syncthreads();
  float rs = rs_sh;

  float4 w0 = w4[t], w1 = w4[t + 256];
  ushort4 o0, o1;
  o0.x = f2bf(v0.x * rs * (1.f + w0.x));
  o0.y = f2bf(v0.y * rs * (1.f + w0.y));
  o0.z = f2bf(v0.z * rs * (1.f + w0.z));
  o0.w = f2bf(v0.w * rs * (1.f + w0.w));
  o1.x = f2bf(v1.x * rs * (1.f + w1.x));
  o1.y = f2bf(v1.y * rs * (1.f + w1.y));
  o1.z = f2bf(v1.z * rs * (1.f + w1.z));
  o1.w = f2bf(v1.w * rs * (1.f + w1.w));
  ushort4* xr = (ushort4*)(x + (size_t)row * HIDD);
  xr[t] = o0;
  xr[t + 256] = o1;
}

// ---------------------------------------------------------------------------
// bf16 MFMA GEMM core: C[.,Ndim] = A[.,2048](bf16) * W[.,2048](bf16)^T.
// 128x128 tile, BK=64, 4 waves (2x2), wave tile 64x64, 16x16x32 MFMA.
// Staging via global_load_lds width=16 (linear dest, pre-swizzled source).
// ---------------------------------------------------------------------------
template <int OBF>
__device__ __forceinline__ void gemm_core(const unsigned short* __restrict__ Ab,
                                          const unsigned short* __restrict__ Bb,
                                          void* __restrict__ Cv,
                                          int Ndim, int bm, int bn,
                                          unsigned short* Als, unsigned short* Bls) {
  char* ldsA = (char*)Als;
  char* ldsB = (char*)Bls;

  int t   = threadIdx.x;
  int r15 = t & 15;
  int g   = (t & 63) >> 4;
  int w   = t >> 6;
  int wr  = w >> 1, wc = w & 1;

  f32x4 acc[4][4] = {};

  for (int k0 = 0; k0 < KDIM; k0 += 64) {
    __syncthreads();            // previous iteration's readers done
#pragma unroll
    for (int it = 0; it < 4; ++it) {
      int f      = it * 256 + t;
      int row    = f >> 3;          // 0..127
      int schunk = (f & 7) ^ (row & 7);   // pre-swizzled source chunk
      unsigned ldsbase = (unsigned)((it * 256 + (w << 6)) << 4);  // wave-uniform
      __builtin_amdgcn_global_load_lds(
          (const unsigned int*)(Ab + ((size_t)(bm + row) << 11) + k0 + schunk * 8),
          (unsigned int*)(ldsA + ldsbase), 16, 0, 0);
      __builtin_amdgcn_global_load_lds(
          (const unsigned int*)(Bb + ((size_t)(bn + row) << 11) + k0 + schunk * 8),
          (unsigned int*)(ldsB + ldsbase), 16, 0, 0);
    }
    __syncthreads();

#pragma unroll
    for (int tt = 0; tt < 2; ++tt) {
      bf16x8 af[4], bfv[4];
#pragma unroll
      for (int mi = 0; mi < 4; ++mi) {
        int row = wr * 64 + mi * 16 + r15;
        af[mi] = *(const bf16x8*)(ldsA + row * 128 + (((4 * tt + g) ^ (row & 7)) << 4));
      }
#pragma unroll
      for (int ni = 0; ni < 4; ++ni) {
        int row = wc * 64 + ni * 16 + r15;
        bfv[ni] = *(const bf16x8*)(ldsB + row * 128 + (((4 * tt + g) ^ (row & 7)) << 4));
      }
#pragma unroll
      for (int mi = 0; mi < 4; ++mi)
#pragma unroll
        for (int ni = 0; ni < 4; ++ni)
          acc[mi][ni] = __builtin_amdgcn_mfma_f32_16x16x32_bf16(af[mi], bfv[ni], acc[mi][ni], 0, 0, 0);
    }
  }

  // epilogue: C/D layout col=lane&15, row=(lane>>4)*4+reg
#pragma unroll
  for (int mi = 0; mi < 4; ++mi)
#pragma unroll
    for (int ni = 0; ni < 4; ++ni) {
      int col = bn + wc * 64 + ni * 16 + r15;
#pragma unroll
      for (int r = 0; r < 4; ++r) {
        int rowg = bm + wr * 64 + mi * 16 + g * 4 + r;
        if (OBF)
          ((unsigned short*)Cv)[(size_t)rowg * Ndim + col] = f2bf(acc[mi][ni][r]);
        else
          ((float*)Cv)[(size_t)rowg * Ndim + col] = acc[mi][ni][r];
      }
    }
}

template <int OBF>
__global__ __launch_bounds__(256) void gemm_bf16(const unsigned short* __restrict__ Ab,
                                                 const unsigned short* __restrict__ Bb,
                                                 void* __restrict__ Cv,
                                                 int Ndim) {
  __shared__ unsigned short Als[128 * 64];
  __shared__ unsigned short Bls[128 * 64];
  gemm_core<OBF>(Ab, Bb, Cv, Ndim, blockIdx.y * 128, blockIdx.x * 128, Als, Bls);
}

// K and V GEMMs fused into one dispatch.
__global__ __launch_bounds__(256) void gemm_kv(const unsigned short* __restrict__ Ab,
                                               const unsigned short* __restrict__ Wk,
                                               const unsigned short* __restrict__ Wv,
                                               unsigned short* __restrict__ Ck,
                                               unsigned short* __restrict__ Cva) {
  __shared__ unsigned short Als[128 * 64];
  __shared__ unsigned short Bls[128 * 64];
  int bx = blockIdx.x;
  const unsigned short* Bb = (bx < 4) ? Wk : Wv;
  unsigned short* Cv = (bx < 4) ? Ck : Cva;
  gemm_core<1>(Ab, Bb, (void*)Cv, KV_N, blockIdx.y * 128, (bx & 3) * 128, Als, Bls);
}

// ---------------------------------------------------------------------------
// bf16 MFMA flash attention v3: v2 (swapped QK^T, 128-row q-tile, packed P,
// defer-max) + 2-phase double-buffered K/V staging: issue next tile's
// global_load_lds (K) and global->reg loads (V) BEFORE computing the current
// tile, so load latency hides under QK^T/softmax/PV.  One barrier per tile.
// LDS: K 2x16K + Vt 2x16K + P 16K = 80 KB -> 2 blocks/CU.
// ---------------------------------------------------------------------------
__global__ __launch_bounds__(256, 2) void attn_mfma(const float* __restrict__ qg,
                                                    const unsigned short* __restrict__ kb,
                                                    const unsigned short* __restrict__ vb,
                                                    unsigned short* __restrict__ obuf) {
  __shared__ unsigned short Ks[2][64 * 128];   // [kv][d], chunk^=(kv&7) swizzle
  __shared__ unsigned short Vt[2][64 * 128];   // [d][kv], chunk^=(d&7) swizzle
  __shared__ unsigned short Ps[4][32 * 64];    // per-wave [q][kv], 8B chunk^=(q&15)
  char* ldsK0 = (char*)Ks;
  char* ldsV0 = (char*)Vt;

  int t = threadIdx.x;
  int l = t & 63, w = t >> 6;
  int c15 = l & 15, g = l >> 4;
  char* ldsP = (char*)(Ps[w]);
  int qt = blockIdx.x, h = blockIdx.y, b = blockIdx.z;
  int kh = h >> 2;                          // G = 4
  size_t rowQ0 = (size_t)b * SS + (size_t)qt * 128;
  size_t rowKbase = (size_t)b * SS;

  // Q fragments (B-operand): q row = w*32 + qi*16 + c15, k(d) = g*8 + ks*32 + j
  bf16x8 qf[2][4];
#pragma unroll
  for (int qi = 0; qi < 2; ++qi)
#pragma unroll
    for (int ks = 0; ks < 4; ++ks) {
      int d0 = g * 8 + ks * 32;
      const float* qp = qg + (rowQ0 + w * 32 + qi * 16 + c15) * QG_N + h * HDD + d0;
      float4 a = *(const float4*)qp;
      float4 c = *(const float4*)(qp + 4);
      bf16x8 q8;
      q8[0] = (__bf16)(a.x * SCALE_); q8[1] = (__bf16)(a.y * SCALE_);
      q8[2] = (__bf16)(a.z * SCALE_); q8[3] = (__bf16)(a.w * SCALE_);
      q8[4] = (__bf16)(c.x * SCALE_); q8[5] = (__bf16)(c.y * SCALE_);
      q8[6] = (__bf16)(c.z * SCALE_); q8[7] = (__bf16)(c.w * SCALE_);
      qf[qi][ks] = q8;
    }

  f32x4 accO[2][8] = {};
  float mrun[2] = {-INFINITY, -INFINITY};
  float lrun[2] = {0.f, 0.f};
  u16x8 vreg[4];                 // V tile in flight (regs)

  // ---- staging helpers (macros keep addressing identical across sites) ----
#define ISSUE_K(bufi, kt_)                                                     \
  {                                                                            \
    size_t rowK0 = rowKbase + (size_t)(kt_) * 64;                              \
    _Pragma("unroll")                                                          \
    for (int it = 0; it < 4; ++it) {                                           \
      int f = it * 256 + t;                                                    \
      int kv = f >> 4;                                                         \
      int schunk = (f & 15) ^ (kv & 7);                                        \
      unsigned ldsbase = (unsigned)((it * 256 + (w << 6)) << 4);               \
      __builtin_amdgcn_global_load_lds(                                        \
          (const unsigned int*)(kb + (rowK0 + kv) * KV_N + kh * HDD + schunk * 8), \
          (unsigned int*)(ldsK0 + (bufi) * 16384 + ldsbase), 16, 0, 0);        \
    }                                                                          \
  }
#define ISSUE_V(kt_)                                                           \
  {                                                                            \
    size_t rowK0 = rowKbase + (size_t)(kt_) * 64;                              \
    _Pragma("unroll")                                                          \
    for (int it = 0; it < 4; ++it) {                                           \
      int f = it * 256 + t;                                                    \
      int kv = f & 63;                                                         \
      int d8 = (f >> 6) * 8;                                                   \
      vreg[it] = *(const u16x8*)(vb + (rowK0 + kv) * KV_N + kh * HDD + d8);    \
    }                                                                          \
  }
#define WRITE_V(bufi)                                                          \
  {                                                                            \
    _Pragma("unroll")                                                          \
    for (int it = 0; it < 4; ++it) {                                           \
      int f = it * 256 + t;                                                    \
      int kv = f & 63;                                                         \
      int d8 = (f >> 6) * 8;                                                   \
      _Pragma("unroll")                                                        \
      for (int i = 0; i < 8; ++i) {                                            \
        int d = d8 + i;                                                        \
        *(unsigned short*)(ldsV0 + (bufi) * 16384 + d * 128 +                  \
                           (((kv >> 3) ^ (d & 7)) << 4) + (kv & 7) * 2) = vreg[it][i]; \
      }                                                                        \
    }                                                                          \
  }

  // ---- prologue: stage tile 0 into buffer 0 ----
  ISSUE_K(0, 0);
  ISSUE_V(0);
  asm volatile("s_waitcnt vmcnt(0)" ::: "memory");
  WRITE_V(0);
  __syncthreads();

  const int NT = SS / 64;
  for (int kt = 0; kt < NT; ++kt) {
    int cur = kt & 1, nxt = cur ^ 1;
    char* ldsK = ldsK0 + cur * 16384;
    char* ldsV = ldsV0 + cur * 16384;

    // prefetch next tile (K direct-to-LDS, V to regs)
    if (kt + 1 < NT) {
      ISSUE_K(nxt, kt + 1);
      ISSUE_V(kt + 1);
    }

    // S^T = K Q : 32 MFMA.  accS[qi][nf]: col=c15=q, row=kv=nf*16+g*4+r
    f32x4 accS[2][4] = {};
#pragma unroll
    for (int nf = 0; nf < 4; ++nf) {
      int kvr = nf * 16 + c15;
#pragma unroll
      for (int ks = 0; ks < 4; ++ks) {
        bf16x8 kf = *(const bf16x8*)(ldsK + kvr * 256 + ((((g + 4 * ks) ^ (kvr & 7)) << 4)));
#pragma unroll
        for (int qi = 0; qi < 2; ++qi)
          accS[qi][nf] = __builtin_amdgcn_mfma_f32_16x16x32_bf16(kf, qf[qi][ks], accS[qi][nf], 0, 0, 0);
      }
    }

    // per-lane tile max over own q-column, reduce over 4 kv-groups
    float mt[2];
#pragma unroll
    for (int qi = 0; qi < 2; ++qi) {
      float m0 = fmaxf(fmaxf(accS[qi][0][0], accS[qi][0][1]), fmaxf(accS[qi][0][2], accS[qi][0][3]));
#pragma unroll
      for (int nf = 1; nf < 4; ++nf)
        m0 = fmaxf(m0, fmaxf(fmaxf(accS[qi][nf][0], accS[qi][nf][1]), fmaxf(accS[qi][nf][2], accS[qi][nf][3])));
      m0 = fmaxf(m0, __shfl_xor(m0, 16, 64));
      m0 = fmaxf(m0, __shfl_xor(m0, 32, 64));
      mt[qi] = m0;
    }

    // defer-max: skip rescale when wave-uniformly safe (bounded by e^8)
    bool safe = (mt[0] <= mrun[0] + 8.f) && (mt[1] <= mrun[1] + 8.f);
    if (!__all(safe)) {
#pragma unroll
      for (int qi = 0; qi < 2; ++qi) {
        float mnew = fmaxf(mrun[qi], mt[qi]);
        float al = __expf(mrun[qi] - mnew);   // first tile: exp(-inf)=0
        mrun[qi] = mnew;
        lrun[qi] *= al;
        float alr[4];
#pragma unroll
        for (int r = 0; r < 4; ++r) alr[r] = __shfl(al, g * 4 + r, 16);
#pragma unroll
        for (int df = 0; df < 8; ++df)
#pragma unroll
          for (int r = 0; r < 4; ++r) accO[qi][df][r] *= alr[r];
      }
    }

    // P = exp(S - m), accumulate row-sum, pack 4 kv -> b64 store
#pragma unroll
    for (int qi = 0; qi < 2; ++qi) {
      float ps = 0.f;
#pragma unroll
      for (int nf = 0; nf < 4; ++nf) {
        float p0 = __expf(accS[qi][nf][0] - mrun[qi]);
        float p1 = __expf(accS[qi][nf][1] - mrun[qi]);
        float p2 = __expf(accS[qi][nf][2] - mrun[qi]);
        float p3 = __expf(accS[qi][nf][3] - mrun[qi]);
        ps += (p0 + p1) + (p2 + p3);
        ushort4 pk;
        pk.x = f2bf(p0); pk.y = f2bf(p1); pk.z = f2bf(p2); pk.w = f2bf(p3);
        int q = qi * 16 + c15;
        *(ushort4*)(ldsP + q * 128 + ((((nf << 2) + g) ^ (q & 15)) << 3)) = pk;
      }
      ps += __shfl_xor(ps, 16, 64);
      ps += __shfl_xor(ps, 32, 64);
      lrun[qi] += ps;
    }
    asm volatile("s_waitcnt lgkmcnt(0)" ::: "memory");  // own-wave P writes done

    // O += P V : 32 MFMA.  A = P[q][kv] (own wave), B = Vt[d][kv]
#pragma unroll
    for (int ks2 = 0; ks2 < 2; ++ks2) {
      bf16x8 pf[2];
#pragma unroll
      for (int qi = 0; qi < 2; ++qi) {
        int q = qi * 16 + c15;
        int ch0 = ((ks2 << 3) + (g << 1)) ^ (q & 15);
        int ch1 = ((ks2 << 3) + (g << 1) + 1) ^ (q & 15);
        ushort4 lo = *(const ushort4*)(ldsP + q * 128 + (ch0 << 3));
        ushort4 hi = *(const ushort4*)(ldsP + q * 128 + (ch1 << 3));
        u16x8 p8 = {lo.x, lo.y, lo.z, lo.w, hi.x, hi.y, hi.z, hi.w};
        pf[qi] = __builtin_bit_cast(bf16x8, p8);
      }
#pragma unroll
      for (int df = 0; df < 8; ++df) {
        int d = df * 16 + c15;
        bf16x8 vf = *(const bf16x8*)(ldsV + d * 128 + ((((g + 4 * ks2) ^ (d & 7)) << 4)));
#pragma unroll
        for (int qi = 0; qi < 2; ++qi)
          accO[qi][df] = __builtin_amdgcn_mfma_f32_16x16x32_bf16(pf[qi], vf, accO[qi][df], 0, 0, 0);
      }
    }

    // drain prefetch loads, commit V tile kt+1 into next buffer
    if (kt + 1 < NT) {
      asm volatile("s_waitcnt vmcnt(0)" ::: "memory");
      WRITE_V(nxt);
    }
    __syncthreads();
  }

  // epilogue: normalize (invL via shfl), sigmoid-gate, bf16 store
#pragma unroll
  for (int qi = 0; qi < 2; ++qi) {
    float invL = 1.f / lrun[qi];
    float ivr[4];
#pragma unroll
    for (int r = 0; r < 4; ++r) ivr[r] = __shfl(invL, g * 4 + r, 16);
#pragma unroll
    for (int r = 0; r < 4; ++r) {
      size_t row = rowQ0 + w * 32 + qi * 16 + g * 4 + r;
#pragma unroll
      for (int df = 0; df < 8; ++df) {
        int d = df * 16 + c15;
        float gt = qg[row * QG_N + O_N + h * HDD + d];
        float sg = 1.f / (1.f + __expf(-gt));
        obuf[row * (size_t)O_N + h * HDD + d] = f2bf(accO[qi][df][r] * ivr[r] * sg);
      }
    }
  }
#undef ISSUE_K
#undef ISSUE_V
#undef WRITE_V
}

// ---------------------------------------------------------------------------
// Launch
// ---------------------------------------------------------------------------
extern "C" void kernel_launch(void* const* d_in, const int* in_sizes, int n_in,
                              void* d_out, int out_size, void* d_ws, size_t ws_size,
                              hipStream_t stream) {
  const float* hs = (const float*)d_in[0];
  // d_in[1] = position_ids (unused by the reference)
  const float* Wq = (const float*)d_in[2];
  const float* Wk = (const float*)d_in[3];
  const float* Wv = (const float*)d_in[4];
  const float* Wo = (const float*)d_in[5];
  const float* nw = (const float*)d_in[6];
  float* out = (float*)d_out;

  // workspace (~138 MB): qgb fp32 | bf16: kb,vb,x,ob,Wq,Wk,Wv,Wo
  float* qgb = (float*)d_ws;
  unsigned short* kb16 = (unsigned short*)(qgb + (size_t)MROWS * QG_N);
  unsigned short* vb16 = kb16 + (size_t)MROWS * KV_N;
  unsigned short* xb   = vb16 + (size_t)MROWS * KV_N;
  unsigned short* ob   = xb   + (size_t)MROWS * HIDD;
  unsigned short* wqb  = ob   + (size_t)MROWS * O_N;
  unsigned short* wkb  = wqb  + (size_t)QG_N * KDIM;
  unsigned short* wvb  = wkb  + (size_t)KV_N * KDIM;
  unsigned short* wob  = wvb  + (size_t)KV_N * KDIM;

  f2bf_k<<<(QG_N*KDIM/4 + 255)/256, 256, 0, stream>>>(Wq, wqb, QG_N*KDIM/4);
  f2bf_k<<<(KV_N*KDIM/4 + 255)/256, 256, 0, stream>>>(Wk, wkb, KV_N*KDIM/4);
  f2bf_k<<<(KV_N*KDIM/4 + 255)/256, 256, 0, stream>>>(Wv, wvb, KV_N*KDIM/4);
  f2bf_k<<<(O_N*KDIM/4  + 255)/256, 256, 0, stream>>>(Wo, wob, O_N*KDIM/4);
  rmsnorm_k<<<MROWS, 256, 0, stream>>>(hs, nw, xb);

  gemm_bf16<0><<<dim3(QG_N/128, MROWS/128), 256, 0, stream>>>(xb, wqb, qgb, QG_N);
  gemm_kv<<<dim3(8, MROWS/128), 256, 0, stream>>>(xb, wkb, wvb, kb16, vb16);
  attn_mfma<<<dim3(SS/128, NHH, BB), 256, 0, stream>>>(qgb, kb16, vb16, ob);
  gemm_bf16<0><<<dim3(O_N/128, MROWS/128), 256, 0, stream>>>(ob, wob, out, O_N);
}

// Round 9
// 292.309 us; speedup vs baseline: 6.3666x; 1.0136x over previous
//
#include <hip/hip_runtime.h>
#include <math.h>

// Problem constants (from reference)
#define BB    2
#define SS    2048
#define HIDD  2048
#define NHH   16
#define NKVV  4
#define HDD   128
#define MROWS 4096            // B*S
#define QG_N  4096            // 2*NH*HD
#define KV_N  512             // NKV*HD
#define O_N   2048            // NH*HD
#define KDIM  2048            // shared K for all four GEMMs (row stride of A and W)
#define EPS_  1e-6f
#define SCALE_ 0.08838834764831845f   // 1/sqrt(128)

typedef __attribute__((ext_vector_type(8))) __bf16 bf16x8;
typedef __attribute__((ext_vector_type(8))) unsigned short u16x8;
typedef __attribute__((ext_vector_type(4))) float f32x4;

__device__ __forceinline__ unsigned short f2bf(float f) {
  return __builtin_bit_cast(unsigned short, (__bf16)f);   // RNE via v_cvt
}

// ---------------------------------------------------------------------------
// fp32 -> bf16 convert, 4 elems/thread
// ---------------------------------------------------------------------------
__global__ __launch_bounds__(256) void f2bf_k(const float* __restrict__ in,
                                              unsigned short* __restrict__ out, int n4) {
  int i = blockIdx.x * 256 + threadIdx.x;
  if (i < n4) {
    float4 v = ((const float4*)in)[i];
    ushort4 u;
    u.x = f2bf(v.x); u.y = f2bf(v.y); u.z = f2bf(v.z); u.w = f2bf(v.w);
    ((ushort4*)out)[i] = u;
  }
}

// ---------------------------------------------------------------------------
// RMSNorm -> bf16 x.  One block per row.
// ---------------------------------------------------------------------------
__global__ __launch_bounds__(256) void rmsnorm_k(const float* __restrict__ h,
                                                 const float* __restrict__ w,
                                                 unsigned short* __restrict__ x) {
  int row = blockIdx.x;
  int t = threadIdx.x;
  const float4* hr = (const float4*)(h + (size_t)row * HIDD);
  const float4* w4 = (const float4*)w;

  float4 v0 = hr[t], v1 = hr[t + 256];
  float ss = v0.x*v0.x + v0.y*v0.y + v0.z*v0.z + v0.w*v0.w
           + v1.x*v1.x + v1.y*v1.y + v1.z*v1.z + v1.w*v1.w;
#pragma unroll
  for (int off = 32; off > 0; off >>= 1) ss += __shfl_down(ss, off, 64);

  __shared__ float part[4];
  __shared__ float rs_sh;
  if ((t & 63) == 0) part[t >> 6] = ss;
  __syncthreads();
  if (t == 0) rs_sh = rsqrtf((part[0]+part[1]+part[2]+part[3]) * (1.0f/HIDD) + EPS_);
  __syncthreads();
  float rs = rs_sh;

  float4 w0 = w4[t], w1 = w4[t + 256];
  ushort4 o0, o1;
  o0.x = f2bf(v0.x * rs * (1.f + w0.x));
  o0.y = f2bf(v0.y * rs * (1.f + w0.y));
  o0.z = f2bf(v0.z * rs * (1.f + w0.z));
  o0.w = f2bf(v0.w * rs * (1.f + w0.w));
  o1.x = f2bf(v1.x * rs * (1.f + w1.x));
  o1.y = f2bf(v1.y * rs * (1.f + w1.y));
  o1.z = f2bf(v1.z * rs * (1.f + w1.z));
  o1.w = f2bf(v1.w * rs * (1.f + w1.w));
  ushort4* xr = (ushort4*)(x + (size_t)row * HIDD);
  xr[t] = o0;
  xr[t + 256] = o1;
}

// ---------------------------------------------------------------------------
// bf16 MFMA GEMM core: C[.,Ndim] = A[.,2048](bf16) * W[.,2048](bf16)^T.
// 128x128 tile, BK=64, 4 waves (2x2), wave tile 64x64, 16x16x32 MFMA.
// Staging via global_load_lds width=16 (linear dest, pre-swizzled source).
// OBF: 0 = fp32 out, 1 = bf16 out, 2 = QG split (cols<2048 -> bf16*SCALE to
// Cv; cols>=2048 -> fp32 to Cv2; both row-stride 2048).
// ---------------------------------------------------------------------------
template <int OBF>
__device__ __forceinline__ void gemm_core(const unsigned short* __restrict__ Ab,
                                          const unsigned short* __restrict__ Bb,
                                          void* __restrict__ Cv,
                                          void* __restrict__ Cv2,
                                          int Ndim, int bm, int bn,
                                          unsigned short* Als, unsigned short* Bls) {
  char* ldsA = (char*)Als;
  char* ldsB = (char*)Bls;

  int t   = threadIdx.x;
  int r15 = t & 15;
  int g   = (t & 63) >> 4;
  int w   = t >> 6;
  int wr  = w >> 1, wc = w & 1;

  f32x4 acc[4][4] = {};

  for (int k0 = 0; k0 < KDIM; k0 += 64) {
    __syncthreads();            // previous iteration's readers done
#pragma unroll
    for (int it = 0; it < 4; ++it) {
      int f      = it * 256 + t;
      int row    = f >> 3;          // 0..127
      int schunk = (f & 7) ^ (row & 7);   // pre-swizzled source chunk
      unsigned ldsbase = (unsigned)((it * 256 + (w << 6)) << 4);  // wave-uniform
      __builtin_amdgcn_global_load_lds(
          (const unsigned int*)(Ab + ((size_t)(bm + row) << 11) + k0 + schunk * 8),
          (unsigned int*)(ldsA + ldsbase), 16, 0, 0);
      __builtin_amdgcn_global_load_lds(
          (const unsigned int*)(Bb + ((size_t)(bn + row) << 11) + k0 + schunk * 8),
          (unsigned int*)(ldsB + ldsbase), 16, 0, 0);
    }
    __syncthreads();

#pragma unroll
    for (int tt = 0; tt < 2; ++tt) {
      bf16x8 af[4], bfv[4];
#pragma unroll
      for (int mi = 0; mi < 4; ++mi) {
        int row = wr * 64 + mi * 16 + r15;
        af[mi] = *(const bf16x8*)(ldsA + row * 128 + (((4 * tt + g) ^ (row & 7)) << 4));
      }
#pragma unroll
      for (int ni = 0; ni < 4; ++ni) {
        int row = wc * 64 + ni * 16 + r15;
        bfv[ni] = *(const bf16x8*)(ldsB + row * 128 + (((4 * tt + g) ^ (row & 7)) << 4));
      }
      __builtin_amdgcn_s_setprio(1);
#pragma unroll
      for (int mi = 0; mi < 4; ++mi)
#pragma unroll
        for (int ni = 0; ni < 4; ++ni)
          acc[mi][ni] = __builtin_amdgcn_mfma_f32_16x16x32_bf16(af[mi], bfv[ni], acc[mi][ni], 0, 0, 0);
      __builtin_amdgcn_s_setprio(0);
    }
  }

  // epilogue: C/D layout col=lane&15, row=(lane>>4)*4+reg
#pragma unroll
  for (int mi = 0; mi < 4; ++mi)
#pragma unroll
    for (int ni = 0; ni < 4; ++ni) {
      int col = bn + wc * 64 + ni * 16 + r15;
#pragma unroll
      for (int r = 0; r < 4; ++r) {
        int rowg = bm + wr * 64 + mi * 16 + g * 4 + r;
        if (OBF == 1)
          ((unsigned short*)Cv)[(size_t)rowg * Ndim + col] = f2bf(acc[mi][ni][r]);
        else if (OBF == 2) {
          if (col < O_N)      // q half: bf16, SCALE folded (same op attn did)
            ((unsigned short*)Cv)[(size_t)rowg * O_N + col] = f2bf(acc[mi][ni][r] * SCALE_);
          else                // gate half: fp32
            ((float*)Cv2)[(size_t)rowg * O_N + (col - O_N)] = acc[mi][ni][r];
        } else
          ((float*)Cv)[(size_t)rowg * Ndim + col] = acc[mi][ni][r];
      }
    }
}

template <int OBF>
__global__ __launch_bounds__(256) void gemm_bf16(const unsigned short* __restrict__ Ab,
                                                 const unsigned short* __restrict__ Bb,
                                                 void* __restrict__ Cv,
                                                 int Ndim) {
  __shared__ unsigned short Als[128 * 64];
  __shared__ unsigned short Bls[128 * 64];
  gemm_core<OBF>(Ab, Bb, Cv, nullptr, Ndim, blockIdx.y * 128, blockIdx.x * 128, Als, Bls);
}

// QG GEMM: q half -> bf16 (SCALE folded), gate half -> fp32.
__global__ __launch_bounds__(256) void gemm_qg(const unsigned short* __restrict__ Ab,
                                               const unsigned short* __restrict__ Bb,
                                               unsigned short* __restrict__ Cq,
                                               float* __restrict__ Cg) {
  __shared__ unsigned short Als[128 * 64];
  __shared__ unsigned short Bls[128 * 64];
  gemm_core<2>(Ab, Bb, (void*)Cq, (void*)Cg, QG_N, blockIdx.y * 128, blockIdx.x * 128, Als, Bls);
}

// K and V GEMMs fused into one dispatch.
__global__ __launch_bounds__(256) void gemm_kv(const unsigned short* __restrict__ Ab,
                                               const unsigned short* __restrict__ Wk,
                                               const unsigned short* __restrict__ Wv,
                                               unsigned short* __restrict__ Ck,
                                               unsigned short* __restrict__ Cva) {
  __shared__ unsigned short Als[128 * 64];
  __shared__ unsigned short Bls[128 * 64];
  int bx = blockIdx.x;
  const unsigned short* Bb = (bx < 4) ? Wk : Wv;
  unsigned short* Cv = (bx < 4) ? Ck : Cva;
  gemm_core<1>(Ab, Bb, (void*)Cv, nullptr, KV_N, blockIdx.y * 128, (bx & 3) * 128, Als, Bls);
}

// ---------------------------------------------------------------------------
// bf16 MFMA flash attention v4 = v3 + setprio around MFMA clusters +
// XCD-chunked grid swizzle (one (b,kh) KV set per XCD -> KV L2-resident) +
// pre-scaled bf16 Q input / fp32 gate input (bit-identical math).
// Block = 256 thr = 4 waves; 1-D grid 512.  LDS 80 KB -> 2 blocks/CU.
// ---------------------------------------------------------------------------
__global__ __launch_bounds__(256, 2) void attn_mfma(const unsigned short* __restrict__ qb,
                                                    const float* __restrict__ gateb,
                                                    const unsigned short* __restrict__ kb,
                                                    const unsigned short* __restrict__ vb,
                                                    unsigned short* __restrict__ obuf) {
  __shared__ unsigned short Ks[2][64 * 128];   // [kv][d], chunk^=(kv&7) swizzle
  __shared__ unsigned short Vt[2][64 * 128];   // [d][kv], chunk^=(d&7) swizzle
  __shared__ unsigned short Ps[4][32 * 64];    // per-wave [q][kv], 8B chunk^=(q&15)
  char* ldsK0 = (char*)Ks;
  char* ldsV0 = (char*)Vt;

  int t = threadIdx.x;
  int l = t & 63, w = t >> 6;
  int c15 = l & 15, g = l >> 4;
  char* ldsP = (char*)(Ps[w]);
  // XCD-chunked swizzle: 512 blocks, 8 XCDs -> XCD c owns swz [c*64, c*64+63]
  // = all 16 qt x one kh group x one b  => its 1 MB K/V set is L2-resident.
  int bid = blockIdx.x;
  int swz = (bid & 7) * 64 + (bid >> 3);
  int qt = swz & 15, h = (swz >> 4) & 15, b = swz >> 8;
  int kh = h >> 2;                          // G = 4
  size_t rowQ0 = (size_t)b * SS + (size_t)qt * 128;
  size_t rowKbase = (size_t)b * SS;

  // Q fragments (B-operand), pre-scaled bf16: q row = w*32 + qi*16 + c15,
  // k(d) = g*8 + ks*32 + j  -> one 16B load per frag
  bf16x8 qf[2][4];
#pragma unroll
  for (int qi = 0; qi < 2; ++qi)
#pragma unroll
    for (int ks = 0; ks < 4; ++ks)
      qf[qi][ks] = *(const bf16x8*)(qb + (rowQ0 + w * 32 + qi * 16 + c15) * O_N
                                       + h * HDD + g * 8 + ks * 32);

  f32x4 accO[2][8] = {};
  float mrun[2] = {-INFINITY, -INFINITY};
  float lrun[2] = {0.f, 0.f};
  u16x8 vreg[4];                 // V tile in flight (regs)

  // ---- staging helpers (macros keep addressing identical across sites) ----
#define ISSUE_K(bufi, kt_)                                                     \
  {                                                                            \
    size_t rowK0 = rowKbase + (size_t)(kt_) * 64;                              \
    _Pragma("unroll")                                                          \
    for (int it = 0; it < 4; ++it) {                                           \
      int f = it * 256 + t;                                                    \
      int kv = f >> 4;                                                         \
      int schunk = (f & 15) ^ (kv & 7);                                        \
      unsigned ldsbase = (unsigned)((it * 256 + (w << 6)) << 4);               \
      __builtin_amdgcn_global_load_lds(                                        \
          (const unsigned int*)(kb + (rowK0 + kv) * KV_N + kh * HDD + schunk * 8), \
          (unsigned int*)(ldsK0 + (bufi) * 16384 + ldsbase), 16, 0, 0);        \
    }                                                                          \
  }
#define ISSUE_V(kt_)                                                           \
  {                                                                            \
    size_t rowK0 = rowKbase + (size_t)(kt_) * 64;                              \
    _Pragma("unroll")                                                          \
    for (int it = 0; it < 4; ++it) {                                           \
      int f = it * 256 + t;                                                    \
      int kv = f & 63;                                                         \
      int d8 = (f >> 6) * 8;                                                   \
      vreg[it] = *(const u16x8*)(vb + (rowK0 + kv) * KV_N + kh * HDD + d8);    \
    }                                                                          \
  }
#define WRITE_V(bufi)                                                          \
  {                                                                            \
    _Pragma("unroll")                                                          \
    for (int it = 0; it < 4; ++it) {                                           \
      int f = it * 256 + t;                                                    \
      int kv = f & 63;                                                         \
      int d8 = (f >> 6) * 8;                                                   \
      _Pragma("unroll")                                                        \
      for (int i = 0; i < 8; ++i) {                                            \
        int d = d8 + i;                                                        \
        *(unsigned short*)(ldsV0 + (bufi) * 16384 + d * 128 +                  \
                           (((kv >> 3) ^ (d & 7)) << 4) + (kv & 7) * 2) = vreg[it][i]; \
      }                                                                        \
    }                                                                          \
  }

  // ---- prologue: stage tile 0 into buffer 0 ----
  ISSUE_K(0, 0);
  ISSUE_V(0);
  asm volatile("s_waitcnt vmcnt(0)" ::: "memory");
  WRITE_V(0);
  __syncthreads();

  const int NT = SS / 64;
  for (int kt = 0; kt < NT; ++kt) {
    int cur = kt & 1, nxt = cur ^ 1;
    char* ldsK = ldsK0 + cur * 16384;
    char* ldsV = ldsV0 + cur * 16384;

    // prefetch next tile (K direct-to-LDS, V to regs)
    if (kt + 1 < NT) {
      ISSUE_K(nxt, kt + 1);
      ISSUE_V(kt + 1);
    }

    // S^T = K Q : 32 MFMA.  accS[qi][nf]: col=c15=q, row=kv=nf*16+g*4+r
    f32x4 accS[2][4] = {};
    __builtin_amdgcn_s_setprio(1);
#pragma unroll
    for (int nf = 0; nf < 4; ++nf) {
      int kvr = nf * 16 + c15;
#pragma unroll
      for (int ks = 0; ks < 4; ++ks) {
        bf16x8 kf = *(const bf16x8*)(ldsK + kvr * 256 + ((((g + 4 * ks) ^ (kvr & 7)) << 4)));
#pragma unroll
        for (int qi = 0; qi < 2; ++qi)
          accS[qi][nf] = __builtin_amdgcn_mfma_f32_16x16x32_bf16(kf, qf[qi][ks], accS[qi][nf], 0, 0, 0);
      }
    }
    __builtin_amdgcn_s_setprio(0);

    // per-lane tile max over own q-column, reduce over 4 kv-groups
    float mt[2];
#pragma unroll
    for (int qi = 0; qi < 2; ++qi) {
      float m0 = fmaxf(fmaxf(accS[qi][0][0], accS[qi][0][1]), fmaxf(accS[qi][0][2], accS[qi][0][3]));
#pragma unroll
      for (int nf = 1; nf < 4; ++nf)
        m0 = fmaxf(m0, fmaxf(fmaxf(accS[qi][nf][0], accS[qi][nf][1]), fmaxf(accS[qi][nf][2], accS[qi][nf][3])));
      m0 = fmaxf(m0, __shfl_xor(m0, 16, 64));
      m0 = fmaxf(m0, __shfl_xor(m0, 32, 64));
      mt[qi] = m0;
    }

    // defer-max: skip rescale when wave-uniformly safe (bounded by e^8)
    bool safe = (mt[0] <= mrun[0] + 8.f) && (mt[1] <= mrun[1] + 8.f);
    if (!__all(safe)) {
#pragma unroll
      for (int qi = 0; qi < 2; ++qi) {
        float mnew = fmaxf(mrun[qi], mt[qi]);
        float al = __expf(mrun[qi] - mnew);   // first tile: exp(-inf)=0
        mrun[qi] = mnew;
        lrun[qi] *= al;
        float alr[4];
#pragma unroll
        for (int r = 0; r < 4; ++r) alr[r] = __shfl(al, g * 4 + r, 16);
#pragma unroll
        for (int df = 0; df < 8; ++df)
#pragma unroll
          for (int r = 0; r < 4; ++r) accO[qi][df][r] *= alr[r];
      }
    }

    // P = exp(S - m), accumulate row-sum, pack 4 kv -> b64 store
#pragma unroll
    for (int qi = 0; qi < 2; ++qi) {
      float ps = 0.f;
#pragma unroll
      for (int nf = 0; nf < 4; ++nf) {
        float p0 = __expf(accS[qi][nf][0] - mrun[qi]);
        float p1 = __expf(accS[qi][nf][1] - mrun[qi]);
        float p2 = __expf(accS[qi][nf][2] - mrun[qi]);
        float p3 = __expf(accS[qi][nf][3] - mrun[qi]);
        ps += (p0 + p1) + (p2 + p3);
        ushort4 pk;
        pk.x = f2bf(p0); pk.y = f2bf(p1); pk.z = f2bf(p2); pk.w = f2bf(p3);
        int q = qi * 16 + c15;
        *(ushort4*)(ldsP + q * 128 + ((((nf << 2) + g) ^ (q & 15)) << 3)) = pk;
      }
      ps += __shfl_xor(ps, 16, 64);
      ps += __shfl_xor(ps, 32, 64);
      lrun[qi] += ps;
    }
    asm volatile("s_waitcnt lgkmcnt(0)" ::: "memory");  // own-wave P writes done

    // O += P V : 32 MFMA.  A = P[q][kv] (own wave), B = Vt[d][kv]
    __builtin_amdgcn_s_setprio(1);
#pragma unroll
    for (int ks2 = 0; ks2 < 2; ++ks2) {
      bf16x8 pf[2];
#pragma unroll
      for (int qi = 0; qi < 2; ++qi) {
        int q = qi * 16 + c15;
        int ch0 = ((ks2 << 3) + (g << 1)) ^ (q & 15);
        int ch1 = ((ks2 << 3) + (g << 1) + 1) ^ (q & 15);
        ushort4 lo = *(const ushort4*)(ldsP + q * 128 + (ch0 << 3));
        ushort4 hi = *(const ushort4*)(ldsP + q * 128 + (ch1 << 3));
        u16x8 p8 = {lo.x, lo.y, lo.z, lo.w, hi.x, hi.y, hi.z, hi.w};
        pf[qi] = __builtin_bit_cast(bf16x8, p8);
      }
#pragma unroll
      for (int df = 0; df < 8; ++df) {
        int d = df * 16 + c15;
        bf16x8 vf = *(const bf16x8*)(ldsV + d * 128 + ((((g + 4 * ks2) ^ (d & 7)) << 4)));
#pragma unroll
        for (int qi = 0; qi < 2; ++qi)
          accO[qi][df] = __builtin_amdgcn_mfma_f32_16x16x32_bf16(pf[qi], vf, accO[qi][df], 0, 0, 0);
      }
    }
    __builtin_amdgcn_s_setprio(0);

    // drain prefetch loads, commit V tile kt+1 into next buffer
    if (kt + 1 < NT) {
      asm volatile("s_waitcnt vmcnt(0)" ::: "memory");
      WRITE_V(nxt);
    }
    __syncthreads();
  }

  // epilogue: normalize (invL via shfl), sigmoid-gate, bf16 store
#pragma unroll
  for (int qi = 0; qi < 2; ++qi) {
    float invL = 1.f / lrun[qi];
    float ivr[4];
#pragma unroll
    for (int r = 0; r < 4; ++r) ivr[r] = __shfl(invL, g * 4 + r, 16);
#pragma unroll
    for (int r = 0; r < 4; ++r) {
      size_t row = rowQ0 + w * 32 + qi * 16 + g * 4 + r;
#pragma unroll
      for (int df = 0; df < 8; ++df) {
        int d = df * 16 + c15;
        float gt = gateb[row * (size_t)O_N + h * HDD + d];
        float sg = 1.f / (1.f + __expf(-gt));
        obuf[row * (size_t)O_N + h * HDD + d] = f2bf(accO[qi][df][r] * ivr[r] * sg);
      }
    }
  }
#undef ISSUE_K
#undef ISSUE_V
#undef WRITE_V
}

// ---------------------------------------------------------------------------
// Launch
// ---------------------------------------------------------------------------
extern "C" void kernel_launch(void* const* d_in, const int* in_sizes, int n_in,
                              void* d_out, int out_size, void* d_ws, size_t ws_size,
                              hipStream_t stream) {
  const float* hs = (const float*)d_in[0];
  // d_in[1] = position_ids (unused by the reference)
  const float* Wq = (const float*)d_in[2];
  const float* Wk = (const float*)d_in[3];
  const float* Wv = (const float*)d_in[4];
  const float* Wo = (const float*)d_in[5];
  const float* nw = (const float*)d_in[6];
  float* out = (float*)d_out;

  // workspace (~121 MB): gate fp32 | bf16: qb,kb,vb,x,ob,Wq,Wk,Wv,Wo
  float* gateb = (float*)d_ws;                                   // 33.5 MB
  unsigned short* qb16 = (unsigned short*)(gateb + (size_t)MROWS * O_N);  // 16.8 MB
  unsigned short* kb16 = qb16 + (size_t)MROWS * O_N;
  unsigned short* vb16 = kb16 + (size_t)MROWS * KV_N;
  unsigned short* xb   = vb16 + (size_t)MROWS * KV_N;
  unsigned short* ob   = xb   + (size_t)MROWS * HIDD;
  unsigned short* wqb  = ob   + (size_t)MROWS * O_N;
  unsigned short* wkb  = wqb  + (size_t)QG_N * KDIM;
  unsigned short* wvb  = wkb  + (size_t)KV_N * KDIM;
  unsigned short* wob  = wvb  + (size_t)KV_N * KDIM;

  f2bf_k<<<(QG_N*KDIM/4 + 255)/256, 256, 0, stream>>>(Wq, wqb, QG_N*KDIM/4);
  f2bf_k<<<(KV_N*KDIM/4 + 255)/256, 256, 0, stream>>>(Wk, wkb, KV_N*KDIM/4);
  f2bf_k<<<(KV_N*KDIM/4 + 255)/256, 256, 0, stream>>>(Wv, wvb, KV_N*KDIM/4);
  f2bf_k<<<(O_N*KDIM/4  + 255)/256, 256, 0, stream>>>(Wo, wob, O_N*KDIM/4);
  rmsnorm_k<<<MROWS, 256, 0, stream>>>(hs, nw, xb);

  gemm_qg<<<dim3(QG_N/128, MROWS/128), 256, 0, stream>>>(xb, wqb, qb16, gateb);
  gemm_kv<<<dim3(8, MROWS/128), 256, 0, stream>>>(xb, wkb, wvb, kb16, vb16);
  attn_mfma<<<dim3(512), 256, 0, stream>>>(qb16, gateb, kb16, vb16, ob);
  gemm_bf16<0><<<dim3(O_N/128, MROWS/128), 256, 0, stream>>>(ob, wob, out, O_N);
}

// Round 10
// 286.335 us; speedup vs baseline: 6.4995x; 1.0209x over previous
//
#include <hip/hip_runtime.h>
#include <math.h>

// Problem constants (from reference)
#define BB    2
#define SS    2048
#define HIDD  2048
#define NHH   16
#define NKVV  4
#define HDD   128
#define MROWS 4096            // B*S
#define QG_N  4096            // 2*NH*HD
#define KV_N  512             // NKV*HD
#define O_N   2048            // NH*HD
#define KDIM  2048            // shared K for all four GEMMs (row stride of A and W)
#define EPS_  1e-6f
#define SCALE_ 0.08838834764831845f   // 1/sqrt(128)

typedef __attribute__((ext_vector_type(8))) __bf16 bf16x8;
typedef __attribute__((ext_vector_type(8))) unsigned short u16x8;
typedef __attribute__((ext_vector_type(4))) float f32x4;

__device__ __forceinline__ unsigned short f2bf(float f) {
  return __builtin_bit_cast(unsigned short, (__bf16)f);   // RNE via v_cvt
}

// ---------------------------------------------------------------------------
// fp32 -> bf16 convert, 4 elems/thread
// ---------------------------------------------------------------------------
__global__ __launch_bounds__(256) void f2bf_k(const float* __restrict__ in,
                                              unsigned short* __restrict__ out, int n4) {
  int i = blockIdx.x * 256 + threadIdx.x;
  if (i < n4) {
    float4 v = ((const float4*)in)[i];
    ushort4 u;
    u.x = f2bf(v.x); u.y = f2bf(v.y); u.z = f2bf(v.z); u.w = f2bf(v.w);
    ((ushort4*)out)[i] = u;
  }
}

// ---------------------------------------------------------------------------
// RMSNorm -> bf16 x.  One block per row.
// ---------------------------------------------------------------------------
__global__ __launch_bounds__(256) void rmsnorm_k(const float* __restrict__ h,
                                                 const float* __restrict__ w,
                                                 unsigned short* __restrict__ x) {
  int row = blockIdx.x;
  int t = threadIdx.x;
  const float4* hr = (const float4*)(h + (size_t)row * HIDD);
  const float4* w4 = (const float4*)w;

  float4 v0 = hr[t], v1 = hr[t + 256];
  float ss = v0.x*v0.x + v0.y*v0.y + v0.z*v0.z + v0.w*v0.w
           + v1.x*v1.x + v1.y*v1.y + v1.z*v1.z + v1.w*v1.w;
#pragma unroll
  for (int off = 32; off > 0; off >>= 1) ss += __shfl_down(ss, off, 64);

  __shared__ float part[4];
  __shared__ float rs_sh;
  if ((t & 63) == 0) part[t >> 6] = ss;
  __syncthreads();
  if (t == 0) rs_sh = rsqrtf((part[0]+part[1]+part[2]+part[3]) * (1.0f/HIDD) + EPS_);
  __syncthreads();
  float rs = rs_sh;

  float4 w0 = w4[t], w1 = w4[t + 256];
  ushort4 o0, o1;
  o0.x = f2bf(v0.x * rs * (1.f + w0.x));
  o0.y = f2bf(v0.y * rs * (1.f + w0.y));
  o0.z = f2bf(v0.z * rs * (1.f + w0.z));
  o0.w = f2bf(v0.w * rs * (1.f + w0.w));
  o1.x = f2bf(v1.x * rs * (1.f + w1.x));
  o1.y = f2bf(v1.y * rs * (1.f + w1.y));
  o1.z = f2bf(v1.z * rs * (1.f + w1.z));
  o1.w = f2bf(v1.w * rs * (1.f + w1.w));
  ushort4* xr = (ushort4*)(x + (size_t)row * HIDD);
  xr[t] = o0;
  xr[t + 256] = o1;
}

// ---------------------------------------------------------------------------
// bf16 MFMA GEMM core: C[.,Ndim] = A[.,2048](bf16) * W[.,2048](bf16)^T.
// 128x128 tile, BK=64, 4 waves (2x2), wave tile 64x64, 16x16x32 MFMA.
// Staging via global_load_lds width=16 (linear dest, pre-swizzled source).
// OBF: 0 = fp32 out, 1 = bf16 out, 2 = QG split (cols<2048 -> bf16*SCALE to
// Cv; cols>=2048 -> fp32 to Cv2; both row-stride 2048).
// ---------------------------------------------------------------------------
template <int OBF>
__device__ __forceinline__ void gemm_core(const unsigned short* __restrict__ Ab,
                                          const unsigned short* __restrict__ Bb,
                                          void* __restrict__ Cv,
                                          void* __restrict__ Cv2,
                                          int Ndim, int bm, int bn,
                                          unsigned short* Als, unsigned short* Bls) {
  char* ldsA = (char*)Als;
  char* ldsB = (char*)Bls;

  int t   = threadIdx.x;
  int r15 = t & 15;
  int g   = (t & 63) >> 4;
  int w   = t >> 6;
  int wr  = w >> 1, wc = w & 1;

  f32x4 acc[4][4] = {};

  for (int k0 = 0; k0 < KDIM; k0 += 64) {
    __syncthreads();            // previous iteration's readers done
#pragma unroll
    for (int it = 0; it < 4; ++it) {
      int f      = it * 256 + t;
      int row    = f >> 3;          // 0..127
      int schunk = (f & 7) ^ (row & 7);   // pre-swizzled source chunk
      unsigned ldsbase = (unsigned)((it * 256 + (w << 6)) << 4);  // wave-uniform
      __builtin_amdgcn_global_load_lds(
          (const unsigned int*)(Ab + ((size_t)(bm + row) << 11) + k0 + schunk * 8),
          (unsigned int*)(ldsA + ldsbase), 16, 0, 0);
      __builtin_amdgcn_global_load_lds(
          (const unsigned int*)(Bb + ((size_t)(bn + row) << 11) + k0 + schunk * 8),
          (unsigned int*)(ldsB + ldsbase), 16, 0, 0);
    }
    __syncthreads();

#pragma unroll
    for (int tt = 0; tt < 2; ++tt) {
      bf16x8 af[4], bfv[4];
#pragma unroll
      for (int mi = 0; mi < 4; ++mi) {
        int row = wr * 64 + mi * 16 + r15;
        af[mi] = *(const bf16x8*)(ldsA + row * 128 + (((4 * tt + g) ^ (row & 7)) << 4));
      }
#pragma unroll
      for (int ni = 0; ni < 4; ++ni) {
        int row = wc * 64 + ni * 16 + r15;
        bfv[ni] = *(const bf16x8*)(ldsB + row * 128 + (((4 * tt + g) ^ (row & 7)) << 4));
      }
      __builtin_amdgcn_s_setprio(1);
#pragma unroll
      for (int mi = 0; mi < 4; ++mi)
#pragma unroll
        for (int ni = 0; ni < 4; ++ni)
          acc[mi][ni] = __builtin_amdgcn_mfma_f32_16x16x32_bf16(af[mi], bfv[ni], acc[mi][ni], 0, 0, 0);
      __builtin_amdgcn_s_setprio(0);
    }
  }

  // epilogue: C/D layout col=lane&15, row=(lane>>4)*4+reg
#pragma unroll
  for (int mi = 0; mi < 4; ++mi)
#pragma unroll
    for (int ni = 0; ni < 4; ++ni) {
      int col = bn + wc * 64 + ni * 16 + r15;
#pragma unroll
      for (int r = 0; r < 4; ++r) {
        int rowg = bm + wr * 64 + mi * 16 + g * 4 + r;
        if (OBF == 1)
          ((unsigned short*)Cv)[(size_t)rowg * Ndim + col] = f2bf(acc[mi][ni][r]);
        else if (OBF == 2) {
          if (col < O_N)      // q half: bf16, SCALE folded (same op attn did)
            ((unsigned short*)Cv)[(size_t)rowg * O_N + col] = f2bf(acc[mi][ni][r] * SCALE_);
          else                // gate half: fp32
            ((float*)Cv2)[(size_t)rowg * O_N + (col - O_N)] = acc[mi][ni][r];
        } else
          ((float*)Cv)[(size_t)rowg * Ndim + col] = acc[mi][ni][r];
      }
    }
}

template <int OBF>
__global__ __launch_bounds__(256) void gemm_bf16(const unsigned short* __restrict__ Ab,
                                                 const unsigned short* __restrict__ Bb,
                                                 void* __restrict__ Cv,
                                                 int Ndim) {
  __shared__ unsigned short Als[128 * 64];
  __shared__ unsigned short Bls[128 * 64];
  gemm_core<OBF>(Ab, Bb, Cv, nullptr, Ndim, blockIdx.y * 128, blockIdx.x * 128, Als, Bls);
}

// QG GEMM: q half -> bf16 (SCALE folded), gate half -> fp32.
__global__ __launch_bounds__(256) void gemm_qg(const unsigned short* __restrict__ Ab,
                                               const unsigned short* __restrict__ Bb,
                                               unsigned short* __restrict__ Cq,
                                               float* __restrict__ Cg) {
  __shared__ unsigned short Als[128 * 64];
  __shared__ unsigned short Bls[128 * 64];
  gemm_core<2>(Ab, Bb, (void*)Cq, (void*)Cg, QG_N, blockIdx.y * 128, blockIdx.x * 128, Als, Bls);
}

// K and V GEMMs fused into one dispatch.
__global__ __launch_bounds__(256) void gemm_kv(const unsigned short* __restrict__ Ab,
                                               const unsigned short* __restrict__ Wk,
                                               const unsigned short* __restrict__ Wv,
                                               unsigned short* __restrict__ Ck,
                                               unsigned short* __restrict__ Cva) {
  __shared__ unsigned short Als[128 * 64];
  __shared__ unsigned short Bls[128 * 64];
  int bx = blockIdx.x;
  const unsigned short* Bb = (bx < 4) ? Wk : Wv;
  unsigned short* Cv = (bx < 4) ? Ck : Cva;
  gemm_core<1>(Ab, Bb, (void*)Cv, nullptr, KV_N, blockIdx.y * 128, (bx & 3) * 128, Als, Bls);
}

// ---------------------------------------------------------------------------
// bf16 MFMA flash attention v5 = v4 + IN-REGISTER P (no P LDS round-trip).
// After swapped QK^T, lane (q=lane&15, g=lane>>4) holds S for kv=nf*16+g*4+r.
// Redefine PV's logical-k mapping: k=(g,j) <-> kv=(2*ks2+(j>>2))*16+g*4+(j&3),
// so the PV A-frag is built from the lane's OWN accS registers (zero LDS).
// V columns are stored at the bit-permuted position sig(kv) so the unchanged
// b128 V-read supplies matching kv order:
//   sig = (kv&32) + ((kv&12)<<1) + ((kv&16)>>2) + (kv&3)   [bijection]
// LDS: K 2x16K + Vt 2x16K = 64 KB (Ps eliminated) -> 2 blocks/CU.
// ---------------------------------------------------------------------------
__global__ __launch_bounds__(256, 2) void attn_mfma(const unsigned short* __restrict__ qb,
                                                    const float* __restrict__ gateb,
                                                    const unsigned short* __restrict__ kb,
                                                    const unsigned short* __restrict__ vb,
                                                    unsigned short* __restrict__ obuf) {
  __shared__ unsigned short Ks[2][64 * 128];   // [kv][d], chunk^=(kv&7) swizzle
  __shared__ unsigned short Vt[2][64 * 128];   // [d][sig(kv)], chunk^=(d&7) swizzle
  char* ldsK0 = (char*)Ks;
  char* ldsV0 = (char*)Vt;

  int t = threadIdx.x;
  int l = t & 63, w = t >> 6;
  int c15 = l & 15, g = l >> 4;
  // XCD-chunked swizzle: 512 blocks, 8 XCDs -> XCD c owns swz [c*64, c*64+63]
  int bid = blockIdx.x;
  int swz = (bid & 7) * 64 + (bid >> 3);
  int qt = swz & 15, h = (swz >> 4) & 15, b = swz >> 8;
  int kh = h >> 2;                          // G = 4
  size_t rowQ0 = (size_t)b * SS + (size_t)qt * 128;
  size_t rowKbase = (size_t)b * SS;

  // Q fragments (B-operand), pre-scaled bf16: q row = w*32 + qi*16 + c15,
  // k(d) = g*8 + ks*32 + j  -> one 16B load per frag
  bf16x8 qf[2][4];
#pragma unroll
  for (int qi = 0; qi < 2; ++qi)
#pragma unroll
    for (int ks = 0; ks < 4; ++ks)
      qf[qi][ks] = *(const bf16x8*)(qb + (rowQ0 + w * 32 + qi * 16 + c15) * O_N
                                       + h * HDD + g * 8 + ks * 32);

  f32x4 accO[2][8] = {};
  float mrun[2] = {-INFINITY, -INFINITY};
  float lrun[2] = {0.f, 0.f};
  u16x8 vreg[4];                 // V tile in flight (regs)

  // ---- staging helpers (macros keep addressing identical across sites) ----
#define ISSUE_K(bufi, kt_)                                                     \
  {                                                                            \
    size_t rowK0 = rowKbase + (size_t)(kt_) * 64;                              \
    _Pragma("unroll")                                                          \
    for (int it = 0; it < 4; ++it) {                                           \
      int f = it * 256 + t;                                                    \
      int kv = f >> 4;                                                         \
      int schunk = (f & 15) ^ (kv & 7);                                        \
      unsigned ldsbase = (unsigned)((it * 256 + (w << 6)) << 4);               \
      __builtin_amdgcn_global_load_lds(                                        \
          (const unsigned int*)(kb + (rowK0 + kv) * KV_N + kh * HDD + schunk * 8), \
          (unsigned int*)(ldsK0 + (bufi) * 16384 + ldsbase), 16, 0, 0);        \
    }                                                                          \
  }
#define ISSUE_V(kt_)                                                           \
  {                                                                            \
    size_t rowK0 = rowKbase + (size_t)(kt_) * 64;                              \
    _Pragma("unroll")                                                          \
    for (int it = 0; it < 4; ++it) {                                           \
      int f = it * 256 + t;                                                    \
      int kv = f & 63;                                                         \
      int d8 = (f >> 6) * 8;                                                   \
      vreg[it] = *(const u16x8*)(vb + (rowK0 + kv) * KV_N + kh * HDD + d8);    \
    }                                                                          \
  }
#define WRITE_V(bufi)                                                          \
  {                                                                            \
    _Pragma("unroll")                                                          \
    for (int it = 0; it < 4; ++it) {                                           \
      int f = it * 256 + t;                                                    \
      int kv = f & 63;                                                         \
      int sig = (kv & 32) + ((kv & 12) << 1) + ((kv & 16) >> 2) + (kv & 3);    \
      int d8 = (f >> 6) * 8;                                                   \
      _Pragma("unroll")                                                        \
      for (int i = 0; i < 8; ++i) {                                            \
        int d = d8 + i;                                                        \
        *(unsigned short*)(ldsV0 + (bufi) * 16384 + d * 128 +                  \
                           (((sig >> 3) ^ (d & 7)) << 4) + (sig & 7) * 2) = vreg[it][i]; \
      }                                                                        \
    }                                                                          \
  }

  // ---- prologue: stage tile 0 into buffer 0 ----
  ISSUE_K(0, 0);
  ISSUE_V(0);
  asm volatile("s_waitcnt vmcnt(0)" ::: "memory");
  WRITE_V(0);
  __syncthreads();

  const int NT = SS / 64;
  for (int kt = 0; kt < NT; ++kt) {
    int cur = kt & 1, nxt = cur ^ 1;
    char* ldsK = ldsK0 + cur * 16384;
    char* ldsV = ldsV0 + cur * 16384;

    // prefetch next tile (K direct-to-LDS, V to regs)
    if (kt + 1 < NT) {
      ISSUE_K(nxt, kt + 1);
      ISSUE_V(kt + 1);
    }

    // S^T = K Q : 32 MFMA.  accS[qi][nf]: col=c15=q, row=kv=nf*16+g*4+r
    f32x4 accS[2][4] = {};
    __builtin_amdgcn_s_setprio(1);
#pragma unroll
    for (int nf = 0; nf < 4; ++nf) {
      int kvr = nf * 16 + c15;
#pragma unroll
      for (int ks = 0; ks < 4; ++ks) {
        bf16x8 kf = *(const bf16x8*)(ldsK + kvr * 256 + ((((g + 4 * ks) ^ (kvr & 7)) << 4)));
#pragma unroll
        for (int qi = 0; qi < 2; ++qi)
          accS[qi][nf] = __builtin_amdgcn_mfma_f32_16x16x32_bf16(kf, qf[qi][ks], accS[qi][nf], 0, 0, 0);
      }
    }
    __builtin_amdgcn_s_setprio(0);

    // per-lane tile max over own q-column, reduce over 4 kv-groups
    float mt[2];
#pragma unroll
    for (int qi = 0; qi < 2; ++qi) {
      float m0 = fmaxf(fmaxf(accS[qi][0][0], accS[qi][0][1]), fmaxf(accS[qi][0][2], accS[qi][0][3]));
#pragma unroll
      for (int nf = 1; nf < 4; ++nf)
        m0 = fmaxf(m0, fmaxf(fmaxf(accS[qi][nf][0], accS[qi][nf][1]), fmaxf(accS[qi][nf][2], accS[qi][nf][3])));
      m0 = fmaxf(m0, __shfl_xor(m0, 16, 64));
      m0 = fmaxf(m0, __shfl_xor(m0, 32, 64));
      mt[qi] = m0;
    }

    // defer-max: skip rescale when wave-uniformly safe (bounded by e^8)
    bool safe = (mt[0] <= mrun[0] + 8.f) && (mt[1] <= mrun[1] + 8.f);
    if (!__all(safe)) {
#pragma unroll
      for (int qi = 0; qi < 2; ++qi) {
        float mnew = fmaxf(mrun[qi], mt[qi]);
        float al = __expf(mrun[qi] - mnew);   // first tile: exp(-inf)=0
        mrun[qi] = mnew;
        lrun[qi] *= al;
        float alr[4];
#pragma unroll
        for (int r = 0; r < 4; ++r) alr[r] = __shfl(al, g * 4 + r, 16);
#pragma unroll
        for (int df = 0; df < 8; ++df)
#pragma unroll
          for (int r = 0; r < 4; ++r) accO[qi][df][r] *= alr[r];
      }
    }

    // P = exp(S - m): pack straight into PV A-fragments (in-register, no LDS).
    // pfr[qi][ks2] element (nf&1)*4+r  <->  kv = nf*16 + g*4 + r
    u16x8 pfr[2][2];
#pragma unroll
    for (int qi = 0; qi < 2; ++qi) {
      float ps = 0.f;
#pragma unroll
      for (int nf = 0; nf < 4; ++nf) {
        float p0 = __expf(accS[qi][nf][0] - mrun[qi]);
        float p1 = __expf(accS[qi][nf][1] - mrun[qi]);
        float p2 = __expf(accS[qi][nf][2] - mrun[qi]);
        float p3 = __expf(accS[qi][nf][3] - mrun[qi]);
        ps += (p0 + p1) + (p2 + p3);
        pfr[qi][nf >> 1][(nf & 1) * 4 + 0] = f2bf(p0);
        pfr[qi][nf >> 1][(nf & 1) * 4 + 1] = f2bf(p1);
        pfr[qi][nf >> 1][(nf & 1) * 4 + 2] = f2bf(p2);
        pfr[qi][nf >> 1][(nf & 1) * 4 + 3] = f2bf(p3);
      }
      ps += __shfl_xor(ps, 16, 64);
      ps += __shfl_xor(ps, 32, 64);
      lrun[qi] += ps;
    }

    // O += P V : 32 MFMA.  A = pfr (own registers), B = Vt[d][sig(kv)]
    __builtin_amdgcn_s_setprio(1);
#pragma unroll
    for (int ks2 = 0; ks2 < 2; ++ks2) {
      bf16x8 pf0 = __builtin_bit_cast(bf16x8, pfr[0][ks2]);
      bf16x8 pf1 = __builtin_bit_cast(bf16x8, pfr[1][ks2]);
#pragma unroll
      for (int df = 0; df < 8; ++df) {
        int d = df * 16 + c15;
        bf16x8 vf = *(const bf16x8*)(ldsV + d * 128 + ((((g + 4 * ks2) ^ (d & 7)) << 4)));
        accO[0][df] = __builtin_amdgcn_mfma_f32_16x16x32_bf16(pf0, vf, accO[0][df], 0, 0, 0);
        accO[1][df] = __builtin_amdgcn_mfma_f32_16x16x32_bf16(pf1, vf, accO[1][df], 0, 0, 0);
      }
    }
    __builtin_amdgcn_s_setprio(0);

    // drain prefetch loads, commit V tile kt+1 into next buffer
    if (kt + 1 < NT) {
      asm volatile("s_waitcnt vmcnt(0)" ::: "memory");
      WRITE_V(nxt);
    }
    __syncthreads();
  }

  // epilogue: normalize (invL via shfl), sigmoid-gate, bf16 store
#pragma unroll
  for (int qi = 0; qi < 2; ++qi) {
    float invL = 1.f / lrun[qi];
    float ivr[4];
#pragma unroll
    for (int r = 0; r < 4; ++r) ivr[r] = __shfl(invL, g * 4 + r, 16);
#pragma unroll
    for (int r = 0; r < 4; ++r) {
      size_t row = rowQ0 + w * 32 + qi * 16 + g * 4 + r;
#pragma unroll
      for (int df = 0; df < 8; ++df) {
        int d = df * 16 + c15;
        float gt = gateb[row * (size_t)O_N + h * HDD + d];
        float sg = 1.f / (1.f + __expf(-gt));
        obuf[row * (size_t)O_N + h * HDD + d] = f2bf(accO[qi][df][r] * ivr[r] * sg);
      }
    }
  }
#undef ISSUE_K
#undef ISSUE_V
#undef WRITE_V
}

// ---------------------------------------------------------------------------
// Launch
// ---------------------------------------------------------------------------
extern "C" void kernel_launch(void* const* d_in, const int* in_sizes, int n_in,
                              void* d_out, int out_size, void* d_ws, size_t ws_size,
                              hipStream_t stream) {
  const float* hs = (const float*)d_in[0];
  // d_in[1] = position_ids (unused by the reference)
  const float* Wq = (const float*)d_in[2];
  const float* Wk = (const float*)d_in[3];
  const float* Wv = (const float*)d_in[4];
  const float* Wo = (const float*)d_in[5];
  const float* nw = (const float*)d_in[6];
  float* out = (float*)d_out;

  // workspace (~121 MB): gate fp32 | bf16: qb,kb,vb,x,ob,Wq,Wk,Wv,Wo
  float* gateb = (float*)d_ws;                                   // 33.5 MB
  unsigned short* qb16 = (unsigned short*)(gateb + (size_t)MROWS * O_N);  // 16.8 MB
  unsigned short* kb16 = qb16 + (size_t)MROWS * O_N;
  unsigned short* vb16 = kb16 + (size_t)MROWS * KV_N;
  unsigned short* xb   = vb16 + (size_t)MROWS * KV_N;
  unsigned short* ob   = xb   + (size_t)MROWS * HIDD;
  unsigned short* wqb  = ob   + (size_t)MROWS * O_N;
  unsigned short* wkb  = wqb  + (size_t)QG_N * KDIM;
  unsigned short* wvb  = wkb  + (size_t)KV_N * KDIM;
  unsigned short* wob  = wvb  + (size_t)KV_N * KDIM;

  f2bf_k<<<(QG_N*KDIM/4 + 255)/256, 256, 0, stream>>>(Wq, wqb, QG_N*KDIM/4);
  f2bf_k<<<(KV_N*KDIM/4 + 255)/256, 256, 0, stream>>>(Wk, wkb, KV_N*KDIM/4);
  f2bf_k<<<(KV_N*KDIM/4 + 255)/256, 256, 0, stream>>>(Wv, wvb, KV_N*KDIM/4);
  f2bf_k<<<(O_N*KDIM/4  + 255)/256, 256, 0, stream>>>(Wo, wob, O_N*KDIM/4);
  rmsnorm_k<<<MROWS, 256, 0, stream>>>(hs, nw, xb);

  gemm_qg<<<dim3(QG_N/128, MROWS/128), 256, 0, stream>>>(xb, wqb, qb16, gateb);
  gemm_kv<<<dim3(8, MROWS/128), 256, 0, stream>>>(xb, wkb, wvb, kb16, vb16);
  attn_mfma<<<dim3(512), 256, 0, stream>>>(qb16, gateb, kb16, vb16, ob);
  gemm_bf16<0><<<dim3(O_N/128, MROWS/128), 256, 0, stream>>>(ob, wob, out, O_N);
}

// Round 12
// 283.936 us; speedup vs baseline: 6.5544x; 1.0085x over previous
//
#include <hip/hip_runtime.h>
#include <math.h>

// Problem constants (from reference)
#define BB    2
#define SS    2048
#define HIDD  2048
#define NHH   16
#define NKVV  4
#define HDD   128
#define MROWS 4096            // B*S
#define QG_N  4096            // 2*NH*HD
#define KV_N  512             // NKV*HD
#define O_N   2048            // NH*HD
#define KDIM  2048            // shared K for all four GEMMs (row stride of A and W)
#define EPS_  1e-6f
#define SCALE_ 0.08838834764831845f   // 1/sqrt(128)

typedef __attribute__((ext_vector_type(8))) __bf16 bf16x8;
typedef __attribute__((ext_vector_type(8))) unsigned short u16x8;
typedef __attribute__((ext_vector_type(4))) float f32x4;

__device__ __forceinline__ unsigned short f2bf(float f) {
  return __builtin_bit_cast(unsigned short, (__bf16)f);   // RNE via v_cvt
}

// ---------------------------------------------------------------------------
// fp32 -> bf16 convert for all four weights in ONE dispatch.
// dst segments (wq|wk|wv|wo) are contiguous in the workspace.
// ---------------------------------------------------------------------------
__global__ __launch_bounds__(256) void f2bf_all(const float* __restrict__ Wq,
                                                const float* __restrict__ Wk,
                                                const float* __restrict__ Wv,
                                                const float* __restrict__ Wo,
                                                unsigned short* __restrict__ dst) {
  const int s0 = QG_N * KDIM / 4;
  const int s1 = s0 + KV_N * KDIM / 4;
  const int s2 = s1 + KV_N * KDIM / 4;
  const int s3 = s2 + O_N * KDIM / 4;
  int i = blockIdx.x * 256 + threadIdx.x;
  if (i >= s3) return;
  float4 v;
  if (i < s0)      v = ((const float4*)Wq)[i];
  else if (i < s1) v = ((const float4*)Wk)[i - s0];
  else if (i < s2) v = ((const float4*)Wv)[i - s1];
  else             v = ((const float4*)Wo)[i - s2];
  ushort4 u;
  u.x = f2bf(v.x); u.y = f2bf(v.y); u.z = f2bf(v.z); u.w = f2bf(v.w);
  ((ushort4*)dst)[i] = u;
}

// ---------------------------------------------------------------------------
// RMSNorm -> bf16 x.  One block per row.
// ---------------------------------------------------------------------------
__global__ __launch_bounds__(256) void rmsnorm_k(const float* __restrict__ h,
                                                 const float* __restrict__ w,
                                                 unsigned short* __restrict__ x) {
  int row = blockIdx.x;
  int t = threadIdx.x;
  const float4* hr = (const float4*)(h + (size_t)row * HIDD);
  const float4* w4 = (const float4*)w;

  float4 v0 = hr[t], v1 = hr[t + 256];
  float ss = v0.x*v0.x + v0.y*v0.y + v0.z*v0.z + v0.w*v0.w
           + v1.x*v1.x + v1.y*v1.y + v1.z*v1.z + v1.w*v1.w;
#pragma unroll
  for (int off = 32; off > 0; off >>= 1) ss += __shfl_down(ss, off, 64);

  __shared__ float part[4];
  __shared__ float rs_sh;
  if ((t & 63) == 0) part[t >> 6] = ss;
  __syncthreads();
  if (t == 0) rs_sh = rsqrtf((part[0]+part[1]+part[2]+part[3]) * (1.0f/HIDD) + EPS_);
  __syncthreads();
  float rs = rs_sh;

  float4 w0 = w4[t], w1 = w4[t + 256];
  ushort4 o0, o1;
  o0.x = f2bf(v0.x * rs * (1.f + w0.x));
  o0.y = f2bf(v0.y * rs * (1.f + w0.y));
  o0.z = f2bf(v0.z * rs * (1.f + w0.z));
  o0.w = f2bf(v0.w * rs * (1.f + w0.w));
  o1.x = f2bf(v1.x * rs * (1.f + w1.x));
  o1.y = f2bf(v1.y * rs * (1.f + w1.y));
  o1.z = f2bf(v1.z * rs * (1.f + w1.z));
  o1.w = f2bf(v1.w * rs * (1.f + w1.w));
  ushort4* xr = (ushort4*)(x + (size_t)row * HIDD);
  xr[t] = o0;
  xr[t + 256] = o1;
}

// ---------------------------------------------------------------------------
// bf16 MFMA GEMM core: C[.,Ndim] = A[.,2048](bf16) * W[.,2048](bf16)^T.
// 128x128 tile, BK=64, 4 waves (2x2), wave tile 64x64, 16x16x32 MFMA.
// Staging via global_load_lds width=16 (linear dest, pre-swizzled source).
// OBF: 0 = fp32 out, 1 = bf16 out, 2 = QG split (q half bf16*SCALE, gate fp32),
// 3 = bf16 TRANSPOSED out (C^T[col][rowg], row-stride MROWS) for V^T.
// ---------------------------------------------------------------------------
template <int OBF>
__device__ __forceinline__ void gemm_core(const unsigned short* __restrict__ Ab,
                                          const unsigned short* __restrict__ Bb,
                                          void* __restrict__ Cv,
                                          void* __restrict__ Cv2,
                                          int Ndim, int bm, int bn,
                                          unsigned short* Als, unsigned short* Bls) {
  char* ldsA = (char*)Als;
  char* ldsB = (char*)Bls;

  int t   = threadIdx.x;
  int r15 = t & 15;
  int g   = (t & 63) >> 4;
  int w   = t >> 6;
  int wr  = w >> 1, wc = w & 1;

  f32x4 acc[4][4] = {};

  for (int k0 = 0; k0 < KDIM; k0 += 64) {
    __syncthreads();            // previous iteration's readers done
#pragma unroll
    for (int it = 0; it < 4; ++it) {
      int f      = it * 256 + t;
      int row    = f >> 3;          // 0..127
      int schunk = (f & 7) ^ (row & 7);   // pre-swizzled source chunk
      unsigned ldsbase = (unsigned)((it * 256 + (w << 6)) << 4);  // wave-uniform
      __builtin_amdgcn_global_load_lds(
          (const unsigned int*)(Ab + ((size_t)(bm + row) << 11) + k0 + schunk * 8),
          (unsigned int*)(ldsA + ldsbase), 16, 0, 0);
      __builtin_amdgcn_global_load_lds(
          (const unsigned int*)(Bb + ((size_t)(bn + row) << 11) + k0 + schunk * 8),
          (unsigned int*)(ldsB + ldsbase), 16, 0, 0);
    }
    __syncthreads();

#pragma unroll
    for (int tt = 0; tt < 2; ++tt) {
      bf16x8 af[4], bfv[4];
#pragma unroll
      for (int mi = 0; mi < 4; ++mi) {
        int row = wr * 64 + mi * 16 + r15;
        af[mi] = *(const bf16x8*)(ldsA + row * 128 + (((4 * tt + g) ^ (row & 7)) << 4));
      }
#pragma unroll
      for (int ni = 0; ni < 4; ++ni) {
        int row = wc * 64 + ni * 16 + r15;
        bfv[ni] = *(const bf16x8*)(ldsB + row * 128 + (((4 * tt + g) ^ (row & 7)) << 4));
      }
      __builtin_amdgcn_s_setprio(1);
#pragma unroll
      for (int mi = 0; mi < 4; ++mi)
#pragma unroll
        for (int ni = 0; ni < 4; ++ni)
          acc[mi][ni] = __builtin_amdgcn_mfma_f32_16x16x32_bf16(af[mi], bfv[ni], acc[mi][ni], 0, 0, 0);
      __builtin_amdgcn_s_setprio(0);
    }
  }

  // epilogue: C/D layout col=lane&15, row=(lane>>4)*4+reg
#pragma unroll
  for (int mi = 0; mi < 4; ++mi)
#pragma unroll
    for (int ni = 0; ni < 4; ++ni) {
      int col = bn + wc * 64 + ni * 16 + r15;
#pragma unroll
      for (int r = 0; r < 4; ++r) {
        int rowg = bm + wr * 64 + mi * 16 + g * 4 + r;
        if (OBF == 1)
          ((unsigned short*)Cv)[(size_t)rowg * Ndim + col] = f2bf(acc[mi][ni][r]);
        else if (OBF == 2) {
          if (col < O_N)      // q half: bf16, SCALE folded (same op attn did)
            ((unsigned short*)Cv)[(size_t)rowg * O_N + col] = f2bf(acc[mi][ni][r] * SCALE_);
          else                // gate half: fp32
            ((float*)Cv2)[(size_t)rowg * O_N + (col - O_N)] = acc[mi][ni][r];
        } else if (OBF == 3)  // transposed bf16: V^T[d][token], 4 r = 8B runs
          ((unsigned short*)Cv)[(size_t)col * MROWS + rowg] = f2bf(acc[mi][ni][r]);
        else
          ((float*)Cv)[(size_t)rowg * Ndim + col] = acc[mi][ni][r];
      }
    }
}

template <int OBF>
__global__ __launch_bounds__(256) void gemm_bf16(const unsigned short* __restrict__ Ab,
                                                 const unsigned short* __restrict__ Bb,
                                                 void* __restrict__ Cv,
                                                 int Ndim) {
  __shared__ unsigned short Als[128 * 64];
  __shared__ unsigned short Bls[128 * 64];
  gemm_core<OBF>(Ab, Bb, Cv, nullptr, Ndim, blockIdx.y * 128, blockIdx.x * 128, Als, Bls);
}

// QG GEMM: q half -> bf16 (SCALE folded), gate half -> fp32.
__global__ __launch_bounds__(256) void gemm_qg(const unsigned short* __restrict__ Ab,
                                               const unsigned short* __restrict__ Bb,
                                               unsigned short* __restrict__ Cq,
                                               float* __restrict__ Cg) {
  __shared__ unsigned short Als[128 * 64];
  __shared__ unsigned short Bls[128 * 64];
  gemm_core<2>(Ab, Bb, (void*)Cq, (void*)Cg, QG_N, blockIdx.y * 128, blockIdx.x * 128, Als, Bls);
}

// K and V GEMMs fused into one dispatch; V stored TRANSPOSED (V^T[d][token]).
__global__ __launch_bounds__(256) void gemm_kv(const unsigned short* __restrict__ Ab,
                                               const unsigned short* __restrict__ Wk,
                                               const unsigned short* __restrict__ Wv,
                                               unsigned short* __restrict__ Ck,
                                               unsigned short* __restrict__ Cvt) {
  __shared__ unsigned short Als[128 * 64];
  __shared__ unsigned short Bls[128 * 64];
  int bx = blockIdx.x;
  if (bx < 4)
    gemm_core<1>(Ab, Wk, (void*)Ck, nullptr, KV_N, blockIdx.y * 128, bx * 128, Als, Bls);
  else
    gemm_core<3>(Ab, Wv, (void*)Cvt, nullptr, KV_N, blockIdx.y * 128, (bx & 3) * 128, Als, Bls);
}

// ---------------------------------------------------------------------------
// bf16 MFMA flash attention v6 = v5 with V^T staged via global_load_lds.
// V arrives pre-transposed (V^T[d][token] from the KV GEMM), so the reg-staged
// transpose (32 scalar ds_writes + sig permutation + vreg) is DELETED; both K
// and V^T stage linearly with pre-swizzled source chunks.  PV B-fragments are
// two swizzled ds_read_b64 per (ks2,df): kv = {32ks2+4g..+3} u {+16} matches
// the in-register P k-slot mapping exactly (math bit-identical to v5).
// LDS: K 2x16K + Vt 2x16K = 64 KB -> 2 blocks/CU.
// ---------------------------------------------------------------------------
__global__ __launch_bounds__(256, 2) void attn_mfma(const unsigned short* __restrict__ qb,
                                                    const float* __restrict__ gateb,
                                                    const unsigned short* __restrict__ kb,
                                                    const unsigned short* __restrict__ vt,
                                                    unsigned short* __restrict__ obuf) {
  __shared__ unsigned short Ks[2][64 * 128];   // [kv][d], chunk^=(kv&7) swizzle
  __shared__ unsigned short Vt[2][128 * 64];   // [d][tok], chunk^=(d&7) swizzle
  char* ldsK0 = (char*)Ks;
  char* ldsV0 = (char*)Vt;

  int t = threadIdx.x;
  int l = t & 63, w = t >> 6;
  int c15 = l & 15, g = l >> 4;
  // XCD-chunked swizzle: 512 blocks, 8 XCDs -> XCD c owns swz [c*64, c*64+63]
  int bid = blockIdx.x;
  int swz = (bid & 7) * 64 + (bid >> 3);
  int qt = swz & 15, h = (swz >> 4) & 15, b = swz >> 8;
  int kh = h >> 2;                          // G = 4
  size_t rowQ0 = (size_t)b * SS + (size_t)qt * 128;
  size_t rowKbase = (size_t)b * SS;

  // Q fragments (B-operand), pre-scaled bf16: q row = w*32 + qi*16 + c15,
  // k(d) = g*8 + ks*32 + j  -> one 16B load per frag
  bf16x8 qf[2][4];
#pragma unroll
  for (int qi = 0; qi < 2; ++qi)
#pragma unroll
    for (int ks = 0; ks < 4; ++ks)
      qf[qi][ks] = *(const bf16x8*)(qb + (rowQ0 + w * 32 + qi * 16 + c15) * O_N
                                       + h * HDD + g * 8 + ks * 32);

  f32x4 accO[2][8] = {};
  float mrun[2] = {-INFINITY, -INFINITY};
  float lrun[2] = {0.f, 0.f};

  // ---- staging helpers ----
#define ISSUE_K(bufi, kt_)                                                     \
  {                                                                            \
    size_t rowK0 = rowKbase + (size_t)(kt_) * 64;                              \
    _Pragma("unroll")                                                          \
    for (int it = 0; it < 4; ++it) {                                           \
      int f = it * 256 + t;                                                    \
      int kv = f >> 4;                                                         \
      int schunk = (f & 15) ^ (kv & 7);                                        \
      unsigned ldsbase = (unsigned)((it * 256 + (w << 6)) << 4);               \
      __builtin_amdgcn_global_load_lds(                                        \
          (const unsigned int*)(kb + (rowK0 + kv) * KV_N + kh * HDD + schunk * 8), \
          (unsigned int*)(ldsK0 + (bufi) * 16384 + ldsbase), 16, 0, 0);        \
    }                                                                          \
  }
#define ISSUE_VT(bufi, kt_)                                                    \
  {                                                                            \
    size_t tokbase = rowKbase + (size_t)(kt_) * 64;                            \
    _Pragma("unroll")                                                          \
    for (int it = 0; it < 4; ++it) {                                           \
      int f = it * 256 + t;                                                    \
      int row = f >> 3;                                                        \
      int schunk = (f & 7) ^ (row & 7);                                        \
      unsigned ldsbase = (unsigned)((it * 256 + (w << 6)) << 4);               \
      __builtin_amdgcn_global_load_lds(                                        \
          (const unsigned int*)(vt + (size_t)(kh * 128 + row) * MROWS + tokbase + schunk * 8), \
          (unsigned int*)(ldsV0 + (bufi) * 16384 + ldsbase), 16, 0, 0);        \
    }                                                                          \
  }

  // ---- prologue: stage tile 0 into buffer 0 ----
  ISSUE_K(0, 0);
  ISSUE_VT(0, 0);
  asm volatile("s_waitcnt vmcnt(0)" ::: "memory");
  __syncthreads();

  const int NT = SS / 64;
  for (int kt = 0; kt < NT; ++kt) {
    int cur = kt & 1, nxt = cur ^ 1;
    char* ldsK = ldsK0 + cur * 16384;
    char* ldsV = ldsV0 + cur * 16384;

    // prefetch next tile (both direct-to-LDS; drained at loop end)
    if (kt + 1 < NT) {
      ISSUE_K(nxt, kt + 1);
      ISSUE_VT(nxt, kt + 1);
    }

    // S^T = K Q : 32 MFMA.  accS[qi][nf]: col=c15=q, row=kv=nf*16+g*4+r
    f32x4 accS[2][4] = {};
    __builtin_amdgcn_s_setprio(1);
#pragma unroll
    for (int nf = 0; nf < 4; ++nf) {
      int kvr = nf * 16 + c15;
#pragma unroll
      for (int ks = 0; ks < 4; ++ks) {
        bf16x8 kf = *(const bf16x8*)(ldsK + kvr * 256 + ((((g + 4 * ks) ^ (kvr & 7)) << 4)));
#pragma unroll
        for (int qi = 0; qi < 2; ++qi)
          accS[qi][nf] = __builtin_amdgcn_mfma_f32_16x16x32_bf16(kf, qf[qi][ks], accS[qi][nf], 0, 0, 0);
      }
    }
    __builtin_amdgcn_s_setprio(0);

    // per-lane tile max over own q-column, reduce over 4 kv-groups
    float mt[2];
#pragma unroll
    for (int qi = 0; qi < 2; ++qi) {
      float m0 = fmaxf(fmaxf(accS[qi][0][0], accS[qi][0][1]), fmaxf(accS[qi][0][2], accS[qi][0][3]));
#pragma unroll
      for (int nf = 1; nf < 4; ++nf)
        m0 = fmaxf(m0, fmaxf(fmaxf(accS[qi][nf][0], accS[qi][nf][1]), fmaxf(accS[qi][nf][2], accS[qi][nf][3])));
      m0 = fmaxf(m0, __shfl_xor(m0, 16, 64));
      m0 = fmaxf(m0, __shfl_xor(m0, 32, 64));
      mt[qi] = m0;
    }

    // defer-max: skip rescale when wave-uniformly safe (bounded by e^8)
    bool safe = (mt[0] <= mrun[0] + 8.f) && (mt[1] <= mrun[1] + 8.f);
    if (!__all(safe)) {
#pragma unroll
      for (int qi = 0; qi < 2; ++qi) {
        float mnew = fmaxf(mrun[qi], mt[qi]);
        float al = __expf(mrun[qi] - mnew);   // first tile: exp(-inf)=0
        mrun[qi] = mnew;
        lrun[qi] *= al;
        float alr[4];
#pragma unroll
        for (int r = 0; r < 4; ++r) alr[r] = __shfl(al, g * 4 + r, 16);
#pragma unroll
        for (int df = 0; df < 8; ++df)
#pragma unroll
          for (int r = 0; r < 4; ++r) accO[qi][df][r] *= alr[r];
      }
    }

    // P = exp(S - m): pack straight into PV A-fragments (in-register, no LDS).
    // pfr[qi][ks2] element j  <->  kv = (2*ks2+(j>>2))*16 + g*4 + (j&3)
    u16x8 pfr[2][2];
#pragma unroll
    for (int qi = 0; qi < 2; ++qi) {
      float ps = 0.f;
#pragma unroll
      for (int nf = 0; nf < 4; ++nf) {
        float p0 = __expf(accS[qi][nf][0] - mrun[qi]);
        float p1 = __expf(accS[qi][nf][1] - mrun[qi]);
        float p2 = __expf(accS[qi][nf][2] - mrun[qi]);
        float p3 = __expf(accS[qi][nf][3] - mrun[qi]);
        ps += (p0 + p1) + (p2 + p3);
        pfr[qi][nf >> 1][(nf & 1) * 4 + 0] = f2bf(p0);
        pfr[qi][nf >> 1][(nf & 1) * 4 + 1] = f2bf(p1);
        pfr[qi][nf >> 1][(nf & 1) * 4 + 2] = f2bf(p2);
        pfr[qi][nf >> 1][(nf & 1) * 4 + 3] = f2bf(p3);
      }
      ps += __shfl_xor(ps, 16, 64);
      ps += __shfl_xor(ps, 32, 64);
      lrun[qi] += ps;
    }

    // O += P V : 32 MFMA.  A = pfr (own regs), B = two b64 reads from Vt:
    // lane (c15,g) supplies k=g*8+j -> kv={32ks2+4g..+3} u {+16}
    __builtin_amdgcn_s_setprio(1);
#pragma unroll
    for (int ks2 = 0; ks2 < 2; ++ks2) {
      bf16x8 pf0 = __builtin_bit_cast(bf16x8, pfr[0][ks2]);
      bf16x8 pf1 = __builtin_bit_cast(bf16x8, pfr[1][ks2]);
      int c0 = 4 * ks2 + (g >> 1);      // 16B chunk of first b64
      int half8 = (g & 1) * 8;          // 8B half within the chunk
#pragma unroll
      for (int df = 0; df < 8; ++df) {
        int d = df * 16 + c15;
        const char* vrow = ldsV + d * 128;
        ushort4 lo = *(const ushort4*)(vrow + (((c0)     ^ (d & 7)) << 4) + half8);
        ushort4 hi = *(const ushort4*)(vrow + (((c0 + 2) ^ (d & 7)) << 4) + half8);
        u16x8 v8 = {lo.x, lo.y, lo.z, lo.w, hi.x, hi.y, hi.z, hi.w};
        bf16x8 vf = __builtin_bit_cast(bf16x8, v8);
        accO[0][df] = __builtin_amdgcn_mfma_f32_16x16x32_bf16(pf0, vf, accO[0][df], 0, 0, 0);
        accO[1][df] = __builtin_amdgcn_mfma_f32_16x16x32_bf16(pf1, vf, accO[1][df], 0, 0, 0);
      }
    }
    __builtin_amdgcn_s_setprio(0);

    // drain prefetch loads before next iteration reads them
    if (kt + 1 < NT) {
      asm volatile("s_waitcnt vmcnt(0)" ::: "memory");
    }
    __syncthreads();
  }

  // epilogue: normalize (invL via shfl), sigmoid-gate, bf16 store
#pragma unroll
  for (int qi = 0; qi < 2; ++qi) {
    float invL = 1.f / lrun[qi];
    float ivr[4];
#pragma unroll
    for (int r = 0; r < 4; ++r) ivr[r] = __shfl(invL, g * 4 + r, 16);
#pragma unroll
    for (int r = 0; r < 4; ++r) {
      size_t row = rowQ0 + w * 32 + qi * 16 + g * 4 + r;
#pragma unroll
      for (int df = 0; df < 8; ++df) {
        int d = df * 16 + c15;
        float gt = gateb[row * (size_t)O_N + h * HDD + d];
        float sg = 1.f / (1.f + __expf(-gt));
        obuf[row * (size_t)O_N + h * HDD + d] = f2bf(accO[qi][df][r] * ivr[r] * sg);
      }
    }
  }
#undef ISSUE_K
#undef ISSUE_VT
}

// ---------------------------------------------------------------------------
// Launch
// ---------------------------------------------------------------------------
extern "C" void kernel_launch(void* const* d_in, const int* in_sizes, int n_in,
                              void* d_out, int out_size, void* d_ws, size_t ws_size,
                              hipStream_t stream) {
  const float* hs = (const float*)d_in[0];
  // d_in[1] = position_ids (unused by the reference)
  const float* Wq = (const float*)d_in[2];
  const float* Wk = (const float*)d_in[3];
  const float* Wv = (const float*)d_in[4];
  const float* Wo = (const float*)d_in[5];
  const float* nw = (const float*)d_in[6];
  float* out = (float*)d_out;

  // workspace (~121 MB): gate fp32 | bf16: qb,kb,vt,x,ob | bf16 W (contiguous)
  float* gateb = (float*)d_ws;                                   // 33.5 MB
  unsigned short* qb16 = (unsigned short*)(gateb + (size_t)MROWS * O_N);  // 16.8 MB
  unsigned short* kb16 = qb16 + (size_t)MROWS * O_N;
  unsigned short* vt16 = kb16 + (size_t)MROWS * KV_N;   // V^T [512][4096]
  unsigned short* xb   = vt16 + (size_t)KV_N * MROWS;
  unsigned short* ob   = xb   + (size_t)MROWS * HIDD;
  unsigned short* wqb  = ob   + (size_t)MROWS * O_N;
  unsigned short* wkb  = wqb  + (size_t)QG_N * KDIM;
  unsigned short* wvb  = wkb  + (size_t)KV_N * KDIM;
  unsigned short* wob  = wvb  + (size_t)KV_N * KDIM;

  // all four weight converts in one dispatch (dst segments contiguous)
  const int tot4 = (QG_N + KV_N + KV_N + O_N) * KDIM / 4;
  f2bf_all<<<(tot4 + 255) / 256, 256, 0, stream>>>(Wq, Wk, Wv, Wo, wqb);
  rmsnorm_k<<<MROWS, 256, 0, stream>>>(hs, nw, xb);

  gemm_qg<<<dim3(QG_N/128, MROWS/128), 256, 0, stream>>>(xb, wqb, qb16, gateb);
  gemm_kv<<<dim3(8, MROWS/128), 256, 0, stream>>>(xb, wkb, wvb, kb16, vt16);
  attn_mfma<<<dim3(512), 256, 0, stream>>>(qb16, gateb, kb16, vt16, ob);
  gemm_bf16<0><<<dim3(O_N/128, MROWS/128), 256, 0, stream>>>(ob, wob, out, O_N);
}

// Round 16
// 262.368 us; speedup vs baseline: 7.0932x; 1.0822x over previous
//
#include <hip/hip_runtime.h>
#include <math.h>

// Problem constants (from reference)
#define BB    2
#define SS    2048
#define HIDD  2048
#define NHH   16
#define NKVV  4
#define HDD   128
#define MROWS 4096            // B*S
#define QG_N  4096            // 2*NH*HD
#define KV_N  512             // NKV*HD
#define O_N   2048            // NH*HD
#define KDIM  2048            // shared K for all four GEMMs (row stride of A and W)
#define EPS_  1e-6f
#define SCALE_ 0.08838834764831845f   // 1/sqrt(128)

typedef __attribute__((ext_vector_type(8))) __bf16 bf16x8;
typedef __attribute__((ext_vector_type(8))) unsigned short u16x8;
typedef __attribute__((ext_vector_type(4))) float f32x4;

__device__ __forceinline__ unsigned short f2bf(float f) {
  return __builtin_bit_cast(unsigned short, (__bf16)f);   // RNE via v_cvt
}

// ---------------------------------------------------------------------------
// fp32 -> bf16 convert for all four weights in ONE dispatch.
// ---------------------------------------------------------------------------
__global__ __launch_bounds__(256) void f2bf_all(const float* __restrict__ Wq,
                                                const float* __restrict__ Wk,
                                                const float* __restrict__ Wv,
                                                const float* __restrict__ Wo,
                                                unsigned short* __restrict__ dst) {
  const int s0 = QG_N * KDIM / 4;
  const int s1 = s0 + KV_N * KDIM / 4;
  const int s2 = s1 + KV_N * KDIM / 4;
  const int s3 = s2 + O_N * KDIM / 4;
  int i = blockIdx.x * 256 + threadIdx.x;
  if (i >= s3) return;
  float4 v;
  if (i < s0)      v = ((const float4*)Wq)[i];
  else if (i < s1) v = ((const float4*)Wk)[i - s0];
  else if (i < s2) v = ((const float4*)Wv)[i - s1];
  else             v = ((const float4*)Wo)[i - s2];
  ushort4 u;
  u.x = f2bf(v.x); u.y = f2bf(v.y); u.z = f2bf(v.z); u.w = f2bf(v.w);
  ((ushort4*)dst)[i] = u;
}

// ---------------------------------------------------------------------------
// RMSNorm -> bf16 x.  One block per row.
// ---------------------------------------------------------------------------
__global__ __launch_bounds__(256) void rmsnorm_k(const float* __restrict__ h,
                                                 const float* __restrict__ w,
                                                 unsigned short* __restrict__ x) {
  int row = blockIdx.x;
  int t = threadIdx.x;
  const float4* hr = (const float4*)(h + (size_t)row * HIDD);
  const float4* w4 = (const float4*)w;

  float4 v0 = hr[t], v1 = hr[t + 256];
  float ss = v0.x*v0.x + v0.y*v0.y + v0.z*v0.z + v0.w*v0.w
           + v1.x*v1.x + v1.y*v1.y + v1.z*v1.z + v1.w*v1.w;
#pragma unroll
  for (int off = 32; off > 0; off >>= 1) ss += __shfl_down(ss, off, 64);

  __shared__ float part[4];
  __shared__ float rs_sh;
  if ((t & 63) == 0) part[t >> 6] = ss;
  __syncthreads();
  if (t == 0) rs_sh = rsqrtf((part[0]+part[1]+part[2]+part[3]) * (1.0f/HIDD) + EPS_);
  __syncthreads();
  float rs = rs_sh;

  float4 w0 = w4[t], w1 = w4[t + 256];
  ushort4 o0, o1;
  o0.x = f2bf(v0.x * rs * (1.f + w0.x));
  o0.y = f2bf(v0.y * rs * (1.f + w0.y));
  o0.z = f2bf(v0.z * rs * (1.f + w0.z));
  o0.w = f2bf(v0.w * rs * (1.f + w0.w));
  o1.x = f2bf(v1.x * rs * (1.f + w1.x));
  o1.y = f2bf(v1.y * rs * (1.f + w1.y));
  o1.z = f2bf(v1.z * rs * (1.f + w1.z));
  o1.w = f2bf(v1.w * rs * (1.f + w1.w));
  ushort4* xr = (ushort4*)(x + (size_t)row * HIDD);
  xr[t] = o0;
  xr[t + 256] = o1;
}

// ---------------------------------------------------------------------------
// 128x128 bf16 MFMA GEMM core (proven path; kept for KV + O-proj).
// ---------------------------------------------------------------------------
template <int OBF>
__device__ __forceinline__ void gemm_core(const unsigned short* __restrict__ Ab,
                                          const unsigned short* __restrict__ Bb,
                                          void* __restrict__ Cv,
                                          int Ndim, int bm, int bn,
                                          unsigned short* Als, unsigned short* Bls) {
  char* ldsA = (char*)Als;
  char* ldsB = (char*)Bls;

  int t   = threadIdx.x;
  int r15 = t & 15;
  int g   = (t & 63) >> 4;
  int w   = t >> 6;
  int wr  = w >> 1, wc = w & 1;

  f32x4 acc[4][4] = {};

  for (int k0 = 0; k0 < KDIM; k0 += 64) {
    __syncthreads();
#pragma unroll
    for (int it = 0; it < 4; ++it) {
      int f      = it * 256 + t;
      int row    = f >> 3;
      int schunk = (f & 7) ^ (row & 7);
      unsigned ldsbase = (unsigned)((it * 256 + (w << 6)) << 4);
      __builtin_amdgcn_global_load_lds(
          (const unsigned int*)(Ab + ((size_t)(bm + row) << 11) + k0 + schunk * 8),
          (unsigned int*)(ldsA + ldsbase), 16, 0, 0);
      __builtin_amdgcn_global_load_lds(
          (const unsigned int*)(Bb + ((size_t)(bn + row) << 11) + k0 + schunk * 8),
          (unsigned int*)(ldsB + ldsbase), 16, 0, 0);
    }
    __syncthreads();

#pragma unroll
    for (int tt = 0; tt < 2; ++tt) {
      bf16x8 af[4], bfv[4];
#pragma unroll
      for (int mi = 0; mi < 4; ++mi) {
        int row = wr * 64 + mi * 16 + r15;
        af[mi] = *(const bf16x8*)(ldsA + row * 128 + (((4 * tt + g) ^ (row & 7)) << 4));
      }
#pragma unroll
      for (int ni = 0; ni < 4; ++ni) {
        int row = wc * 64 + ni * 16 + r15;
        bfv[ni] = *(const bf16x8*)(ldsB + row * 128 + (((4 * tt + g) ^ (row & 7)) << 4));
      }
      __builtin_amdgcn_s_setprio(1);
#pragma unroll
      for (int mi = 0; mi < 4; ++mi)
#pragma unroll
        for (int ni = 0; ni < 4; ++ni)
          acc[mi][ni] = __builtin_amdgcn_mfma_f32_16x16x32_bf16(af[mi], bfv[ni], acc[mi][ni], 0, 0, 0);
      __builtin_amdgcn_s_setprio(0);
    }
  }

#pragma unroll
  for (int mi = 0; mi < 4; ++mi)
#pragma unroll
    for (int ni = 0; ni < 4; ++ni) {
      int col = bn + wc * 64 + ni * 16 + r15;
#pragma unroll
      for (int r = 0; r < 4; ++r) {
        int rowg = bm + wr * 64 + mi * 16 + g * 4 + r;
        if (OBF == 1)
          ((unsigned short*)Cv)[(size_t)rowg * Ndim + col] = f2bf(acc[mi][ni][r]);
        else if (OBF == 3)  // transposed bf16: V^T[d][token]
          ((unsigned short*)Cv)[(size_t)col * MROWS + rowg] = f2bf(acc[mi][ni][r]);
        else
          ((float*)Cv)[(size_t)rowg * Ndim + col] = acc[mi][ni][r];
      }
    }
}

template <int OBF>
__global__ __launch_bounds__(256) void gemm_bf16(const unsigned short* __restrict__ Ab,
                                                 const unsigned short* __restrict__ Bb,
                                                 void* __restrict__ Cv,
                                                 int Ndim) {
  __shared__ unsigned short Als[128 * 64];
  __shared__ unsigned short Bls[128 * 64];
  gemm_core<OBF>(Ab, Bb, Cv, Ndim, blockIdx.y * 128, blockIdx.x * 128, Als, Bls);
}

// K and V GEMMs fused; V stored TRANSPOSED (V^T[d][token]).
__global__ __launch_bounds__(256) void gemm_kv(const unsigned short* __restrict__ Ab,
                                               const unsigned short* __restrict__ Wk,
                                               const unsigned short* __restrict__ Wv,
                                               unsigned short* __restrict__ Ck,
                                               unsigned short* __restrict__ Cvt) {
  __shared__ unsigned short Als[128 * 64];
  __shared__ unsigned short Bls[128 * 64];
  int bx = blockIdx.x;
  if (bx < 4)
    gemm_core<1>(Ab, Wk, (void*)Ck, KV_N, blockIdx.y * 128, bx * 128, Als, Bls);
  else
    gemm_core<3>(Ab, Wv, (void*)Cvt, KV_N, blockIdx.y * 128, (bx & 3) * 128, Als, Bls);
}

// ---------------------------------------------------------------------------
// QG GEMM, 256x256 8-phase counted-vmcnt schedule — CORRECTED LEDGER (r15).
// BM=BN=256, BK=64, 512 thr = 8 waves (2x4), wave tile 128x64.
// KEY FIX vs r14: with wr in {0,1} (128-row wave tiles) and wc in {0..3},
// EVERY RD_A touches BOTH A halves and every RD_B both B halves (different
// halves for different waves).  Buffer liveness: A0 read ph0,ph2; B0 read
// ph0,ph1; A1 read ph4,ph6; B1 read ph4,ph5.  Stages strictly after last
// reader:  ph2:B0h0(te)  ph3:A0h0(te)  ph4:A0h1(te)  ph5:B0h1(te)
//          ph6:B1h0+B1h1(to)  ph7:A1h0+A1h1(to)
// Counted waits (2 loads/thread per half-tile stage):
//   vmcnt(4) @ph3-end: 12 outstanding -> oldest 8 = prev-iter odd tiles
//                      land before ph4 reads of A1/B1.
//   vmcnt(8) @ph7-end: 16 outstanding -> oldest 8 = even tiles land
//                      before next ph0 reads of A0/B0.
// Never 0 in loop; peeled last iteration drains with vmcnt(0) mid-way.
// Epilogue: q half (col<2048) -> bf16*SCALE, gate half -> fp32.
// ---------------------------------------------------------------------------
#define LD8(basep, r, x) \
  (*(const bf16x8*)((basep) + (size_t)(r) * 128 + ((((x) ^ ((r)&7))) << 4)))

#define STAGE_A(bufi, h, tk)                                                   \
  { _Pragma("unroll")                                                          \
    for (int c = 0; c < 2; ++c) {                                              \
      int f = c * 512 + t;                                                     \
      int rr = f >> 3;                                                         \
      int sc = (f & 7) ^ (rr & 7);                                             \
      __builtin_amdgcn_global_load_lds(                                        \
        (const unsigned int*)(Ab + ((size_t)(bm + (h)*128 + rr) << 11) + (tk)*64 + sc*8), \
        (unsigned int*)(lds8 + (bufi)*32768 + (h)*16384 + c*8192 + (w<<10)), 16, 0, 0); \
    } }

#define STAGE_B(bufi, h, tk)                                                   \
  { _Pragma("unroll")                                                          \
    for (int c = 0; c < 2; ++c) {                                              \
      int f = c * 512 + t;                                                     \
      int rr = f >> 3;                                                         \
      int sc = (f & 7) ^ (rr & 7);                                             \
      __builtin_amdgcn_global_load_lds(                                        \
        (const unsigned int*)(Bbp + ((size_t)(bn + (h)*128 + rr) << 11) + (tk)*64 + sc*8), \
        (unsigned int*)(lds8 + 65536 + (bufi)*32768 + (h)*16384 + c*8192 + (w<<10)), 16, 0, 0); \
    } }

#define RD_A(SRC, MIBASE)                                                      \
  { _Pragma("unroll")                                                          \
    for (int mi = 0; mi < 4; ++mi) {                                           \
      int rr = wr * 128 + ((MIBASE) + mi) * 16 + r15;                          \
      afr[mi][0] = LD8(SRC, rr, g);                                            \
      afr[mi][1] = LD8(SRC, rr, 4 + g);                                        \
    } }

#define RD_B(SRC, NIBASE, DST)                                                 \
  { _Pragma("unroll")                                                          \
    for (int ni = 0; ni < 2; ++ni) {                                           \
      int rr = wc * 64 + ((NIBASE) + ni) * 16 + r15;                           \
      DST[ni][0] = LD8(SRC, rr, g);                                            \
      DST[ni][1] = LD8(SRC, rr, 4 + g);                                        \
    } }

#define MFMA_QUAD(MIBASE, NIBASE, BREG)                                        \
  { __builtin_amdgcn_s_setprio(1);                                             \
    _Pragma("unroll")                                                          \
    for (int mi = 0; mi < 4; ++mi)                                             \
      _Pragma("unroll")                                                        \
      for (int ni = 0; ni < 2; ++ni)                                           \
        _Pragma("unroll")                                                      \
        for (int ks = 0; ks < 2; ++ks)                                         \
          acc[(MIBASE)+mi][(NIBASE)+ni] =                                      \
            __builtin_amdgcn_mfma_f32_16x16x32_bf16(afr[mi][ks], BREG[ni][ks], \
                                                    acc[(MIBASE)+mi][(NIBASE)+ni], 0, 0, 0); \
    __builtin_amdgcn_s_setprio(0); }

#define BAR() __builtin_amdgcn_s_barrier()

__global__ __launch_bounds__(512, 2) void gemm_qg256(const unsigned short* __restrict__ Ab,
                                                     const unsigned short* __restrict__ Bbp,
                                                     unsigned short* __restrict__ Cq,
                                                     float* __restrict__ Cg) {
  __shared__ char lds8[131072];
  int t = threadIdx.x;
  int r15 = t & 15, g = (t & 63) >> 4, w = t >> 6;
  int wr = w >> 2, wc = w & 3;
  int bm = blockIdx.y * 256, bn = blockIdx.x * 256;
  char* A0 = lds8;            char* A1 = lds8 + 32768;
  char* B0 = lds8 + 65536;    char* B1 = lds8 + 98304;

  f32x4 acc[8][4] = {};
  bf16x8 afr[4][2], b0r[2][2], b1r[2][2];

  // prologue: K-steps 0 (buf0) and 1 (buf1); wait t0 landed, t1 may fly
  STAGE_A(0, 0, 0); STAGE_A(0, 1, 0); STAGE_B(0, 0, 0); STAGE_B(0, 1, 0);
  STAGE_A(1, 0, 1); STAGE_A(1, 1, 1); STAGE_B(1, 0, 1); STAGE_B(1, 1, 1);
  asm volatile("s_waitcnt vmcnt(8)" ::: "memory");
  BAR();

  for (int i = 0; i < 15; ++i) {        // K-steps 0..29; te<=30, to<=31
    int te = 2 * i + 2, to = 2 * i + 3;
    // ph0: RD A0(lo) + B0(lo); MFMA q(0,0).  No stage (A0/B0 still live).
    RD_A(A0, 0); RD_B(B0, 0, b0r);
    BAR(); MFMA_QUAD(0, 0, b0r); BAR();
    // ph1: RD B0(hi); MFMA q(0,1).  B0 last read here.
    RD_B(B0, 2, b1r);
    BAR(); MFMA_QUAD(0, 2, b1r); BAR();
    // ph2: RD A0(hi); stage B0h0(te); MFMA q(1,0).  A0 last read here.
    RD_A(A0, 4);
    STAGE_B(0, 0, te);
    BAR(); MFMA_QUAD(4, 0, b0r); BAR();
    // ph3: stage A0h0(te); MFMA q(1,1); vmcnt(4): prev odd tiles landed
    STAGE_A(0, 0, te);
    BAR(); MFMA_QUAD(4, 2, b1r);
    asm volatile("s_waitcnt vmcnt(4)" ::: "memory");
    BAR();
    // ph4: RD A1(lo) + B1(lo); stage A0h1(te); MFMA q(0,0)
    RD_A(A1, 0); RD_B(B1, 0, b0r);
    STAGE_A(0, 1, te);
    BAR(); MFMA_QUAD(0, 0, b0r); BAR();
    // ph5: RD B1(hi); stage B0h1(te); MFMA q(0,1).  B1 last read here.
    RD_B(B1, 2, b1r);
    STAGE_B(0, 1, te);
    BAR(); MFMA_QUAD(0, 2, b1r); BAR();
    // ph6: RD A1(hi); stage B1 both halves (to); MFMA q(1,0). A1 last read.
    RD_A(A1, 4);
    STAGE_B(1, 0, to); STAGE_B(1, 1, to);
    BAR(); MFMA_QUAD(4, 0, b0r); BAR();
    // ph7: stage A1 both halves (to); MFMA q(1,1); vmcnt(8): even tiles landed
    STAGE_A(1, 0, to); STAGE_A(1, 1, to);
    BAR(); MFMA_QUAD(4, 2, b1r);
    asm volatile("s_waitcnt vmcnt(8)" ::: "memory");
    BAR();
  }
  // peeled last iteration (K-steps 30,31): no stages; drain at mid-point
  RD_A(A0, 0); RD_B(B0, 0, b0r);
  BAR(); MFMA_QUAD(0, 0, b0r); BAR();
  RD_B(B0, 2, b1r);
  BAR(); MFMA_QUAD(0, 2, b1r); BAR();
  RD_A(A0, 4);
  BAR(); MFMA_QUAD(4, 0, b0r); BAR();
  BAR(); MFMA_QUAD(4, 2, b1r);
  asm volatile("s_waitcnt vmcnt(0)" ::: "memory");
  BAR();
  RD_A(A1, 0); RD_B(B1, 0, b0r);
  BAR(); MFMA_QUAD(0, 0, b0r); BAR();
  RD_B(B1, 2, b1r);
  BAR(); MFMA_QUAD(0, 2, b1r); BAR();
  RD_A(A1, 4);
  BAR(); MFMA_QUAD(4, 0, b0r); BAR();
  BAR(); MFMA_QUAD(4, 2, b1r);

  // epilogue: q half -> bf16*SCALE, gate half -> fp32 (tiles never straddle)
  bool isq = (bn < O_N);
  int colbase = bn + wc * 64;
#pragma unroll
  for (int mi = 0; mi < 8; ++mi) {
    size_t row = (size_t)bm + wr * 128 + mi * 16 + g * 4;
#pragma unroll
    for (int ni = 0; ni < 4; ++ni) {
      int col = colbase + ni * 16 + r15;
#pragma unroll
      for (int r = 0; r < 4; ++r) {
        if (isq) Cq[(row + r) * O_N + col] = f2bf(acc[mi][ni][r] * SCALE_);
        else     Cg[(row + r) * O_N + (col - O_N)] = acc[mi][ni][r];
      }
    }
  }
}

// ---------------------------------------------------------------------------
// bf16 MFMA flash attention v6 (unchanged from round 12).
// ---------------------------------------------------------------------------
__global__ __launch_bounds__(256, 2) void attn_mfma(const unsigned short* __restrict__ qb,
                                                    const float* __restrict__ gateb,
                                                    const unsigned short* __restrict__ kb,
                                                    const unsigned short* __restrict__ vt,
                                                    unsigned short* __restrict__ obuf) {
  __shared__ unsigned short Ks[2][64 * 128];   // [kv][d], chunk^=(kv&7) swizzle
  __shared__ unsigned short Vt[2][128 * 64];   // [d][tok], chunk^=(d&7) swizzle
  char* ldsK0 = (char*)Ks;
  char* ldsV0 = (char*)Vt;

  int t = threadIdx.x;
  int l = t & 63, w = t >> 6;
  int c15 = l & 15, g = l >> 4;
  int bid = blockIdx.x;
  int swz = (bid & 7) * 64 + (bid >> 3);
  int qt = swz & 15, h = (swz >> 4) & 15, b = swz >> 8;
  int kh = h >> 2;                          // G = 4
  size_t rowQ0 = (size_t)b * SS + (size_t)qt * 128;
  size_t rowKbase = (size_t)b * SS;

  bf16x8 qf[2][4];
#pragma unroll
  for (int qi = 0; qi < 2; ++qi)
#pragma unroll
    for (int ks = 0; ks < 4; ++ks)
      qf[qi][ks] = *(const bf16x8*)(qb + (rowQ0 + w * 32 + qi * 16 + c15) * O_N
                                       + h * HDD + g * 8 + ks * 32);

  f32x4 accO[2][8] = {};
  float mrun[2] = {-INFINITY, -INFINITY};
  float lrun[2] = {0.f, 0.f};

#define ISSUE_K(bufi, kt_)                                                     \
  {                                                                            \
    size_t rowK0 = rowKbase + (size_t)(kt_) * 64;                              \
    _Pragma("unroll")                                                          \
    for (int it = 0; it < 4; ++it) {                                           \
      int f = it * 256 + t;                                                    \
      int kv = f >> 4;                                                         \
      int schunk = (f & 15) ^ (kv & 7);                                        \
      unsigned ldsbase = (unsigned)((it * 256 + (w << 6)) << 4);               \
      __builtin_amdgcn_global_load_lds(                                        \
          (const unsigned int*)(kb + (rowK0 + kv) * KV_N + kh * HDD + schunk * 8), \
          (unsigned int*)(ldsK0 + (bufi) * 16384 + ldsbase), 16, 0, 0);        \
    }                                                                          \
  }
#define ISSUE_VT(bufi, kt_)                                                    \
  {                                                                            \
    size_t tokbase = rowKbase + (size_t)(kt_) * 64;                            \
    _Pragma("unroll")                                                          \
    for (int it = 0; it < 4; ++it) {                                           \
      int f = it * 256 + t;                                                    \
      int row = f >> 3;                                                        \
      int schunk = (f & 7) ^ (row & 7);                                        \
      unsigned ldsbase = (unsigned)((it * 256 + (w << 6)) << 4);               \
      __builtin_amdgcn_global_load_lds(                                        \
          (const unsigned int*)(vt + (size_t)(kh * 128 + row) * MROWS + tokbase + schunk * 8), \
          (unsigned int*)(ldsV0 + (bufi) * 16384 + ldsbase), 16, 0, 0);        \
    }                                                                          \
  }

  ISSUE_K(0, 0);
  ISSUE_VT(0, 0);
  asm volatile("s_waitcnt vmcnt(0)" ::: "memory");
  __syncthreads();

  const int NT = SS / 64;
  for (int kt = 0; kt < NT; ++kt) {
    int cur = kt & 1, nxt = cur ^ 1;
    char* ldsK = ldsK0 + cur * 16384;
    char* ldsV = ldsV0 + cur * 16384;

    if (kt + 1 < NT) {
      ISSUE_K(nxt, kt + 1);
      ISSUE_VT(nxt, kt + 1);
    }

    f32x4 accS[2][4] = {};
    __builtin_amdgcn_s_setprio(1);
#pragma unroll
    for (int nf = 0; nf < 4; ++nf) {
      int kvr = nf * 16 + c15;
#pragma unroll
      for (int ks = 0; ks < 4; ++ks) {
        bf16x8 kf = *(const bf16x8*)(ldsK + kvr * 256 + ((((g + 4 * ks) ^ (kvr & 7)) << 4)));
#pragma unroll
        for (int qi = 0; qi < 2; ++qi)
          accS[qi][nf] = __builtin_amdgcn_mfma_f32_16x16x32_bf16(kf, qf[qi][ks], accS[qi][nf], 0, 0, 0);
      }
    }
    __builtin_amdgcn_s_setprio(0);

    float mt[2];
#pragma unroll
    for (int qi = 0; qi < 2; ++qi) {
      float m0 = fmaxf(fmaxf(accS[qi][0][0], accS[qi][0][1]), fmaxf(accS[qi][0][2], accS[qi][0][3]));
#pragma unroll
      for (int nf = 1; nf < 4; ++nf)
        m0 = fmaxf(m0, fmaxf(fmaxf(accS[qi][nf][0], accS[qi][nf][1]), fmaxf(accS[qi][nf][2], accS[qi][nf][3])));
      m0 = fmaxf(m0, __shfl_xor(m0, 16, 64));
      m0 = fmaxf(m0, __shfl_xor(m0, 32, 64));
      mt[qi] = m0;
    }

    bool safe = (mt[0] <= mrun[0] + 8.f) && (mt[1] <= mrun[1] + 8.f);
    if (!__all(safe)) {
#pragma unroll
      for (int qi = 0; qi < 2; ++qi) {
        float mnew = fmaxf(mrun[qi], mt[qi]);
        float al = __expf(mrun[qi] - mnew);
        mrun[qi] = mnew;
        lrun[qi] *= al;
        float alr[4];
#pragma unroll
        for (int r = 0; r < 4; ++r) alr[r] = __shfl(al, g * 4 + r, 16);
#pragma unroll
        for (int df = 0; df < 8; ++df)
#pragma unroll
          for (int r = 0; r < 4; ++r) accO[qi][df][r] *= alr[r];
      }
    }

    u16x8 pfr[2][2];
#pragma unroll
    for (int qi = 0; qi < 2; ++qi) {
      float ps = 0.f;
#pragma unroll
      for (int nf = 0; nf < 4; ++nf) {
        float p0 = __expf(accS[qi][nf][0] - mrun[qi]);
        float p1 = __expf(accS[qi][nf][1] - mrun[qi]);
        float p2 = __expf(accS[qi][nf][2] - mrun[qi]);
        float p3 = __expf(accS[qi][nf][3] - mrun[qi]);
        ps += (p0 + p1) + (p2 + p3);
        pfr[qi][nf >> 1][(nf & 1) * 4 + 0] = f2bf(p0);
        pfr[qi][nf >> 1][(nf & 1) * 4 + 1] = f2bf(p1);
        pfr[qi][nf >> 1][(nf & 1) * 4 + 2] = f2bf(p2);
        pfr[qi][nf >> 1][(nf & 1) * 4 + 3] = f2bf(p3);
      }
      ps += __shfl_xor(ps, 16, 64);
      ps += __shfl_xor(ps, 32, 64);
      lrun[qi] += ps;
    }

    __builtin_amdgcn_s_setprio(1);
#pragma unroll
    for (int ks2 = 0; ks2 < 2; ++ks2) {
      bf16x8 pf0 = __builtin_bit_cast(bf16x8, pfr[0][ks2]);
      bf16x8 pf1 = __builtin_bit_cast(bf16x8, pfr[1][ks2]);
      int c0 = 4 * ks2 + (g >> 1);
      int half8 = (g & 1) * 8;
#pragma unroll
      for (int df = 0; df < 8; ++df) {
        int d = df * 16 + c15;
        const char* vrow = ldsV + d * 128;
        ushort4 lo = *(const ushort4*)(vrow + (((c0)     ^ (d & 7)) << 4) + half8);
        ushort4 hi = *(const ushort4*)(vrow + (((c0 + 2) ^ (d & 7)) << 4) + half8);
        u16x8 v8 = {lo.x, lo.y, lo.z, lo.w, hi.x, hi.y, hi.z, hi.w};
        bf16x8 vf = __builtin_bit_cast(bf16x8, v8);
        accO[0][df] = __builtin_amdgcn_mfma_f32_16x16x32_bf16(pf0, vf, accO[0][df], 0, 0, 0);
        accO[1][df] = __builtin_amdgcn_mfma_f32_16x16x32_bf16(pf1, vf, accO[1][df], 0, 0, 0);
      }
    }
    __builtin_amdgcn_s_setprio(0);

    if (kt + 1 < NT) {
      asm volatile("s_waitcnt vmcnt(0)" ::: "memory");
    }
    __syncthreads();
  }

#pragma unroll
  for (int qi = 0; qi < 2; ++qi) {
    float invL = 1.f / lrun[qi];
    float ivr[4];
#pragma unroll
    for (int r = 0; r < 4; ++r) ivr[r] = __shfl(invL, g * 4 + r, 16);
#pragma unroll
    for (int r = 0; r < 4; ++r) {
      size_t row = rowQ0 + w * 32 + qi * 16 + g * 4 + r;
#pragma unroll
      for (int df = 0; df < 8; ++df) {
        int d = df * 16 + c15;
        float gt = gateb[row * (size_t)O_N + h * HDD + d];
        float sg = 1.f / (1.f + __expf(-gt));
        obuf[row * (size_t)O_N + h * HDD + d] = f2bf(accO[qi][df][r] * ivr[r] * sg);
      }
    }
  }
#undef ISSUE_K
#undef ISSUE_VT
}

// ---------------------------------------------------------------------------
// Launch
// ---------------------------------------------------------------------------
extern "C" void kernel_launch(void* const* d_in, const int* in_sizes, int n_in,
                              void* d_out, int out_size, void* d_ws, size_t ws_size,
                              hipStream_t stream) {
  const float* hs = (const float*)d_in[0];
  // d_in[1] = position_ids (unused by the reference)
  const float* Wq = (const float*)d_in[2];
  const float* Wk = (const float*)d_in[3];
  const float* Wv = (const float*)d_in[4];
  const float* Wo = (const float*)d_in[5];
  const float* nw = (const float*)d_in[6];
  float* out = (float*)d_out;

  // workspace (~121 MB): gate fp32 | bf16: qb,kb,vt,x,ob | bf16 W (contiguous)
  float* gateb = (float*)d_ws;
  unsigned short* qb16 = (unsigned short*)(gateb + (size_t)MROWS * O_N);
  unsigned short* kb16 = qb16 + (size_t)MROWS * O_N;
  unsigned short* vt16 = kb16 + (size_t)MROWS * KV_N;   // V^T [512][4096]
  unsigned short* xb   = vt16 + (size_t)KV_N * MROWS;
  unsigned short* ob   = xb   + (size_t)MROWS * HIDD;
  unsigned short* wqb  = ob   + (size_t)MROWS * O_N;
  unsigned short* wkb  = wqb  + (size_t)QG_N * KDIM;
  unsigned short* wvb  = wkb  + (size_t)KV_N * KDIM;
  unsigned short* wob  = wvb  + (size_t)KV_N * KDIM;

  const int tot4 = (QG_N + KV_N + KV_N + O_N) * KDIM / 4;
  f2bf_all<<<(tot4 + 255) / 256, 256, 0, stream>>>(Wq, Wk, Wv, Wo, wqb);
  rmsnorm_k<<<MROWS, 256, 0, stream>>>(hs, nw, xb);

  gemm_qg256<<<dim3(QG_N/256, MROWS/256), 512, 0, stream>>>(xb, wqb, qb16, gateb);
  gemm_kv<<<dim3(8, MROWS/128), 256, 0, stream>>>(xb, wkb, wvb, kb16, vt16);
  attn_mfma<<<dim3(512), 256, 0, stream>>>(qb16, gateb, kb16, vt16, ob);
  gemm_bf16<0><<<dim3(O_N/128, MROWS/128), 256, 0, stream>>>(ob, wob, out, O_N);
}

// Round 17
// 252.128 us; speedup vs baseline: 7.3813x; 1.0406x over previous
//
#include <hip/hip_runtime.h>
#include <math.h>

// Problem constants (from reference)
#define BB    2
#define SS    2048
#define HIDD  2048
#define NHH   16
#define NKVV  4
#define HDD   128
#define MROWS 4096            // B*S
#define QG_N  4096            // 2*NH*HD
#define KV_N  512             // NKV*HD
#define O_N   2048            // NH*HD
#define KDIM  2048            // shared K for all four GEMMs (row stride of A and W)
#define EPS_  1e-6f
#define SCALE_ 0.08838834764831845f   // 1/sqrt(128)

typedef __attribute__((ext_vector_type(8))) __bf16 bf16x8;
typedef __attribute__((ext_vector_type(8))) unsigned short u16x8;
typedef __attribute__((ext_vector_type(4))) float f32x4;

__device__ __forceinline__ unsigned short f2bf(float f) {
  return __builtin_bit_cast(unsigned short, (__bf16)f);   // RNE via v_cvt
}

// ---------------------------------------------------------------------------
// fp32 -> bf16 convert for all four weights in ONE dispatch.
// ---------------------------------------------------------------------------
__global__ __launch_bounds__(256) void f2bf_all(const float* __restrict__ Wq,
                                                const float* __restrict__ Wk,
                                                const float* __restrict__ Wv,
                                                const float* __restrict__ Wo,
                                                unsigned short* __restrict__ dst) {
  const int s0 = QG_N * KDIM / 4;
  const int s1 = s0 + KV_N * KDIM / 4;
  const int s2 = s1 + KV_N * KDIM / 4;
  const int s3 = s2 + O_N * KDIM / 4;
  int i = blockIdx.x * 256 + threadIdx.x;
  if (i >= s3) return;
  float4 v;
  if (i < s0)      v = ((const float4*)Wq)[i];
  else if (i < s1) v = ((const float4*)Wk)[i - s0];
  else if (i < s2) v = ((const float4*)Wv)[i - s1];
  else             v = ((const float4*)Wo)[i - s2];
  ushort4 u;
  u.x = f2bf(v.x); u.y = f2bf(v.y); u.z = f2bf(v.z); u.w = f2bf(v.w);
  ((ushort4*)dst)[i] = u;
}

// ---------------------------------------------------------------------------
// RMSNorm -> bf16 x.  One block per row.
// ---------------------------------------------------------------------------
__global__ __launch_bounds__(256) void rmsnorm_k(const float* __restrict__ h,
                                                 const float* __restrict__ w,
                                                 unsigned short* __restrict__ x) {
  int row = blockIdx.x;
  int t = threadIdx.x;
  const float4* hr = (const float4*)(h + (size_t)row * HIDD);
  const float4* w4 = (const float4*)w;

  float4 v0 = hr[t], v1 = hr[t + 256];
  float ss = v0.x*v0.x + v0.y*v0.y + v0.z*v0.z + v0.w*v0.w
           + v1.x*v1.x + v1.y*v1.y + v1.z*v1.z + v1.w*v1.w;
#pragma unroll
  for (int off = 32; off > 0; off >>= 1) ss += __shfl_down(ss, off, 64);

  __shared__ float part[4];
  __shared__ float rs_sh;
  if ((t & 63) == 0) part[t >> 6] = ss;
  __syncthreads();
  if (t == 0) rs_sh = rsqrtf((part[0]+part[1]+part[2]+part[3]) * (1.0f/HIDD) + EPS_);
  __syncthreads();
  float rs = rs_sh;

  float4 w0 = w4[t], w1 = w4[t + 256];
  ushort4 o0, o1;
  o0.x = f2bf(v0.x * rs * (1.f + w0.x));
  o0.y = f2bf(v0.y * rs * (1.f + w0.y));
  o0.z = f2bf(v0.z * rs * (1.f + w0.z));
  o0.w = f2bf(v0.w * rs * (1.f + w0.w));
  o1.x = f2bf(v1.x * rs * (1.f + w1.x));
  o1.y = f2bf(v1.y * rs * (1.f + w1.y));
  o1.z = f2bf(v1.z * rs * (1.f + w1.z));
  o1.w = f2bf(v1.w * rs * (1.f + w1.w));
  ushort4* xr = (ushort4*)(x + (size_t)row * HIDD);
  xr[t] = o0;
  xr[t + 256] = o1;
}

// ---------------------------------------------------------------------------
// 128x128 bf16 MFMA GEMM core (proven path; kept for KV + O-proj).
// OBF: 0 = fp32 out, 1 = bf16 out, 3 = bf16 transposed V^T[d][tok'] with the
// sigma bit-permutation folded into the token column (tok' = (tok&~63)|sig):
//   sig = (tok&32) + ((tok&12)<<1) + ((tok&16)>>2) + (tok&3)
// sigma keeps bits 0-1, so the 4-token 8B store runs are preserved.
// ---------------------------------------------------------------------------
template <int OBF>
__device__ __forceinline__ void gemm_core(const unsigned short* __restrict__ Ab,
                                          const unsigned short* __restrict__ Bb,
                                          void* __restrict__ Cv,
                                          int Ndim, int bm, int bn,
                                          unsigned short* Als, unsigned short* Bls) {
  char* ldsA = (char*)Als;
  char* ldsB = (char*)Bls;

  int t   = threadIdx.x;
  int r15 = t & 15;
  int g   = (t & 63) >> 4;
  int w   = t >> 6;
  int wr  = w >> 1, wc = w & 1;

  f32x4 acc[4][4] = {};

  for (int k0 = 0; k0 < KDIM; k0 += 64) {
    __syncthreads();
#pragma unroll
    for (int it = 0; it < 4; ++it) {
      int f      = it * 256 + t;
      int row    = f >> 3;
      int schunk = (f & 7) ^ (row & 7);
      unsigned ldsbase = (unsigned)((it * 256 + (w << 6)) << 4);
      __builtin_amdgcn_global_load_lds(
          (const unsigned int*)(Ab + ((size_t)(bm + row) << 11) + k0 + schunk * 8),
          (unsigned int*)(ldsA + ldsbase), 16, 0, 0);
      __builtin_amdgcn_global_load_lds(
          (const unsigned int*)(Bb + ((size_t)(bn + row) << 11) + k0 + schunk * 8),
          (unsigned int*)(ldsB + ldsbase), 16, 0, 0);
    }
    __syncthreads();

#pragma unroll
    for (int tt = 0; tt < 2; ++tt) {
      bf16x8 af[4], bfv[4];
#pragma unroll
      for (int mi = 0; mi < 4; ++mi) {
        int row = wr * 64 + mi * 16 + r15;
        af[mi] = *(const bf16x8*)(ldsA + row * 128 + (((4 * tt + g) ^ (row & 7)) << 4));
      }
#pragma unroll
      for (int ni = 0; ni < 4; ++ni) {
        int row = wc * 64 + ni * 16 + r15;
        bfv[ni] = *(const bf16x8*)(ldsB + row * 128 + (((4 * tt + g) ^ (row & 7)) << 4));
      }
      __builtin_amdgcn_s_setprio(1);
#pragma unroll
      for (int mi = 0; mi < 4; ++mi)
#pragma unroll
        for (int ni = 0; ni < 4; ++ni)
          acc[mi][ni] = __builtin_amdgcn_mfma_f32_16x16x32_bf16(af[mi], bfv[ni], acc[mi][ni], 0, 0, 0);
      __builtin_amdgcn_s_setprio(0);
    }
  }

#pragma unroll
  for (int mi = 0; mi < 4; ++mi)
#pragma unroll
    for (int ni = 0; ni < 4; ++ni) {
      int col = bn + wc * 64 + ni * 16 + r15;
#pragma unroll
      for (int r = 0; r < 4; ++r) {
        int rowg = bm + wr * 64 + mi * 16 + g * 4 + r;
        if (OBF == 1)
          ((unsigned short*)Cv)[(size_t)rowg * Ndim + col] = f2bf(acc[mi][ni][r]);
        else if (OBF == 3) {  // transposed bf16 V^T[d][tok'], sigma folded
          int t6 = rowg & 63;
          int sig = (t6 & 32) + ((t6 & 12) << 1) + ((t6 & 16) >> 2) + (t6 & 3);
          int tokp = (rowg & ~63) | sig;
          ((unsigned short*)Cv)[(size_t)col * MROWS + tokp] = f2bf(acc[mi][ni][r]);
        } else
          ((float*)Cv)[(size_t)rowg * Ndim + col] = acc[mi][ni][r];
      }
    }
}

template <int OBF>
__global__ __launch_bounds__(256) void gemm_bf16(const unsigned short* __restrict__ Ab,
                                                 const unsigned short* __restrict__ Bb,
                                                 void* __restrict__ Cv,
                                                 int Ndim) {
  __shared__ unsigned short Als[128 * 64];
  __shared__ unsigned short Bls[128 * 64];
  gemm_core<OBF>(Ab, Bb, Cv, Ndim, blockIdx.y * 128, blockIdx.x * 128, Als, Bls);
}

// K and V GEMMs fused; V stored TRANSPOSED + sigma-permuted (V^T[d][tok']).
__global__ __launch_bounds__(256) void gemm_kv(const unsigned short* __restrict__ Ab,
                                               const unsigned short* __restrict__ Wk,
                                               const unsigned short* __restrict__ Wv,
                                               unsigned short* __restrict__ Ck,
                                               unsigned short* __restrict__ Cvt) {
  __shared__ unsigned short Als[128 * 64];
  __shared__ unsigned short Bls[128 * 64];
  int bx = blockIdx.x;
  if (bx < 4)
    gemm_core<1>(Ab, Wk, (void*)Ck, KV_N, blockIdx.y * 128, bx * 128, Als, Bls);
  else
    gemm_core<3>(Ab, Wv, (void*)Cvt, KV_N, blockIdx.y * 128, (bx & 3) * 128, Als, Bls);
}

// ---------------------------------------------------------------------------
// QG GEMM, 256x256 8-phase counted-vmcnt schedule (r15-corrected ledger).
// ---------------------------------------------------------------------------
#define LD8(basep, r, x) \
  (*(const bf16x8*)((basep) + (size_t)(r) * 128 + ((((x) ^ ((r)&7))) << 4)))

#define STAGE_A(bufi, h, tk)                                                   \
  { _Pragma("unroll")                                                          \
    for (int c = 0; c < 2; ++c) {                                              \
      int f = c * 512 + t;                                                     \
      int rr = f >> 3;                                                         \
      int sc = (f & 7) ^ (rr & 7);                                             \
      __builtin_amdgcn_global_load_lds(                                        \
        (const unsigned int*)(Ab + ((size_t)(bm + (h)*128 + rr) << 11) + (tk)*64 + sc*8), \
        (unsigned int*)(lds8 + (bufi)*32768 + (h)*16384 + c*8192 + (w<<10)), 16, 0, 0); \
    } }

#define STAGE_B(bufi, h, tk)                                                   \
  { _Pragma("unroll")                                                          \
    for (int c = 0; c < 2; ++c) {                                              \
      int f = c * 512 + t;                                                     \
      int rr = f >> 3;                                                         \
      int sc = (f & 7) ^ (rr & 7);                                             \
      __builtin_amdgcn_global_load_lds(                                        \
        (const unsigned int*)(Bbp + ((size_t)(bn + (h)*128 + rr) << 11) + (tk)*64 + sc*8), \
        (unsigned int*)(lds8 + 65536 + (bufi)*32768 + (h)*16384 + c*8192 + (w<<10)), 16, 0, 0); \
    } }

#define RD_A(SRC, MIBASE)                                                      \
  { _Pragma("unroll")                                                          \
    for (int mi = 0; mi < 4; ++mi) {                                           \
      int rr = wr * 128 + ((MIBASE) + mi) * 16 + r15;                          \
      afr[mi][0] = LD8(SRC, rr, g);                                            \
      afr[mi][1] = LD8(SRC, rr, 4 + g);                                        \
    } }

#define RD_B(SRC, NIBASE, DST)                                                 \
  { _Pragma("unroll")                                                          \
    for (int ni = 0; ni < 2; ++ni) {                                           \
      int rr = wc * 64 + ((NIBASE) + ni) * 16 + r15;                           \
      DST[ni][0] = LD8(SRC, rr, g);                                            \
      DST[ni][1] = LD8(SRC, rr, 4 + g);                                        \
    } }

#define MFMA_QUAD(MIBASE, NIBASE, BREG)                                        \
  { __builtin_amdgcn_s_setprio(1);                                             \
    _Pragma("unroll")                                                          \
    for (int mi = 0; mi < 4; ++mi)                                             \
      _Pragma("unroll")                                                        \
      for (int ni = 0; ni < 2; ++ni)                                           \
        _Pragma("unroll")                                                      \
        for (int ks = 0; ks < 2; ++ks)                                         \
          acc[(MIBASE)+mi][(NIBASE)+ni] =                                      \
            __builtin_amdgcn_mfma_f32_16x16x32_bf16(afr[mi][ks], BREG[ni][ks], \
                                                    acc[(MIBASE)+mi][(NIBASE)+ni], 0, 0, 0); \
    __builtin_amdgcn_s_setprio(0); }

#define BAR() __builtin_amdgcn_s_barrier()

__global__ __launch_bounds__(512, 2) void gemm_qg256(const unsigned short* __restrict__ Ab,
                                                     const unsigned short* __restrict__ Bbp,
                                                     unsigned short* __restrict__ Cq,
                                                     float* __restrict__ Cg) {
  __shared__ char lds8[131072];
  int t = threadIdx.x;
  int r15 = t & 15, g = (t & 63) >> 4, w = t >> 6;
  int wr = w >> 2, wc = w & 3;
  int bm = blockIdx.y * 256, bn = blockIdx.x * 256;
  char* A0 = lds8;            char* A1 = lds8 + 32768;
  char* B0 = lds8 + 65536;    char* B1 = lds8 + 98304;

  f32x4 acc[8][4] = {};
  bf16x8 afr[4][2], b0r[2][2], b1r[2][2];

  // prologue: K-steps 0 (buf0) and 1 (buf1); wait t0 landed, t1 may fly
  STAGE_A(0, 0, 0); STAGE_A(0, 1, 0); STAGE_B(0, 0, 0); STAGE_B(0, 1, 0);
  STAGE_A(1, 0, 1); STAGE_A(1, 1, 1); STAGE_B(1, 0, 1); STAGE_B(1, 1, 1);
  asm volatile("s_waitcnt vmcnt(8)" ::: "memory");
  BAR();

  for (int i = 0; i < 15; ++i) {        // K-steps 0..29; te<=30, to<=31
    int te = 2 * i + 2, to = 2 * i + 3;
    // ph0: RD A0(lo) + B0(lo); MFMA q(0,0).  No stage (A0/B0 still live).
    RD_A(A0, 0); RD_B(B0, 0, b0r);
    BAR(); MFMA_QUAD(0, 0, b0r); BAR();
    // ph1: RD B0(hi); MFMA q(0,1).  B0 last read here.
    RD_B(B0, 2, b1r);
    BAR(); MFMA_QUAD(0, 2, b1r); BAR();
    // ph2: RD A0(hi); stage B0h0(te); MFMA q(1,0).  A0 last read here.
    RD_A(A0, 4);
    STAGE_B(0, 0, te);
    BAR(); MFMA_QUAD(4, 0, b0r); BAR();
    // ph3: stage A0h0(te); MFMA q(1,1); vmcnt(4): prev odd tiles landed
    STAGE_A(0, 0, te);
    BAR(); MFMA_QUAD(4, 2, b1r);
    asm volatile("s_waitcnt vmcnt(4)" ::: "memory");
    BAR();
    // ph4: RD A1(lo) + B1(lo); stage A0h1(te); MFMA q(0,0)
    RD_A(A1, 0); RD_B(B1, 0, b0r);
    STAGE_A(0, 1, te);
    BAR(); MFMA_QUAD(0, 0, b0r); BAR();
    // ph5: RD B1(hi); stage B0h1(te); MFMA q(0,1).  B1 last read here.
    RD_B(B1, 2, b1r);
    STAGE_B(0, 1, te);
    BAR(); MFMA_QUAD(0, 2, b1r); BAR();
    // ph6: RD A1(hi); stage B1 both halves (to); MFMA q(1,0). A1 last read.
    RD_A(A1, 4);
    STAGE_B(1, 0, to); STAGE_B(1, 1, to);
    BAR(); MFMA_QUAD(4, 0, b0r); BAR();
    // ph7: stage A1 both halves (to); MFMA q(1,1); vmcnt(8): even tiles landed
    STAGE_A(1, 0, to); STAGE_A(1, 1, to);
    BAR(); MFMA_QUAD(4, 2, b1r);
    asm volatile("s_waitcnt vmcnt(8)" ::: "memory");
    BAR();
  }
  // peeled last iteration (K-steps 30,31): no stages; drain at mid-point
  RD_A(A0, 0); RD_B(B0, 0, b0r);
  BAR(); MFMA_QUAD(0, 0, b0r); BAR();
  RD_B(B0, 2, b1r);
  BAR(); MFMA_QUAD(0, 2, b1r); BAR();
  RD_A(A0, 4);
  BAR(); MFMA_QUAD(4, 0, b0r); BAR();
  BAR(); MFMA_QUAD(4, 2, b1r);
  asm volatile("s_waitcnt vmcnt(0)" ::: "memory");
  BAR();
  RD_A(A1, 0); RD_B(B1, 0, b0r);
  BAR(); MFMA_QUAD(0, 0, b0r); BAR();
  RD_B(B1, 2, b1r);
  BAR(); MFMA_QUAD(0, 2, b1r); BAR();
  RD_A(A1, 4);
  BAR(); MFMA_QUAD(4, 0, b0r); BAR();
  BAR(); MFMA_QUAD(4, 2, b1r);

  // epilogue: q half -> bf16*SCALE, gate half -> fp32 (tiles never straddle)
  bool isq = (bn < O_N);
  int colbase = bn + wc * 64;
#pragma unroll
  for (int mi = 0; mi < 8; ++mi) {
    size_t row = (size_t)bm + wr * 128 + mi * 16 + g * 4;
#pragma unroll
    for (int ni = 0; ni < 4; ++ni) {
      int col = colbase + ni * 16 + r15;
#pragma unroll
      for (int r = 0; r < 4; ++r) {
        if (isq) Cq[(row + r) * O_N + col] = f2bf(acc[mi][ni][r] * SCALE_);
        else     Cg[(row + r) * O_N + (col - O_N)] = acc[mi][ni][r];
      }
    }
  }
}

// ---------------------------------------------------------------------------
// bf16 MFMA flash attention v7 = v6 with sigma folded into the V^T buffer:
// PV B-fragment is ONE swizzled b128 read (chunk (g+4*ks2)^(d&7)) — operand
// bits identical to v6's two-b64 assembly, bank conflicts back to the K-read
// floor.  Everything else unchanged.
// ---------------------------------------------------------------------------
__global__ __launch_bounds__(256, 2) void attn_mfma(const unsigned short* __restrict__ qb,
                                                    const float* __restrict__ gateb,
                                                    const unsigned short* __restrict__ kb,
                                                    const unsigned short* __restrict__ vt,
                                                    unsigned short* __restrict__ obuf) {
  __shared__ unsigned short Ks[2][64 * 128];   // [kv][d], chunk^=(kv&7) swizzle
  __shared__ unsigned short Vt[2][128 * 64];   // [d][sig(tok)], chunk^=(d&7) swizzle
  char* ldsK0 = (char*)Ks;
  char* ldsV0 = (char*)Vt;

  int t = threadIdx.x;
  int l = t & 63, w = t >> 6;
  int c15 = l & 15, g = l >> 4;
  int bid = blockIdx.x;
  int swz = (bid & 7) * 64 + (bid >> 3);
  int qt = swz & 15, h = (swz >> 4) & 15, b = swz >> 8;
  int kh = h >> 2;                          // G = 4
  size_t rowQ0 = (size_t)b * SS + (size_t)qt * 128;
  size_t rowKbase = (size_t)b * SS;

  bf16x8 qf[2][4];
#pragma unroll
  for (int qi = 0; qi < 2; ++qi)
#pragma unroll
    for (int ks = 0; ks < 4; ++ks)
      qf[qi][ks] = *(const bf16x8*)(qb + (rowQ0 + w * 32 + qi * 16 + c15) * O_N
                                       + h * HDD + g * 8 + ks * 32);

  f32x4 accO[2][8] = {};
  float mrun[2] = {-INFINITY, -INFINITY};
  float lrun[2] = {0.f, 0.f};

#define ISSUE_K(bufi, kt_)                                                     \
  {                                                                            \
    size_t rowK0 = rowKbase + (size_t)(kt_) * 64;                              \
    _Pragma("unroll")                                                          \
    for (int it = 0; it < 4; ++it) {                                           \
      int f = it * 256 + t;                                                    \
      int kv = f >> 4;                                                         \
      int schunk = (f & 15) ^ (kv & 7);                                        \
      unsigned ldsbase = (unsigned)((it * 256 + (w << 6)) << 4);               \
      __builtin_amdgcn_global_load_lds(                                        \
          (const unsigned int*)(kb + (rowK0 + kv) * KV_N + kh * HDD + schunk * 8), \
          (unsigned int*)(ldsK0 + (bufi) * 16384 + ldsbase), 16, 0, 0);        \
    }                                                                          \
  }
#define ISSUE_VT(bufi, kt_)                                                    \
  {                                                                            \
    size_t tokbase = rowKbase + (size_t)(kt_) * 64;                            \
    _Pragma("unroll")                                                          \
    for (int it = 0; it < 4; ++it) {                                           \
      int f = it * 256 + t;                                                    \
      int row = f >> 3;                                                        \
      int schunk = (f & 7) ^ (row & 7);                                        \
      unsigned ldsbase = (unsigned)((it * 256 + (w << 6)) << 4);               \
      __builtin_amdgcn_global_load_lds(                                        \
          (const unsigned int*)(vt + (size_t)(kh * 128 + row) * MROWS + tokbase + schunk * 8), \
          (unsigned int*)(ldsV0 + (bufi) * 16384 + ldsbase), 16, 0, 0);        \
    }                                                                          \
  }

  ISSUE_K(0, 0);
  ISSUE_VT(0, 0);
  asm volatile("s_waitcnt vmcnt(0)" ::: "memory");
  __syncthreads();

  const int NT = SS / 64;
  for (int kt = 0; kt < NT; ++kt) {
    int cur = kt & 1, nxt = cur ^ 1;
    char* ldsK = ldsK0 + cur * 16384;
    char* ldsV = ldsV0 + cur * 16384;

    if (kt + 1 < NT) {
      ISSUE_K(nxt, kt + 1);
      ISSUE_VT(nxt, kt + 1);
    }

    f32x4 accS[2][4] = {};
    __builtin_amdgcn_s_setprio(1);
#pragma unroll
    for (int nf = 0; nf < 4; ++nf) {
      int kvr = nf * 16 + c15;
#pragma unroll
      for (int ks = 0; ks < 4; ++ks) {
        bf16x8 kf = *(const bf16x8*)(ldsK + kvr * 256 + ((((g + 4 * ks) ^ (kvr & 7)) << 4)));
#pragma unroll
        for (int qi = 0; qi < 2; ++qi)
          accS[qi][nf] = __builtin_amdgcn_mfma_f32_16x16x32_bf16(kf, qf[qi][ks], accS[qi][nf], 0, 0, 0);
      }
    }
    __builtin_amdgcn_s_setprio(0);

    float mt[2];
#pragma unroll
    for (int qi = 0; qi < 2; ++qi) {
      float m0 = fmaxf(fmaxf(accS[qi][0][0], accS[qi][0][1]), fmaxf(accS[qi][0][2], accS[qi][0][3]));
#pragma unroll
      for (int nf = 1; nf < 4; ++nf)
        m0 = fmaxf(m0, fmaxf(fmaxf(accS[qi][nf][0], accS[qi][nf][1]), fmaxf(accS[qi][nf][2], accS[qi][nf][3])));
      m0 = fmaxf(m0, __shfl_xor(m0, 16, 64));
      m0 = fmaxf(m0, __shfl_xor(m0, 32, 64));
      mt[qi] = m0;
    }

    bool safe = (mt[0] <= mrun[0] + 8.f) && (mt[1] <= mrun[1] + 8.f);
    if (!__all(safe)) {
#pragma unroll
      for (int qi = 0; qi < 2; ++qi) {
        float mnew = fmaxf(mrun[qi], mt[qi]);
        float al = __expf(mrun[qi] - mnew);
        mrun[qi] = mnew;
        lrun[qi] *= al;
        float alr[4];
#pragma unroll
        for (int r = 0; r < 4; ++r) alr[r] = __shfl(al, g * 4 + r, 16);
#pragma unroll
        for (int df = 0; df < 8; ++df)
#pragma unroll
          for (int r = 0; r < 4; ++r) accO[qi][df][r] *= alr[r];
      }
    }

    u16x8 pfr[2][2];
#pragma unroll
    for (int qi = 0; qi < 2; ++qi) {
      float ps = 0.f;
#pragma unroll
      for (int nf = 0; nf < 4; ++nf) {
        float p0 = __expf(accS[qi][nf][0] - mrun[qi]);
        float p1 = __expf(accS[qi][nf][1] - mrun[qi]);
        float p2 = __expf(accS[qi][nf][2] - mrun[qi]);
        float p3 = __expf(accS[qi][nf][3] - mrun[qi]);
        ps += (p0 + p1) + (p2 + p3);
        pfr[qi][nf >> 1][(nf & 1) * 4 + 0] = f2bf(p0);
        pfr[qi][nf >> 1][(nf & 1) * 4 + 1] = f2bf(p1);
        pfr[qi][nf >> 1][(nf & 1) * 4 + 2] = f2bf(p2);
        pfr[qi][nf >> 1][(nf & 1) * 4 + 3] = f2bf(p3);
      }
      ps += __shfl_xor(ps, 16, 64);
      ps += __shfl_xor(ps, 32, 64);
      lrun[qi] += ps;
    }

    // O += P V : 32 MFMA.  A = pfr (own regs), B = ONE b128 from sigma-space Vt
    __builtin_amdgcn_s_setprio(1);
#pragma unroll
    for (int ks2 = 0; ks2 < 2; ++ks2) {
      bf16x8 pf0 = __builtin_bit_cast(bf16x8, pfr[0][ks2]);
      bf16x8 pf1 = __builtin_bit_cast(bf16x8, pfr[1][ks2]);
#pragma unroll
      for (int df = 0; df < 8; ++df) {
        int d = df * 16 + c15;
        bf16x8 vf = *(const bf16x8*)(ldsV + d * 128 + ((((g + 4 * ks2) ^ (d & 7)) << 4)));
        accO[0][df] = __builtin_amdgcn_mfma_f32_16x16x32_bf16(pf0, vf, accO[0][df], 0, 0, 0);
        accO[1][df] = __builtin_amdgcn_mfma_f32_16x16x32_bf16(pf1, vf, accO[1][df], 0, 0, 0);
      }
    }
    __builtin_amdgcn_s_setprio(0);

    if (kt + 1 < NT) {
      asm volatile("s_waitcnt vmcnt(0)" ::: "memory");
    }
    __syncthreads();
  }

#pragma unroll
  for (int qi = 0; qi < 2; ++qi) {
    float invL = 1.f / lrun[qi];
    float ivr[4];
#pragma unroll
    for (int r = 0; r < 4; ++r) ivr[r] = __shfl(invL, g * 4 + r, 16);
#pragma unroll
    for (int r = 0; r < 4; ++r) {
      size_t row = rowQ0 + w * 32 + qi * 16 + g * 4 + r;
#pragma unroll
      for (int df = 0; df < 8; ++df) {
        int d = df * 16 + c15;
        float gt = gateb[row * (size_t)O_N + h * HDD + d];
        float sg = 1.f / (1.f + __expf(-gt));
        obuf[row * (size_t)O_N + h * HDD + d] = f2bf(accO[qi][df][r] * ivr[r] * sg);
      }
    }
  }
#undef ISSUE_K
#undef ISSUE_VT
}

// ---------------------------------------------------------------------------
// Launch
// ---------------------------------------------------------------------------
extern "C" void kernel_launch(void* const* d_in, const int* in_sizes, int n_in,
                              void* d_out, int out_size, void* d_ws, size_t ws_size,
                              hipStream_t stream) {
  const float* hs = (const float*)d_in[0];
  // d_in[1] = position_ids (unused by the reference)
  const float* Wq = (const float*)d_in[2];
  const float* Wk = (const float*)d_in[3];
  const float* Wv = (const float*)d_in[4];
  const float* Wo = (const float*)d_in[5];
  const float* nw = (const float*)d_in[6];
  float* out = (float*)d_out;

  // workspace (~121 MB): gate fp32 | bf16: qb,kb,vt,x,ob | bf16 W (contiguous)
  float* gateb = (float*)d_ws;
  unsigned short* qb16 = (unsigned short*)(gateb + (size_t)MROWS * O_N);
  unsigned short* kb16 = qb16 + (size_t)MROWS * O_N;
  unsigned short* vt16 = kb16 + (size_t)MROWS * KV_N;   // V^T [512][4096], sigma-permuted
  unsigned short* xb   = vt16 + (size_t)KV_N * MROWS;
  unsigned short* ob   = xb   + (size_t)MROWS * HIDD;
  unsigned short* wqb  = ob   + (size_t)MROWS * O_N;
  unsigned short* wkb  = wqb  + (size_t)QG_N * KDIM;
  unsigned short* wvb  = wkb  + (size_t)KV_N * KDIM;
  unsigned short* wob  = wvb  + (size_t)KV_N * KDIM;

  const int tot4 = (QG_N + KV_N + KV_N + O_N) * KDIM / 4;
  f2bf_all<<<(tot4 + 255) / 256, 256, 0, stream>>>(Wq, Wk, Wv, Wo, wqb);
  rmsnorm_k<<<MROWS, 256, 0, stream>>>(hs, nw, xb);

  gemm_qg256<<<dim3(QG_N/256, MROWS/256), 512, 0, stream>>>(xb, wqb, qb16, gateb);
  gemm_kv<<<dim3(8, MROWS/128), 256, 0, stream>>>(xb, wkb, wvb, kb16, vt16);
  attn_mfma<<<dim3(512), 256, 0, stream>>>(qb16, gateb, kb16, vt16, ob);
  gemm_bf16<0><<<dim3(O_N/128, MROWS/128), 256, 0, stream>>>(ob, wob, out, O_N);
}

// Round 18
// 250.685 us; speedup vs baseline: 7.4238x; 1.0058x over previous
//
#include <hip/hip_runtime.h>
#include <math.h>

// Problem constants (from reference)
#define BB    2
#define SS    2048
#define HIDD  2048
#define NHH   16
#define NKVV  4
#define HDD   128
#define MROWS 4096            // B*S
#define QG_N  4096            // 2*NH*HD
#define KV_N  512             // NKV*HD
#define O_N   2048            // NH*HD
#define KDIM  2048            // shared K for all four GEMMs (row stride of A and W)
#define EPS_  1e-6f
#define SCALE_ 0.08838834764831845f   // 1/sqrt(128)

typedef __attribute__((ext_vector_type(8))) __bf16 bf16x8;
typedef __attribute__((ext_vector_type(8))) unsigned short u16x8;
typedef __attribute__((ext_vector_type(4))) float f32x4;

__device__ __forceinline__ unsigned short f2bf(float f) {
  return __builtin_bit_cast(unsigned short, (__bf16)f);   // RNE via v_cvt
}

// ---------------------------------------------------------------------------
// fp32 -> bf16 convert for all four weights in ONE dispatch.
// ---------------------------------------------------------------------------
__global__ __launch_bounds__(256) void f2bf_all(const float* __restrict__ Wq,
                                                const float* __restrict__ Wk,
                                                const float* __restrict__ Wv,
                                                const float* __restrict__ Wo,
                                                unsigned short* __restrict__ dst) {
  const int s0 = QG_N * KDIM / 4;
  const int s1 = s0 + KV_N * KDIM / 4;
  const int s2 = s1 + KV_N * KDIM / 4;
  const int s3 = s2 + O_N * KDIM / 4;
  int i = blockIdx.x * 256 + threadIdx.x;
  if (i >= s3) return;
  float4 v;
  if (i < s0)      v = ((const float4*)Wq)[i];
  else if (i < s1) v = ((const float4*)Wk)[i - s0];
  else if (i < s2) v = ((const float4*)Wv)[i - s1];
  else             v = ((const float4*)Wo)[i - s2];
  ushort4 u;
  u.x = f2bf(v.x); u.y = f2bf(v.y); u.z = f2bf(v.z); u.w = f2bf(v.w);
  ((ushort4*)dst)[i] = u;
}

// ---------------------------------------------------------------------------
// RMSNorm -> bf16 x.  One block per row.
// ---------------------------------------------------------------------------
__global__ __launch_bounds__(256) void rmsnorm_k(const float* __restrict__ h,
                                                 const float* __restrict__ w,
                                                 unsigned short* __restrict__ x) {
  int row = blockIdx.x;
  int t = threadIdx.x;
  const float4* hr = (const float4*)(h + (size_t)row * HIDD);
  const float4* w4 = (const float4*)w;

  float4 v0 = hr[t], v1 = hr[t + 256];
  float ss = v0.x*v0.x + v0.y*v0.y + v0.z*v0.z + v0.w*v0.w
           + v1.x*v1.x + v1.y*v1.y + v1.z*v1.z + v1.w*v1.w;
#pragma unroll
  for (int off = 32; off > 0; off >>= 1) ss += __shfl_down(ss, off, 64);

  __shared__ float part[4];
  __shared__ float rs_sh;
  if ((t & 63) == 0) part[t >> 6] = ss;
  __syncthreads();
  if (t == 0) rs_sh = rsqrtf((part[0]+part[1]+part[2]+part[3]) * (1.0f/HIDD) + EPS_);
  __syncthreads();
  float rs = rs_sh;

  float4 w0 = w4[t], w1 = w4[t + 256];
  ushort4 o0, o1;
  o0.x = f2bf(v0.x * rs * (1.f + w0.x));
  o0.y = f2bf(v0.y * rs * (1.f + w0.y));
  o0.z = f2bf(v0.z * rs * (1.f + w0.z));
  o0.w = f2bf(v0.w * rs * (1.f + w0.w));
  o1.x = f2bf(v1.x * rs * (1.f + w1.x));
  o1.y = f2bf(v1.y * rs * (1.f + w1.y));
  o1.z = f2bf(v1.z * rs * (1.f + w1.z));
  o1.w = f2bf(v1.w * rs * (1.f + w1.w));
  ushort4* xr = (ushort4*)(x + (size_t)row * HIDD);
  xr[t] = o0;
  xr[t + 256] = o1;
}

// ---------------------------------------------------------------------------
// 128x128 bf16 MFMA GEMM core (proven path; kept for KV).
// OBF: 0 = fp32 out, 1 = bf16 out, 3 = bf16 transposed V^T[d][tok'] with the
// sigma bit-permutation folded into the token column (tok' = (tok&~63)|sig):
//   sig = (tok&32) + ((tok&12)<<1) + ((tok&16)>>2) + (tok&3)
// ---------------------------------------------------------------------------
template <int OBF>
__device__ __forceinline__ void gemm_core(const unsigned short* __restrict__ Ab,
                                          const unsigned short* __restrict__ Bb,
                                          void* __restrict__ Cv,
                                          int Ndim, int bm, int bn,
                                          unsigned short* Als, unsigned short* Bls) {
  char* ldsA = (char*)Als;
  char* ldsB = (char*)Bls;

  int t   = threadIdx.x;
  int r15 = t & 15;
  int g   = (t & 63) >> 4;
  int w   = t >> 6;
  int wr  = w >> 1, wc = w & 1;

  f32x4 acc[4][4] = {};

  for (int k0 = 0; k0 < KDIM; k0 += 64) {
    __syncthreads();
#pragma unroll
    for (int it = 0; it < 4; ++it) {
      int f      = it * 256 + t;
      int row    = f >> 3;
      int schunk = (f & 7) ^ (row & 7);
      unsigned ldsbase = (unsigned)((it * 256 + (w << 6)) << 4);
      __builtin_amdgcn_global_load_lds(
          (const unsigned int*)(Ab + ((size_t)(bm + row) << 11) + k0 + schunk * 8),
          (unsigned int*)(ldsA + ldsbase), 16, 0, 0);
      __builtin_amdgcn_global_load_lds(
          (const unsigned int*)(Bb + ((size_t)(bn + row) << 11) + k0 + schunk * 8),
          (unsigned int*)(ldsB + ldsbase), 16, 0, 0);
    }
    __syncthreads();

#pragma unroll
    for (int tt = 0; tt < 2; ++tt) {
      bf16x8 af[4], bfv[4];
#pragma unroll
      for (int mi = 0; mi < 4; ++mi) {
        int row = wr * 64 + mi * 16 + r15;
        af[mi] = *(const bf16x8*)(ldsA + row * 128 + (((4 * tt + g) ^ (row & 7)) << 4));
      }
#pragma unroll
      for (int ni = 0; ni < 4; ++ni) {
        int row = wc * 64 + ni * 16 + r15;
        bfv[ni] = *(const bf16x8*)(ldsB + row * 128 + (((4 * tt + g) ^ (row & 7)) << 4));
      }
      __builtin_amdgcn_s_setprio(1);
#pragma unroll
      for (int mi = 0; mi < 4; ++mi)
#pragma unroll
        for (int ni = 0; ni < 4; ++ni)
          acc[mi][ni] = __builtin_amdgcn_mfma_f32_16x16x32_bf16(af[mi], bfv[ni], acc[mi][ni], 0, 0, 0);
      __builtin_amdgcn_s_setprio(0);
    }
  }

#pragma unroll
  for (int mi = 0; mi < 4; ++mi)
#pragma unroll
    for (int ni = 0; ni < 4; ++ni) {
      int col = bn + wc * 64 + ni * 16 + r15;
#pragma unroll
      for (int r = 0; r < 4; ++r) {
        int rowg = bm + wr * 64 + mi * 16 + g * 4 + r;
        if (OBF == 1)
          ((unsigned short*)Cv)[(size_t)rowg * Ndim + col] = f2bf(acc[mi][ni][r]);
        else if (OBF == 3) {  // transposed bf16 V^T[d][tok'], sigma folded
          int t6 = rowg & 63;
          int sig = (t6 & 32) + ((t6 & 12) << 1) + ((t6 & 16) >> 2) + (t6 & 3);
          int tokp = (rowg & ~63) | sig;
          ((unsigned short*)Cv)[(size_t)col * MROWS + tokp] = f2bf(acc[mi][ni][r]);
        } else
          ((float*)Cv)[(size_t)rowg * Ndim + col] = acc[mi][ni][r];
      }
    }
}

template <int OBF>
__global__ __launch_bounds__(256) void gemm_bf16(const unsigned short* __restrict__ Ab,
                                                 const unsigned short* __restrict__ Bb,
                                                 void* __restrict__ Cv,
                                                 int Ndim) {
  __shared__ unsigned short Als[128 * 64];
  __shared__ unsigned short Bls[128 * 64];
  gemm_core<OBF>(Ab, Bb, Cv, Ndim, blockIdx.y * 128, blockIdx.x * 128, Als, Bls);
}

// K and V GEMMs fused; V stored TRANSPOSED + sigma-permuted (V^T[d][tok']).
__global__ __launch_bounds__(256) void gemm_kv(const unsigned short* __restrict__ Ab,
                                               const unsigned short* __restrict__ Wk,
                                               const unsigned short* __restrict__ Wv,
                                               unsigned short* __restrict__ Ck,
                                               unsigned short* __restrict__ Cvt) {
  __shared__ unsigned short Als[128 * 64];
  __shared__ unsigned short Bls[128 * 64];
  int bx = blockIdx.x;
  if (bx < 4)
    gemm_core<1>(Ab, Wk, (void*)Ck, KV_N, blockIdx.y * 128, bx * 128, Als, Bls);
  else
    gemm_core<3>(Ab, Wv, (void*)Cvt, KV_N, blockIdx.y * 128, (bx & 3) * 128, Als, Bls);
}

// ---------------------------------------------------------------------------
// QG GEMM, 256x256 8-phase counted-vmcnt schedule (r15-corrected ledger).
// ---------------------------------------------------------------------------
#define LD8(basep, r, x) \
  (*(const bf16x8*)((basep) + (size_t)(r) * 128 + ((((x) ^ ((r)&7))) << 4)))

#define STAGE_A(bufi, h, tk)                                                   \
  { _Pragma("unroll")                                                          \
    for (int c = 0; c < 2; ++c) {                                              \
      int f = c * 512 + t;                                                     \
      int rr = f >> 3;                                                         \
      int sc = (f & 7) ^ (rr & 7);                                             \
      __builtin_amdgcn_global_load_lds(                                        \
        (const unsigned int*)(Ab + ((size_t)(bm + (h)*128 + rr) << 11) + (tk)*64 + sc*8), \
        (unsigned int*)(lds8 + (bufi)*32768 + (h)*16384 + c*8192 + (w<<10)), 16, 0, 0); \
    } }

#define STAGE_B(bufi, h, tk)                                                   \
  { _Pragma("unroll")                                                          \
    for (int c = 0; c < 2; ++c) {                                              \
      int f = c * 512 + t;                                                     \
      int rr = f >> 3;                                                         \
      int sc = (f & 7) ^ (rr & 7);                                             \
      __builtin_amdgcn_global_load_lds(                                        \
        (const unsigned int*)(Bbp + ((size_t)(bn + (h)*128 + rr) << 11) + (tk)*64 + sc*8), \
        (unsigned int*)(lds8 + 65536 + (bufi)*32768 + (h)*16384 + c*8192 + (w<<10)), 16, 0, 0); \
    } }

#define RD_A(SRC, MIBASE)                                                      \
  { _Pragma("unroll")                                                          \
    for (int mi = 0; mi < 4; ++mi) {                                           \
      int rr = wr * 128 + ((MIBASE) + mi) * 16 + r15;                          \
      afr[mi][0] = LD8(SRC, rr, g);                                            \
      afr[mi][1] = LD8(SRC, rr, 4 + g);                                        \
    } }

#define RD_B(SRC, NIBASE, DST)                                                 \
  { _Pragma("unroll")                                                          \
    for (int ni = 0; ni < 2; ++ni) {                                           \
      int rr = wc * 64 + ((NIBASE) + ni) * 16 + r15;                           \
      DST[ni][0] = LD8(SRC, rr, g);                                            \
      DST[ni][1] = LD8(SRC, rr, 4 + g);                                        \
    } }

#define MFMA_QUAD(MIBASE, NIBASE, BREG)                                        \
  { __builtin_amdgcn_s_setprio(1);                                             \
    _Pragma("unroll")                                                          \
    for (int mi = 0; mi < 4; ++mi)                                             \
      _Pragma("unroll")                                                        \
      for (int ni = 0; ni < 2; ++ni)                                           \
        _Pragma("unroll")                                                      \
        for (int ks = 0; ks < 2; ++ks)                                         \
          acc[(MIBASE)+mi][(NIBASE)+ni] =                                      \
            __builtin_amdgcn_mfma_f32_16x16x32_bf16(afr[mi][ks], BREG[ni][ks], \
                                                    acc[(MIBASE)+mi][(NIBASE)+ni], 0, 0, 0); \
    __builtin_amdgcn_s_setprio(0); }

#define BAR() __builtin_amdgcn_s_barrier()

__global__ __launch_bounds__(512, 2) void gemm_qg256(const unsigned short* __restrict__ Ab,
                                                     const unsigned short* __restrict__ Bbp,
                                                     unsigned short* __restrict__ Cq,
                                                     float* __restrict__ Cg) {
  __shared__ char lds8[131072];
  int t = threadIdx.x;
  int r15 = t & 15, g = (t & 63) >> 4, w = t >> 6;
  int wr = w >> 2, wc = w & 3;
  int bm = blockIdx.y * 256, bn = blockIdx.x * 256;
  char* A0 = lds8;            char* A1 = lds8 + 32768;
  char* B0 = lds8 + 65536;    char* B1 = lds8 + 98304;

  f32x4 acc[8][4] = {};
  bf16x8 afr[4][2], b0r[2][2], b1r[2][2];

  // prologue: K-steps 0 (buf0) and 1 (buf1); wait t0 landed, t1 may fly
  STAGE_A(0, 0, 0); STAGE_A(0, 1, 0); STAGE_B(0, 0, 0); STAGE_B(0, 1, 0);
  STAGE_A(1, 0, 1); STAGE_A(1, 1, 1); STAGE_B(1, 0, 1); STAGE_B(1, 1, 1);
  asm volatile("s_waitcnt vmcnt(8)" ::: "memory");
  BAR();

  for (int i = 0; i < 15; ++i) {        // K-steps 0..29; te<=30, to<=31
    int te = 2 * i + 2, to = 2 * i + 3;
    // ph0: RD A0(lo) + B0(lo); MFMA q(0,0).  No stage (A0/B0 still live).
    RD_A(A0, 0); RD_B(B0, 0, b0r);
    BAR(); MFMA_QUAD(0, 0, b0r); BAR();
    // ph1: RD B0(hi); MFMA q(0,1).  B0 last read here.
    RD_B(B0, 2, b1r);
    BAR(); MFMA_QUAD(0, 2, b1r); BAR();
    // ph2: RD A0(hi); stage B0h0(te); MFMA q(1,0).  A0 last read here.
    RD_A(A0, 4);
    STAGE_B(0, 0, te);
    BAR(); MFMA_QUAD(4, 0, b0r); BAR();
    // ph3: stage A0h0(te); MFMA q(1,1); vmcnt(4): prev odd tiles landed
    STAGE_A(0, 0, te);
    BAR(); MFMA_QUAD(4, 2, b1r);
    asm volatile("s_waitcnt vmcnt(4)" ::: "memory");
    BAR();
    // ph4: RD A1(lo) + B1(lo); stage A0h1(te); MFMA q(0,0)
    RD_A(A1, 0); RD_B(B1, 0, b0r);
    STAGE_A(0, 1, te);
    BAR(); MFMA_QUAD(0, 0, b0r); BAR();
    // ph5: RD B1(hi); stage B0h1(te); MFMA q(0,1).  B1 last read here.
    RD_B(B1, 2, b1r);
    STAGE_B(0, 1, te);
    BAR(); MFMA_QUAD(0, 2, b1r); BAR();
    // ph6: RD A1(hi); stage B1 both halves (to); MFMA q(1,0). A1 last read.
    RD_A(A1, 4);
    STAGE_B(1, 0, to); STAGE_B(1, 1, to);
    BAR(); MFMA_QUAD(4, 0, b0r); BAR();
    // ph7: stage A1 both halves (to); MFMA q(1,1); vmcnt(8): even tiles landed
    STAGE_A(1, 0, to); STAGE_A(1, 1, to);
    BAR(); MFMA_QUAD(4, 2, b1r);
    asm volatile("s_waitcnt vmcnt(8)" ::: "memory");
    BAR();
  }
  // peeled last iteration (K-steps 30,31): no stages; drain at mid-point
  RD_A(A0, 0); RD_B(B0, 0, b0r);
  BAR(); MFMA_QUAD(0, 0, b0r); BAR();
  RD_B(B0, 2, b1r);
  BAR(); MFMA_QUAD(0, 2, b1r); BAR();
  RD_A(A0, 4);
  BAR(); MFMA_QUAD(4, 0, b0r); BAR();
  BAR(); MFMA_QUAD(4, 2, b1r);
  asm volatile("s_waitcnt vmcnt(0)" ::: "memory");
  BAR();
  RD_A(A1, 0); RD_B(B1, 0, b0r);
  BAR(); MFMA_QUAD(0, 0, b0r); BAR();
  RD_B(B1, 2, b1r);
  BAR(); MFMA_QUAD(0, 2, b1r); BAR();
  RD_A(A1, 4);
  BAR(); MFMA_QUAD(4, 0, b0r); BAR();
  BAR(); MFMA_QUAD(4, 2, b1r);

  // epilogue: q half -> bf16*SCALE, gate half -> fp32 (tiles never straddle)
  bool isq = (bn < O_N);
  int colbase = bn + wc * 64;
#pragma unroll
  for (int mi = 0; mi < 8; ++mi) {
    size_t row = (size_t)bm + wr * 128 + mi * 16 + g * 4;
#pragma unroll
    for (int ni = 0; ni < 4; ++ni) {
      int col = colbase + ni * 16 + r15;
#pragma unroll
      for (int r = 0; r < 4; ++r) {
        if (isq) Cq[(row + r) * O_N + col] = f2bf(acc[mi][ni][r] * SCALE_);
        else     Cg[(row + r) * O_N + (col - O_N)] = acc[mi][ni][r];
      }
    }
  }
}

// ---------------------------------------------------------------------------
// O-proj GEMM, 256x128 8-phase counted-vmcnt schedule (4 MFMA phases/iter).
// BM=256, BN=128, BK=64, 512 thr = 8 waves (wr 0..3 x wc 0..1), wave 64x64.
// LDS 96 KB: A 2x(2 halves x 16K) @0/32768, B 2x16K @65536/81920.
// Buffer liveness per iter (K-steps te=2i buf0, to=2i+1 buf1):
//   ph0: RD A0(all mi)+B0(n01); stage B1(2i+1)   [B1 old dead since prev ph3]
//   ph1: RD B0(n23);            stage A0h0(te+2) [A0 dead after ph0]
//        vmcnt(2): drains A1(to)+B1(to) before ph2 reads  [leaves A0h0']
//   ph2: RD A1(all)+B1(n01);    stage A0h1(te+2)+B0(te+2) [B0 dead after ph1]
//   ph3: RD B1(n23);            stage A1 both (to+2)      [A1 dead after ph2]
//        vmcnt(4): drains A0'h0/h1+B0' before next ph0    [leaves A1'(4)]
// Loop invariant: 4 outstanding (A1' halves) entering ph0.  Peel drains 0.
// ---------------------------------------------------------------------------
#define OST_A(bufi, h, tk)                                                     \
  { _Pragma("unroll")                                                          \
    for (int c = 0; c < 2; ++c) {                                              \
      int f = c * 512 + t;                                                     \
      int rr = f >> 3;                                                         \
      int sc = (f & 7) ^ (rr & 7);                                             \
      __builtin_amdgcn_global_load_lds(                                        \
        (const unsigned int*)(Ab + ((size_t)(bm + (h)*128 + rr) << 11) + (tk)*64 + sc*8), \
        (unsigned int*)(lds8 + (bufi)*32768 + (h)*16384 + c*8192 + (w<<10)), 16, 0, 0); \
    } }

#define OST_B(bufi, tk)                                                        \
  { _Pragma("unroll")                                                          \
    for (int c = 0; c < 2; ++c) {                                              \
      int f = c * 512 + t;                                                     \
      int rr = f >> 3;                                                         \
      int sc = (f & 7) ^ (rr & 7);                                             \
      __builtin_amdgcn_global_load_lds(                                        \
        (const unsigned int*)(Bbp + ((size_t)(bn + rr) << 11) + (tk)*64 + sc*8), \
        (unsigned int*)(lds8 + 65536 + (bufi)*16384 + c*8192 + (w<<10)), 16, 0, 0); \
    } }

#define ORD_A(bufi)                                                            \
  { const char* abase = lds8 + (bufi)*32768 + (wr >> 1)*16384;                 \
    _Pragma("unroll")                                                          \
    for (int mi = 0; mi < 4; ++mi) {                                           \
      int rl = ((wr & 1) * 64) + mi * 16 + r15;                                \
      afr[mi][0] = LD8(abase, rl, g);                                          \
      afr[mi][1] = LD8(abase, rl, 4 + g);                                      \
    } }

#define ORD_B(bufi, NIBASE, DST)                                               \
  { const char* bbase = lds8 + 65536 + (bufi)*16384;                           \
    _Pragma("unroll")                                                          \
    for (int ni = 0; ni < 2; ++ni) {                                           \
      int rl = wc * 64 + ((NIBASE) + ni) * 16 + r15;                           \
      DST[ni][0] = LD8(bbase, rl, g);                                          \
      DST[ni][1] = LD8(bbase, rl, 4 + g);                                      \
    } }

#define OMFMA(NIBASE, BREG)                                                    \
  { __builtin_amdgcn_s_setprio(1);                                             \
    _Pragma("unroll")                                                          \
    for (int mi = 0; mi < 4; ++mi)                                             \
      _Pragma("unroll")                                                        \
      for (int ni = 0; ni < 2; ++ni)                                           \
        _Pragma("unroll")                                                      \
        for (int ks = 0; ks < 2; ++ks)                                         \
          acc[mi][(NIBASE)+ni] =                                               \
            __builtin_amdgcn_mfma_f32_16x16x32_bf16(afr[mi][ks], BREG[ni][ks], \
                                                    acc[mi][(NIBASE)+ni], 0, 0, 0); \
    __builtin_amdgcn_s_setprio(0); }

__global__ __launch_bounds__(512, 2) void gemm_o256(const unsigned short* __restrict__ Ab,
                                                    const unsigned short* __restrict__ Bbp,
                                                    float* __restrict__ C) {
  __shared__ char lds8[98304];
  int t = threadIdx.x;
  int r15 = t & 15, g = (t & 63) >> 4, w = t >> 6;
  int wr = w >> 1, wc = w & 1;
  int bm = blockIdx.y * 256, bn = blockIdx.x * 128;

  f32x4 acc[4][4] = {};
  bf16x8 afr[4][2], b0r[2][2], b1r[2][2];

  // prologue: A0/B0 = K-step 0, A1 = K-step 1 (B1(1) staged at iter-0 ph0)
  OST_A(0, 0, 0); OST_A(0, 1, 0); OST_B(0, 0);
  OST_A(1, 0, 1); OST_A(1, 1, 1);
  asm volatile("s_waitcnt vmcnt(4)" ::: "memory");   // A0,B0 landed; A1 flying
  BAR();

  for (int i = 0; i < 15; ++i) {        // K-step pairs (2i, 2i+1), i=0..14
    int to = 2 * i + 1, te2 = 2 * i + 2, to2 = 2 * i + 3;
    // ph0: RD A0+B0(n01); stage B1(to) [read this iter ph2/3]; MFMA q(n01,te)
    ORD_A(0); ORD_B(0, 0, b0r);
    OST_B(1, to);
    BAR(); OMFMA(0, b0r); BAR();
    // ph1: RD B0(n23); stage A0h0(te2); MFMA q(n23,te); vmcnt(2)
    ORD_B(0, 2, b1r);
    OST_A(0, 0, te2);
    BAR(); OMFMA(2, b1r);
    asm volatile("s_waitcnt vmcnt(2)" ::: "memory");  // A1(to),B1(to) landed
    BAR();
    // ph2: RD A1+B1(n01); stage A0h1(te2)+B0(te2); MFMA q(n01,to)
    ORD_A(1); ORD_B(1, 0, b0r);
    OST_A(0, 1, te2); OST_B(0, te2);
    BAR(); OMFMA(0, b0r); BAR();
    // ph3: RD B1(n23); stage A1 both (to2); MFMA q(n23,to); vmcnt(4)
    ORD_B(1, 2, b1r);
    OST_A(1, 0, to2); OST_A(1, 1, to2);
    BAR(); OMFMA(2, b1r);
    asm volatile("s_waitcnt vmcnt(4)" ::: "memory");  // A0',B0' landed
    BAR();
  }
  // peeled pair (K-steps 30,31): stage only B1(31); drain mid-way
  ORD_A(0); ORD_B(0, 0, b0r);
  OST_B(1, 31);
  BAR(); OMFMA(0, b0r); BAR();
  ORD_B(0, 2, b1r);
  BAR(); OMFMA(2, b1r);
  asm volatile("s_waitcnt vmcnt(0)" ::: "memory");
  BAR();
  ORD_A(1); ORD_B(1, 0, b0r);
  BAR(); OMFMA(0, b0r); BAR();
  ORD_B(1, 2, b1r);
  BAR(); OMFMA(2, b1r);

  // epilogue: fp32 store
#pragma unroll
  for (int mi = 0; mi < 4; ++mi) {
    size_t row = (size_t)bm + wr * 64 + mi * 16 + g * 4;
#pragma unroll
    for (int ni = 0; ni < 4; ++ni) {
      int col = bn + wc * 64 + ni * 16 + r15;
#pragma unroll
      for (int r = 0; r < 4; ++r)
        C[(row + r) * O_N + col] = acc[mi][ni][r];
    }
  }
}

// ---------------------------------------------------------------------------
// bf16 MFMA flash attention v7 (unchanged from round 17).
// ---------------------------------------------------------------------------
__global__ __launch_bounds__(256, 2) void attn_mfma(const unsigned short* __restrict__ qb,
                                                    const float* __restrict__ gateb,
                                                    const unsigned short* __restrict__ kb,
                                                    const unsigned short* __restrict__ vt,
                                                    unsigned short* __restrict__ obuf) {
  __shared__ unsigned short Ks[2][64 * 128];   // [kv][d], chunk^=(kv&7) swizzle
  __shared__ unsigned short Vt[2][128 * 64];   // [d][sig(tok)], chunk^=(d&7) swizzle
  char* ldsK0 = (char*)Ks;
  char* ldsV0 = (char*)Vt;

  int t = threadIdx.x;
  int l = t & 63, w = t >> 6;
  int c15 = l & 15, g = l >> 4;
  int bid = blockIdx.x;
  int swz = (bid & 7) * 64 + (bid >> 3);
  int qt = swz & 15, h = (swz >> 4) & 15, b = swz >> 8;
  int kh = h >> 2;                          // G = 4
  size_t rowQ0 = (size_t)b * SS + (size_t)qt * 128;
  size_t rowKbase = (size_t)b * SS;

  bf16x8 qf[2][4];
#pragma unroll
  for (int qi = 0; qi < 2; ++qi)
#pragma unroll
    for (int ks = 0; ks < 4; ++ks)
      qf[qi][ks] = *(const bf16x8*)(qb + (rowQ0 + w * 32 + qi * 16 + c15) * O_N
                                       + h * HDD + g * 8 + ks * 32);

  f32x4 accO[2][8] = {};
  float mrun[2] = {-INFINITY, -INFINITY};
  float lrun[2] = {0.f, 0.f};

#define ISSUE_K(bufi, kt_)                                                     \
  {                                                                            \
    size_t rowK0 = rowKbase + (size_t)(kt_) * 64;                              \
    _Pragma("unroll")                                                          \
    for (int it = 0; it < 4; ++it) {                                           \
      int f = it * 256 + t;                                                    \
      int kv = f >> 4;                                                         \
      int schunk = (f & 15) ^ (kv & 7);                                        \
      unsigned ldsbase = (unsigned)((it * 256 + (w << 6)) << 4);               \
      __builtin_amdgcn_global_load_lds(                                        \
          (const unsigned int*)(kb + (rowK0 + kv) * KV_N + kh * HDD + schunk * 8), \
          (unsigned int*)(ldsK0 + (bufi) * 16384 + ldsbase), 16, 0, 0);        \
    }                                                                          \
  }
#define ISSUE_VT(bufi, kt_)                                                    \
  {                                                                            \
    size_t tokbase = rowKbase + (size_t)(kt_) * 64;                            \
    _Pragma("unroll")                                                          \
    for (int it = 0; it < 4; ++it) {                                           \
      int f = it * 256 + t;                                                    \
      int row = f >> 3;                                                        \
      int schunk = (f & 7) ^ (row & 7);                                        \
      unsigned ldsbase = (unsigned)((it * 256 + (w << 6)) << 4);               \
      __builtin_amdgcn_global_load_lds(                                        \
          (const unsigned int*)(vt + (size_t)(kh * 128 + row) * MROWS + tokbase + schunk * 8), \
          (unsigned int*)(ldsV0 + (bufi) * 16384 + ldsbase), 16, 0, 0);        \
    }                                                                          \
  }

  ISSUE_K(0, 0);
  ISSUE_VT(0, 0);
  asm volatile("s_waitcnt vmcnt(0)" ::: "memory");
  __syncthreads();

  const int NT = SS / 64;
  for (int kt = 0; kt < NT; ++kt) {
    int cur = kt & 1, nxt = cur ^ 1;
    char* ldsK = ldsK0 + cur * 16384;
    char* ldsV = ldsV0 + cur * 16384;

    if (kt + 1 < NT) {
      ISSUE_K(nxt, kt + 1);
      ISSUE_VT(nxt, kt + 1);
    }

    f32x4 accS[2][4] = {};
    __builtin_amdgcn_s_setprio(1);
#pragma unroll
    for (int nf = 0; nf < 4; ++nf) {
      int kvr = nf * 16 + c15;
#pragma unroll
      for (int ks = 0; ks < 4; ++ks) {
        bf16x8 kf = *(const bf16x8*)(ldsK + kvr * 256 + ((((g + 4 * ks) ^ (kvr & 7)) << 4)));
#pragma unroll
        for (int qi = 0; qi < 2; ++qi)
          accS[qi][nf] = __builtin_amdgcn_mfma_f32_16x16x32_bf16(kf, qf[qi][ks], accS[qi][nf], 0, 0, 0);
      }
    }
    __builtin_amdgcn_s_setprio(0);

    float mt[2];
#pragma unroll
    for (int qi = 0; qi < 2; ++qi) {
      float m0 = fmaxf(fmaxf(accS[qi][0][0], accS[qi][0][1]), fmaxf(accS[qi][0][2], accS[qi][0][3]));
#pragma unroll
      for (int nf = 1; nf < 4; ++nf)
        m0 = fmaxf(m0, fmaxf(fmaxf(accS[qi][nf][0], accS[qi][nf][1]), fmaxf(accS[qi][nf][2], accS[qi][nf][3])));
      m0 = fmaxf(m0, __shfl_xor(m0, 16, 64));
      m0 = fmaxf(m0, __shfl_xor(m0, 32, 64));
      mt[qi] = m0;
    }

    bool safe = (mt[0] <= mrun[0] + 8.f) && (mt[1] <= mrun[1] + 8.f);
    if (!__all(safe)) {
#pragma unroll
      for (int qi = 0; qi < 2; ++qi) {
        float mnew = fmaxf(mrun[qi], mt[qi]);
        float al = __expf(mrun[qi] - mnew);
        mrun[qi] = mnew;
        lrun[qi] *= al;
        float alr[4];
#pragma unroll
        for (int r = 0; r < 4; ++r) alr[r] = __shfl(al, g * 4 + r, 16);
#pragma unroll
        for (int df = 0; df < 8; ++df)
#pragma unroll
          for (int r = 0; r < 4; ++r) accO[qi][df][r] *= alr[r];
      }
    }

    u16x8 pfr[2][2];
#pragma unroll
    for (int qi = 0; qi < 2; ++qi) {
      float ps = 0.f;
#pragma unroll
      for (int nf = 0; nf < 4; ++nf) {
        float p0 = __expf(accS[qi][nf][0] - mrun[qi]);
        float p1 = __expf(accS[qi][nf][1] - mrun[qi]);
        float p2 = __expf(accS[qi][nf][2] - mrun[qi]);
        float p3 = __expf(accS[qi][nf][3] - mrun[qi]);
        ps += (p0 + p1) + (p2 + p3);
        pfr[qi][nf >> 1][(nf & 1) * 4 + 0] = f2bf(p0);
        pfr[qi][nf >> 1][(nf & 1) * 4 + 1] = f2bf(p1);
        pfr[qi][nf >> 1][(nf & 1) * 4 + 2] = f2bf(p2);
        pfr[qi][nf >> 1][(nf & 1) * 4 + 3] = f2bf(p3);
      }
      ps += __shfl_xor(ps, 16, 64);
      ps += __shfl_xor(ps, 32, 64);
      lrun[qi] += ps;
    }

    // O += P V : 32 MFMA.  A = pfr (own regs), B = ONE b128 from sigma-space Vt
    __builtin_amdgcn_s_setprio(1);
#pragma unroll
    for (int ks2 = 0; ks2 < 2; ++ks2) {
      bf16x8 pf0 = __builtin_bit_cast(bf16x8, pfr[0][ks2]);
      bf16x8 pf1 = __builtin_bit_cast(bf16x8, pfr[1][ks2]);
#pragma unroll
      for (int df = 0; df < 8; ++df) {
        int d = df * 16 + c15;
        bf16x8 vf = *(const bf16x8*)(ldsV + d * 128 + ((((g + 4 * ks2) ^ (d & 7)) << 4)));
        accO[0][df] = __builtin_amdgcn_mfma_f32_16x16x32_bf16(pf0, vf, accO[0][df], 0, 0, 0);
        accO[1][df] = __builtin_amdgcn_mfma_f32_16x16x32_bf16(pf1, vf, accO[1][df], 0, 0, 0);
      }
    }
    __builtin_amdgcn_s_setprio(0);

    if (kt + 1 < NT) {
      asm volatile("s_waitcnt vmcnt(0)" ::: "memory");
    }
    __syncthreads();
  }

#pragma unroll
  for (int qi = 0; qi < 2; ++qi) {
    float invL = 1.f / lrun[qi];
    float ivr[4];
#pragma unroll
    for (int r = 0; r < 4; ++r) ivr[r] = __shfl(invL, g * 4 + r, 16);
#pragma unroll
    for (int r = 0; r < 4; ++r) {
      size_t row = rowQ0 + w * 32 + qi * 16 + g * 4 + r;
#pragma unroll
      for (int df = 0; df < 8; ++df) {
        int d = df * 16 + c15;
        float gt = gateb[row * (size_t)O_N + h * HDD + d];
        float sg = 1.f / (1.f + __expf(-gt));
        obuf[row * (size_t)O_N + h * HDD + d] = f2bf(accO[qi][df][r] * ivr[r] * sg);
      }
    }
  }
#undef ISSUE_K
#undef ISSUE_VT
}

// ---------------------------------------------------------------------------
// Launch
// ---------------------------------------------------------------------------
extern "C" void kernel_launch(void* const* d_in, const int* in_sizes, int n_in,
                              void* d_out, int out_size, void* d_ws, size_t ws_size,
                              hipStream_t stream) {
  const float* hs = (const float*)d_in[0];
  // d_in[1] = position_ids (unused by the reference)
  const float* Wq = (const float*)d_in[2];
  const float* Wk = (const float*)d_in[3];
  const float* Wv = (const float*)d_in[4];
  const float* Wo = (const float*)d_in[5];
  const float* nw = (const float*)d_in[6];
  float* out = (float*)d_out;

  // workspace (~121 MB): gate fp32 | bf16: qb,kb,vt,x,ob | bf16 W (contiguous)
  float* gateb = (float*)d_ws;
  unsigned short* qb16 = (unsigned short*)(gateb + (size_t)MROWS * O_N);
  unsigned short* kb16 = qb16 + (size_t)MROWS * O_N;
  unsigned short* vt16 = kb16 + (size_t)MROWS * KV_N;   // V^T [512][4096], sigma-permuted
  unsigned short* xb   = vt16 + (size_t)KV_N * MROWS;
  unsigned short* ob   = xb   + (size_t)MROWS * HIDD;
  unsigned short* wqb  = ob   + (size_t)MROWS * O_N;
  unsigned short* wkb  = wqb  + (size_t)QG_N * KDIM;
  unsigned short* wvb  = wkb  + (size_t)KV_N * KDIM;
  unsigned short* wob  = wvb  + (size_t)KV_N * KDIM;

  const int tot4 = (QG_N + KV_N + KV_N + O_N) * KDIM / 4;
  f2bf_all<<<(tot4 + 255) / 256, 256, 0, stream>>>(Wq, Wk, Wv, Wo, wqb);
  rmsnorm_k<<<MROWS, 256, 0, stream>>>(hs, nw, xb);

  gemm_qg256<<<dim3(QG_N/256, MROWS/256), 512, 0, stream>>>(xb, wqb, qb16, gateb);
  gemm_kv<<<dim3(8, MROWS/128), 256, 0, stream>>>(xb, wkb, wvb, kb16, vt16);
  attn_mfma<<<dim3(512), 256, 0, stream>>>(qb16, gateb, kb16, vt16, ob);
  gemm_o256<<<dim3(O_N/128, MROWS/256), 512, 0, stream>>>(ob, wob, out);
}